// Round 2
// baseline (718.200 us; speedup 1.0000x reference)
//
#include <hip/hip_runtime.h>
#include <hip/hip_bf16.h>

typedef __attribute__((ext_vector_type(8))) short v8s;   // 8 x bf16 (as i16)
typedef __attribute__((ext_vector_type(4))) float v4f;
typedef unsigned short u16;

static constexpr int TT = 2048;        // tokens
static constexpr int HD = 2048;        // hidden
static constexpr int FD = 8192;        // ffn dim
static constexpr int NE = 8;           // experts
static constexpr int NR = 16;          // lora rank
static constexpr int NX = FD + NE*NR;  // 8320 = 65*128 (ext N for gate/up GEMM)

// ---------- helpers ----------
__device__ __forceinline__ u16 f2b(float f) {            // fp32 -> bf16 RNE
  union { float f; unsigned u; } v; v.f = f;
  unsigned r = v.u + 0x7FFFu + ((v.u >> 16) & 1u);
  return (u16)(r >> 16);
}
__device__ __forceinline__ float b2f(u16 h) {
  union { unsigned u; float f; } v; v.u = ((unsigned)h) << 16;
  return v.f;
}
__device__ __forceinline__ v8s pack8(v4f a, v4f b) {
  v8s r;
  r[0]=(short)f2b(a.x); r[1]=(short)f2b(a.y); r[2]=(short)f2b(a.z); r[3]=(short)f2b(a.w);
  r[4]=(short)f2b(b.x); r[5]=(short)f2b(b.y); r[6]=(short)f2b(b.z); r[7]=(short)f2b(b.w);
  return r;
}
__device__ __forceinline__ void gload_lds16(const void* g, void* l) {
  __builtin_amdgcn_global_load_lds(
      (const __attribute__((address_space(1))) unsigned int*)g,
      (__attribute__((address_space(3))) unsigned int*)l, 16, 0, 0);
}

// ---------- cast fp32 -> bf16 ----------
__global__ __launch_bounds__(256)
void cast_kernel(const float* __restrict__ src, u16* __restrict__ dst, long n) {
  long stride = (long)gridDim.x * 256 * 8;
  for (long i = ((long)blockIdx.x * 256 + threadIdx.x) * 8; i < n; i += stride) {
    v4f a = *(const v4f*)(src + i);
    v4f b = *(const v4f*)(src + i + 4);
    *(v8s*)(dst + i) = pack8(a, b);
  }
}

// ---------- router + gather ----------
__global__ __launch_bounds__(64)
void router_kernel(const float* __restrict__ h, const float* __restrict__ gw,
                   int* __restrict__ sel, int* __restrict__ count,
                   int* __restrict__ listTok, float* __restrict__ listW) {
  int t = blockIdx.x, lane = threadIdx.x;
  const float* hp = h + (size_t)t * HD;
  float acc[8] = {0,0,0,0,0,0,0,0};
  for (int i = lane; i < HD; i += 64) {
    float hv = hp[i];
    #pragma unroll
    for (int e = 0; e < 8; ++e) acc[e] += hv * gw[e*HD + i];
  }
  #pragma unroll
  for (int off = 32; off > 0; off >>= 1) {
    #pragma unroll
    for (int e = 0; e < 8; ++e) acc[e] += __shfl_xor(acc[e], off, 64);
  }
  if (lane == 0) {
    int e0 = -1, e1 = -1; float b0 = -1e30f, b1 = -1e30f;
    #pragma unroll
    for (int e = 0; e < 8; ++e) {
      float v = acc[e];
      if (v > b0) { b1 = b0; e1 = e0; b0 = v; e0 = e; }
      else if (v > b1) { b1 = v; e1 = e; }
    }
    float p1 = __expf(b1 - b0);            // p0 = 1
    float w0 = 1.f / (1.f + p1);
    float w1 = p1 * w0;
    sel[2*t] = e0; sel[2*t+1] = e1;
    int pos0 = atomicAdd(&count[e0], 1);
    listTok[e0*TT + pos0] = t;           listW[e0*TT + pos0] = w0;
    int pos1 = atomicAdd(&count[e1], 1);
    listTok[e1*TT + pos1] = t | (1<<20); listW[e1*TT + pos1] = w1;
  }
}

// ---------- 128x128x64 bf16 GEMM (m97 structure), C = A @ B^T ----------
// MODE 0: store bf16 C (ldc). MODE 1: fp32 out + fused down-lora epilogue.
template<int MODE>
__global__ __launch_bounds__(256)
void gemm128(const u16* __restrict__ A, const u16* __restrict__ B, void* __restrict__ Cout,
             int M, int N, int K, int ldc,
             const float* __restrict__ cC, const int* __restrict__ sel,
             const float* __restrict__ Bd) {
  __shared__ u16 As[128*64];
  __shared__ u16 Bs[128*64];
  const int tid  = threadIdx.x;
  const int lane = tid & 63, wid = tid >> 6;
  const int m0 = blockIdx.x * 128, n0 = blockIdx.y * 128;
  const int wr = wid >> 1, wc = wid & 1;                 // 2x2 waves of 64x64
  const int lrow = lane >> 3, lcol = (lane & 7) * 8;
  v4f acc[4][4];
  #pragma unroll
  for (int mi = 0; mi < 4; ++mi)
    #pragma unroll
    for (int ni = 0; ni < 4; ++ni) acc[mi][ni] = (v4f){0.f,0.f,0.f,0.f};

  for (int k0 = 0; k0 < K; k0 += 64) {
    #pragma unroll
    for (int it = 0; it < 4; ++it) {
      int seg = wid*4 + it;                 // 0..15, uniform per wave
      int row = seg*8 + lrow;               // 0..127
      gload_lds16(A + (size_t)(m0+row)*K + k0 + lcol, As + seg*512);
      gload_lds16(B + (size_t)(n0+row)*K + k0 + lcol, Bs + seg*512);
    }
    __syncthreads();
    #pragma unroll
    for (int kk = 0; kk < 64; kk += 32) {
      v8s af[4], bfr[4];
      #pragma unroll
      for (int mi = 0; mi < 4; ++mi)
        af[mi] = *(const v8s*)(As + (wr*64 + mi*16 + (lane&15))*64 + kk + (lane>>4)*8);
      #pragma unroll
      for (int ni = 0; ni < 4; ++ni)
        bfr[ni] = *(const v8s*)(Bs + (wc*64 + ni*16 + (lane&15))*64 + kk + (lane>>4)*8);
      #pragma unroll
      for (int mi = 0; mi < 4; ++mi)
        #pragma unroll
        for (int ni = 0; ni < 4; ++ni)
          acc[mi][ni] = __builtin_amdgcn_mfma_f32_16x16x32_bf16(af[mi], bfr[ni], acc[mi][ni], 0, 0, 0);
    }
    __syncthreads();
  }

  if (MODE == 0) {
    u16* C = (u16*)Cout;
    #pragma unroll
    for (int mi = 0; mi < 4; ++mi)
      #pragma unroll
      for (int j = 0; j < 4; ++j) {
        int row = m0 + wr*64 + mi*16 + (lane>>4)*4 + j;
        size_t base = (size_t)row*ldc + n0 + wc*64 + (lane&15);
        #pragma unroll
        for (int ni = 0; ni < 4; ++ni)
          C[base + ni*16] = f2b(acc[mi][ni][j]);
      }
  } else {
    float* C = (float*)Cout;
    #pragma unroll
    for (int mi = 0; mi < 4; ++mi)
      #pragma unroll
      for (int j = 0; j < 4; ++j) {
        int t = m0 + wr*64 + mi*16 + (lane>>4)*4 + j;
        int e0 = sel[2*t], e1 = sel[2*t+1];
        const float* cc = cC + (size_t)t*32;
        float c0r[16], c1r[16];
        #pragma unroll
        for (int r = 0; r < 16; ++r) { c0r[r] = cc[r]; c1r[r] = cc[16+r]; }
        const float* bd0b = Bd + (size_t)e0*HD*16;
        const float* bd1b = Bd + (size_t)e1*HD*16;
        #pragma unroll
        for (int ni = 0; ni < 4; ++ni) {
          int col = n0 + wc*64 + ni*16 + (lane&15);
          const float* bd0 = bd0b + (size_t)col*16;
          const float* bd1 = bd1b + (size_t)col*16;
          float lora = 0.f;
          #pragma unroll
          for (int r = 0; r < 16; ++r) lora += c0r[r]*bd0[r] + c1r[r]*bd1[r];
          C[(size_t)t*ldc + col] = acc[mi][ni][j] + lora;
        }
      }
  }
}

// ---------- expert kernel: rank-16 deltas + silu*u + weighted act + c=2w*(act@Ad^T) ----------
static constexpr int HA_LD = 40;   // padded LDS strides (bank-spread, 16B-aligned)
static constexpr int BG_LD = 40;
static constexpr int AW_LD = 72;

__global__ __launch_bounds__(256)
void expert_kernel(const u16* __restrict__ cgE, const u16* __restrict__ cuE,   // [TT][NX]
                   const float* __restrict__ Bg, const float* __restrict__ Bu, // [E][F][16]
                   const float* __restrict__ Ad,                               // [E][16][F]
                   const int* __restrict__ count, const int* __restrict__ listTok,
                   const float* __restrict__ listW,
                   u16* __restrict__ actw0, u16* __restrict__ actw1,           // [TT+1][F]
                   float* __restrict__ cC) {                                   // [TT+1][2][16]
  const int e = blockIdx.y, g = blockIdx.x;
  const int n = count[e];
  if (g*16 >= n) return;
  const int tid = threadIdx.x, lane = tid & 63, w = tid >> 6;
  __shared__ u16 hAg[16*HA_LD], hAu[16*HA_LD];
  __shared__ u16 BgS[4][64*BG_LD], BuS[4][64*BG_LD];
  __shared__ u16 AWs[4][16*AW_LD];
  __shared__ int sTok[16], sSlot[16];
  __shared__ float sW[16];
  __shared__ float dAred[4][256];

  if (tid < 16) {
    int idx = g*16 + tid;
    if (idx < n) {
      int ent = listTok[e*TT + idx];
      sTok[tid] = ent & 0xFFFF; sSlot[tid] = (ent >> 20) & 1; sW[tid] = listW[e*TT + idx];
    } else { sTok[tid] = TT; sSlot[tid] = 0; sW[tid] = 0.f; }  // dummy -> dump row TT
  }
  __syncthreads();
  if (tid < 128) {   // stage hA (both tensors), zero-pad K 16..31
    int tensor = tid >> 6;
    int sub = tid & 63;
    int row = sub >> 2, c8 = (sub & 3) * 8;
    int trd = min(sTok[row], TT - 1);
    u16 vals[8];
    if (c8 < 16) {
      const u16* src = (tensor ? cuE : cgE) + (size_t)trd*NX + FD + e*NR + c8;
      #pragma unroll
      for (int q = 0; q < 8; ++q) vals[q] = src[q];
    } else {
      #pragma unroll
      for (int q = 0; q < 8; ++q) vals[q] = 0;
    }
    u16* dst = (tensor ? hAu : hAg) + row*HA_LD + c8;
    #pragma unroll
    for (int q = 0; q < 8; ++q) dst[q] = vals[q];
  }
  __syncthreads();

  int tR[4], slR[4]; float wR[4]; size_t tRD[4];
  #pragma unroll
  for (int j = 0; j < 4; ++j) {
    int r = (lane>>4)*4 + j;
    tR[j] = sTok[r]; slR[j] = sSlot[r]; wR[j] = sW[r];
    tRD[j] = (size_t)min(tR[j], TT - 1);
  }
  v8s afg = *(const v8s*)(hAg + (lane&15)*HA_LD + (lane>>4)*8);
  v8s afu = *(const v8s*)(hAu + (lane&15)*HA_LD + (lane>>4)*8);
  v4f accDA = (v4f){0.f,0.f,0.f,0.f};
  u16* bgw = BgS[w]; u16* buw = BuS[w]; u16* aww = AWs[w];

  { // zero K=16..31 pad of B-staging once (per-wave private region)
    v8s z = {0,0,0,0,0,0,0,0};
    *(v8s*)(bgw + lane*BG_LD + 16) = z; *(v8s*)(bgw + lane*BG_LD + 24) = z;
    *(v8s*)(buw + lane*BG_LD + 16) = z; *(v8s*)(buw + lane*BG_LD + 24) = z;
  }

  for (int ch = w; ch < 128; ch += 4) {   // 64-wide f-chunks, wave-private
    int f0 = ch * 64;
    { // stage Bg/Bu rows (lane = f-row), fp32 -> bf16
      const float* gp = Bg + ((size_t)e*FD + f0 + lane)*16;
      v4f q0 = *(const v4f*)gp, q1 = *(const v4f*)(gp+4), q2 = *(const v4f*)(gp+8), q3 = *(const v4f*)(gp+12);
      *(v8s*)(bgw + lane*BG_LD)     = pack8(q0, q1);
      *(v8s*)(bgw + lane*BG_LD + 8) = pack8(q2, q3);
      const float* up = Bu + ((size_t)e*FD + f0 + lane)*16;
      v4f r0 = *(const v4f*)up, r1 = *(const v4f*)(up+4), r2 = *(const v4f*)(up+8), r3 = *(const v4f*)(up+12);
      *(v8s*)(buw + lane*BG_LD)     = pack8(r0, r1);
      *(v8s*)(buw + lane*BG_LD + 8) = pack8(r2, r3);
    }
    v4f dg[4], du[4];
    #pragma unroll
    for (int nf = 0; nf < 4; ++nf) {
      v8s bgf = *(const v8s*)(bgw + (nf*16 + (lane&15))*BG_LD + (lane>>4)*8);
      v8s buf = *(const v8s*)(buw + (nf*16 + (lane&15))*BG_LD + (lane>>4)*8);
      dg[nf] = __builtin_amdgcn_mfma_f32_16x16x32_bf16(afg, bgf, (v4f){0.f,0.f,0.f,0.f}, 0, 0, 0);
      du[nf] = __builtin_amdgcn_mfma_f32_16x16x32_bf16(afu, buf, (v4f){0.f,0.f,0.f,0.f}, 0, 0, 0);
    }
    #pragma unroll
    for (int nf = 0; nf < 4; ++nf) {
      #pragma unroll
      for (int j = 0; j < 4; ++j) {
        int fi = nf*16 + (lane&15);
        size_t fg = (size_t)(f0 + fi);
        float cgv = b2f(cgE[tRD[j]*NX + fg]);
        float cuv = b2f(cuE[tRD[j]*NX + fg]);
        float gv = cgv + 2.f * dg[nf][j];
        float uv = cuv + 2.f * du[nf][j];
        float a  = gv / (1.f + __expf(-gv)) * uv;   // silu(g)*u
        u16 ab = f2b(wR[j] * a);
        (slR[j] ? actw1 : actw0)[(size_t)tR[j]*FD + fg] = ab;
        aww[((lane>>4)*4 + j)*AW_LD + fi] = ab;
      }
    }
    #pragma unroll
    for (int ks = 0; ks < 2; ++ks) {   // dA accumulate: [16 tok] x [16 r] over K=64
      v8s aA = *(const v8s*)(aww + (lane&15)*AW_LD + ks*32 + (lane>>4)*8);
      const float* ap = Ad + ((size_t)e*16 + (lane&15))*FD + f0 + ks*32 + (lane>>4)*8;
      v4f q0 = *(const v4f*)ap, q1 = *(const v4f*)(ap+4);
      v8s bA = pack8(q0, q1);
      accDA = __builtin_amdgcn_mfma_f32_16x16x32_bf16(aA, bA, accDA, 0, 0, 0);
    }
  }
  #pragma unroll
  for (int j = 0; j < 4; ++j)
    dAred[w][((lane>>4)*4 + j)*16 + (lane&15)] = accDA[j];
  __syncthreads();
  {
    int row = tid >> 4, col = tid & 15;
    float s2 = dAred[0][row*16+col] + dAred[1][row*16+col] + dAred[2][row*16+col] + dAred[3][row*16+col];
    cC[((size_t)sTok[row]*2 + sSlot[row])*16 + col] = 2.f * s2;   // LORA_SCALING folded
  }
}

// ---------- combine: abar = actw0 + actw1 (bf16) ----------
__global__ __launch_bounds__(256)
void combine_kernel(const u16* __restrict__ a0, const u16* __restrict__ a1,
                    u16* __restrict__ ab, long n) {
  long stride = (long)gridDim.x * 256 * 8;
  for (long i = ((long)blockIdx.x * 256 + threadIdx.x) * 8; i < n; i += stride) {
    v8s x = *(const v8s*)(a0 + i);
    v8s y = *(const v8s*)(a1 + i);
    v8s o;
    #pragma unroll
    for (int j = 0; j < 8; ++j) o[j] = (short)f2b(b2f((u16)x[j]) + b2f((u16)y[j]));
    *(v8s*)(ab + i) = o;
  }
}

// ---------- launch ----------
extern "C" void kernel_launch(void* const* d_in, const int* in_sizes, int n_in,
                              void* d_out, int out_size, void* d_ws, size_t ws_size,
                              hipStream_t stream) {
  (void)in_sizes; (void)n_in; (void)out_size; (void)ws_size;
  const float* h  = (const float*)d_in[0];
  const float* gw = (const float*)d_in[1];
  const float* Wg = (const float*)d_in[2];
  const float* Wu = (const float*)d_in[3];
  const float* Wd = (const float*)d_in[4];
  const float* Ag = (const float*)d_in[5];
  const float* Bg = (const float*)d_in[6];
  const float* Au = (const float*)d_in[7];
  const float* Bu = (const float*)d_in[8];
  const float* Ad = (const float*)d_in[9];
  const float* Bd = (const float*)d_in[10];

  char* ws = (char*)d_ws;
  size_t off = 0;
  auto alloc = [&](size_t bytes) { size_t c = off; off += (bytes + 255) & ~(size_t)255; return c; };
  u16*  hb     = (u16*)(ws + alloc((size_t)TT*HD*2));            // 8 MB
  u16*  Bgx    = (u16*)(ws + alloc((size_t)NX*HD*2));            // 34 MB, later aliased as actw0 [TT+1][F]
  u16*  Bux    = (u16*)(ws + alloc((size_t)NX*HD*2));            // 34 MB, later actw1
  u16*  Wdb    = (u16*)(ws + alloc((size_t)HD*FD*2));            // 33.5 MB
  u16*  CG     = (u16*)(ws + alloc((size_t)TT*NX*2));            // 34 MB, later aliased as abar [TT][F]
  u16*  CU     = (u16*)(ws + alloc((size_t)TT*NX*2));            // 34 MB
  float* cC    = (float*)(ws + alloc((size_t)(TT+1)*2*16*4));
  int*  sel    = (int*)(ws + alloc((size_t)TT*2*4));
  int*  count  = (int*)(ws + alloc(256));
  int*  listTok= (int*)(ws + alloc((size_t)NE*TT*4));
  float* listW = (float*)(ws + alloc((size_t)NE*TT*4));
  u16*  abar   = CG;   // alias: CG is dead after expert_kernel; total ws ~179 MB

  hipMemsetAsync(count, 0, NE*sizeof(int), stream);

  // bf16 casts (Ag/Au rows appended onto Wg/Wu -> N = 8320)
  cast_kernel<<<2048, 256, 0, stream>>>(h,  hb,  (long)TT*HD);
  cast_kernel<<<4096, 256, 0, stream>>>(Wg, Bgx, (long)FD*HD);
  cast_kernel<<<128,  256, 0, stream>>>(Ag, Bgx + (size_t)FD*HD, (long)NE*NR*HD);
  cast_kernel<<<4096, 256, 0, stream>>>(Wu, Bux, (long)FD*HD);
  cast_kernel<<<128,  256, 0, stream>>>(Au, Bux + (size_t)FD*HD, (long)NE*NR*HD);
  cast_kernel<<<4096, 256, 0, stream>>>(Wd, Wdb, (long)HD*FD);

  router_kernel<<<TT, 64, 0, stream>>>(h, gw, sel, count, listTok, listW);

  // CG = h @ [Wg;Ag]^T , CU = h @ [Wu;Au]^T   (M=2048, N=8320, K=2048)
  gemm128<0><<<dim3(16, 65), 256, 0, stream>>>(hb, Bgx, CG, TT, NX, HD, NX, nullptr, nullptr, nullptr);
  gemm128<0><<<dim3(16, 65), 256, 0, stream>>>(hb, Bux, CU, TT, NX, HD, NX, nullptr, nullptr, nullptr);

  // per-expert: deltas, act, weighted act into slot buffers (aliasing Bgx/Bux), c coefs
  expert_kernel<<<dim3(128, NE), 256, 0, stream>>>(CG, CU, Bg, Bu, Ad, count, listTok, listW,
                                                   Bgx /*actw0*/, Bux /*actw1*/, cC);

  // abar = actw0 + actw1 (writes into the dead CG region)
  combine_kernel<<<2048, 256, 0, stream>>>(Bgx, Bux, abar, (long)TT*FD);

  // out = abar @ Wd^T + down-lora   (M=2048, N=2048, K=8192)
  gemm128<1><<<dim3(16, 16), 256, 0, stream>>>(abar, Wdb, d_out, TT, HD, FD, HD, cC, sel, Bd);
}

// Round 3
// 653.891 us; speedup vs baseline: 1.0983x; 1.0983x over previous
//
#include <hip/hip_runtime.h>
#include <hip/hip_bf16.h>

typedef __attribute__((ext_vector_type(8))) short v8s;   // 8 x bf16 (as i16)
typedef __attribute__((ext_vector_type(4))) float v4f;
typedef unsigned short u16;

static constexpr int TT = 2048;        // tokens
static constexpr int HD = 2048;        // hidden
static constexpr int FD = 8192;        // ffn dim
static constexpr int NE = 8;           // experts
static constexpr int NR = 16;          // lora rank
static constexpr int NX = FD + NE*NR;  // 8320 = 65*128 (ext N for gate/up GEMM)
static constexpr int KX = FD + NE*NR;  // 8448? no: ext K for down GEMM = 8192+256
static constexpr int KXD = FD + 256;   // 8448 = 132*64 (ext K for down GEMM)

// ---------- helpers ----------
__device__ __forceinline__ u16 f2b(float f) {            // fp32 -> bf16 RNE
  union { float f; unsigned u; } v; v.f = f;
  unsigned r = v.u + 0x7FFFu + ((v.u >> 16) & 1u);
  return (u16)(r >> 16);
}
__device__ __forceinline__ float b2f(u16 h) {
  union { unsigned u; float f; } v; v.u = ((unsigned)h) << 16;
  return v.f;
}
__device__ __forceinline__ v8s pack8(v4f a, v4f b) {
  v8s r;
  r[0]=(short)f2b(a.x); r[1]=(short)f2b(a.y); r[2]=(short)f2b(a.z); r[3]=(short)f2b(a.w);
  r[4]=(short)f2b(b.x); r[5]=(short)f2b(b.y); r[6]=(short)f2b(b.z); r[7]=(short)f2b(b.w);
  return r;
}
__device__ __forceinline__ void gload_lds16(const void* g, void* l) {
  __builtin_amdgcn_global_load_lds(
      (const __attribute__((address_space(1))) unsigned int*)g,
      (__attribute__((address_space(3))) unsigned int*)l, 16, 0, 0);
}

// ---------- cast fp32 -> bf16 (contiguous) ----------
__global__ __launch_bounds__(256)
void cast_kernel(const float* __restrict__ src, u16* __restrict__ dst, long n) {
  long stride = (long)gridDim.x * 256 * 8;
  for (long i = ((long)blockIdx.x * 256 + threadIdx.x) * 8; i < n; i += stride) {
    v4f a = *(const v4f*)(src + i);
    v4f b = *(const v4f*)(src + i + 4);
    *(v8s*)(dst + i) = pack8(a, b);
  }
}

// ---------- cast fp32 -> bf16 with dst leading-dim (Wd into Wdx[HD][KXD]) ----------
__global__ __launch_bounds__(256)
void cast_ld_kernel(const float* __restrict__ src, u16* __restrict__ dst,
                    int rows, int cols, int dld) {
  long total = (long)rows * (cols / 8);
  long stride = (long)gridDim.x * 256;
  for (long idx = (long)blockIdx.x * 256 + threadIdx.x; idx < total; idx += stride) {
    long r = idx / (cols / 8);
    int c8 = (int)(idx % (cols / 8)) * 8;
    v4f a = *(const v4f*)(src + r * cols + c8);
    v4f b = *(const v4f*)(src + r * cols + c8 + 4);
    *(v8s*)(dst + r * dld + c8) = pack8(a, b);
  }
}

// ---------- Bd[E][H][16] -> ext cols of Wdx[h][FD + e*16 + r] ----------
__global__ __launch_bounds__(256)
void bdext_kernel(const float* __restrict__ Bd, u16* __restrict__ Wdx) {
  int idx = blockIdx.x * 256 + threadIdx.x;          // total HD*128 = 262144
  int hrow = idx >> 7, c = idx & 127;
  int e = c >> 4, r = c & 15;
  float v = Bd[((size_t)e * HD + hrow) * 16 + r];
  Wdx[(size_t)hrow * KXD + FD + c] = f2b(v);
}

// ---------- router + gather ----------
__global__ __launch_bounds__(64)
void router_kernel(const float* __restrict__ h, const float* __restrict__ gw,
                   int* __restrict__ sel, int* __restrict__ count,
                   int* __restrict__ listTok, float* __restrict__ listW) {
  int t = blockIdx.x, lane = threadIdx.x;
  const float* hp = h + (size_t)t * HD;
  float acc[8] = {0,0,0,0,0,0,0,0};
  for (int i = lane; i < HD; i += 64) {
    float hv = hp[i];
    #pragma unroll
    for (int e = 0; e < 8; ++e) acc[e] += hv * gw[e*HD + i];
  }
  #pragma unroll
  for (int off = 32; off > 0; off >>= 1) {
    #pragma unroll
    for (int e = 0; e < 8; ++e) acc[e] += __shfl_xor(acc[e], off, 64);
  }
  if (lane == 0) {
    int e0 = -1, e1 = -1; float b0 = -1e30f, b1 = -1e30f;
    #pragma unroll
    for (int e = 0; e < 8; ++e) {
      float v = acc[e];
      if (v > b0) { b1 = b0; e1 = e0; b0 = v; e0 = e; }
      else if (v > b1) { b1 = v; e1 = e; }
    }
    float p1 = __expf(b1 - b0);            // p0 = 1
    float w0 = 1.f / (1.f + p1);
    float w1 = p1 * w0;
    sel[2*t] = e0; sel[2*t+1] = e1;
    int pos0 = atomicAdd(&count[e0], 1);
    listTok[e0*TT + pos0] = t;           listW[e0*TT + pos0] = w0;
    int pos1 = atomicAdd(&count[e1], 1);
    listTok[e1*TT + pos1] = t | (1<<20); listW[e1*TT + pos1] = w1;
  }
}

// ---------- 128x128x64 bf16 GEMM (m97 structure), C = A @ B^T ----------
// grid: (mtiles, ntiles, splitk); XCD-swizzled (requires mtiles*ntiles % 8 == 0).
// MODE 0: store bf16 C. MODE 2: fp32 atomicAdd into C (C pre-zeroed).
template<int MODE>
__global__ __launch_bounds__(256)
void gemm128(const u16* __restrict__ A, const u16* __restrict__ B, void* __restrict__ Cout,
             int K, int ldc) {
  __shared__ u16 As[128*64];
  __shared__ u16 Bs[128*64];
  const int tid  = threadIdx.x;
  const int lane = tid & 63, wid = tid >> 6;
  // bijective XCD swizzle (nwg % 8 == 0 by launch construction)
  const int gx = gridDim.x;
  const int lin = blockIdx.y * gx + blockIdx.x;
  const int chunk = (gx * gridDim.y) >> 3;
  const int wg = (lin & 7) * chunk + (lin >> 3);
  const int m0 = (wg % gx) * 128, n0 = (wg / gx) * 128;
  const int kc = K / gridDim.z;
  const int kbeg = blockIdx.z * kc;
  const int wr = wid >> 1, wc = wid & 1;                 // 2x2 waves of 64x64
  const int lrow = lane >> 3, lcol = (lane & 7) * 8;
  v4f acc[4][4];
  #pragma unroll
  for (int mi = 0; mi < 4; ++mi)
    #pragma unroll
    for (int ni = 0; ni < 4; ++ni) acc[mi][ni] = (v4f){0.f,0.f,0.f,0.f};

  for (int k0 = kbeg; k0 < kbeg + kc; k0 += 64) {
    #pragma unroll
    for (int it = 0; it < 4; ++it) {
      int seg = wid*4 + it;                 // 0..15, uniform per wave
      int row = seg*8 + lrow;               // 0..127
      gload_lds16(A + (size_t)(m0+row)*K + k0 + lcol, As + seg*512);
      gload_lds16(B + (size_t)(n0+row)*K + k0 + lcol, Bs + seg*512);
    }
    __syncthreads();
    #pragma unroll
    for (int kk = 0; kk < 64; kk += 32) {
      v8s af[4], bfr[4];
      #pragma unroll
      for (int mi = 0; mi < 4; ++mi)
        af[mi] = *(const v8s*)(As + (wr*64 + mi*16 + (lane&15))*64 + kk + (lane>>4)*8);
      #pragma unroll
      for (int ni = 0; ni < 4; ++ni)
        bfr[ni] = *(const v8s*)(Bs + (wc*64 + ni*16 + (lane&15))*64 + kk + (lane>>4)*8);
      #pragma unroll
      for (int mi = 0; mi < 4; ++mi)
        #pragma unroll
        for (int ni = 0; ni < 4; ++ni)
          acc[mi][ni] = __builtin_amdgcn_mfma_f32_16x16x32_bf16(af[mi], bfr[ni], acc[mi][ni], 0, 0, 0);
    }
    __syncthreads();
  }

  if (MODE == 0) {
    u16* C = (u16*)Cout;
    #pragma unroll
    for (int mi = 0; mi < 4; ++mi)
      #pragma unroll
      for (int j = 0; j < 4; ++j) {
        int row = m0 + wr*64 + mi*16 + (lane>>4)*4 + j;
        size_t base = (size_t)row*ldc + n0 + wc*64 + (lane&15);
        #pragma unroll
        for (int ni = 0; ni < 4; ++ni)
          C[base + ni*16] = f2b(acc[mi][ni][j]);
      }
  } else {
    float* C = (float*)Cout;
    #pragma unroll
    for (int mi = 0; mi < 4; ++mi)
      #pragma unroll
      for (int j = 0; j < 4; ++j) {
        int row = m0 + wr*64 + mi*16 + (lane>>4)*4 + j;
        size_t base = (size_t)row*ldc + n0 + wc*64 + (lane&15);
        #pragma unroll
        for (int ni = 0; ni < 4; ++ni)
          atomicAdd(&C[base + ni*16], acc[mi][ni][j]);
      }
  }
}

// ---------- expert kernel ----------
// grid (128 groups, NE, 4 f-blocks). Per block: 16 tokens x 2048 f-cols.
// Computes rank-16 gate/up deltas, silu*u, weighted act into slot buffers,
// and partial c = 2w*(act@Ad^T) atomically accumulated into cC (pre-zeroed).
static constexpr int HA_LD = 40;   // padded LDS strides (16B-aligned)
static constexpr int BG_LD = 40;
static constexpr int AW_LD = 72;
static constexpr int CT_LD = 72;

__global__ __launch_bounds__(256)
void expert_kernel(const u16* __restrict__ cgE, const u16* __restrict__ cuE,   // [TT][NX]
                   const float* __restrict__ Bg, const float* __restrict__ Bu, // [E][F][16]
                   const float* __restrict__ Ad,                               // [E][16][F]
                   const int* __restrict__ count, const int* __restrict__ listTok,
                   const float* __restrict__ listW,
                   u16* __restrict__ actw0, u16* __restrict__ actw1,           // [TT+1][F]
                   float* __restrict__ cC) {                                   // [TT+1][2][16]
  const int e = blockIdx.y, g = blockIdx.x, fb = blockIdx.z;
  const int n = count[e];
  if (g*16 >= n) return;
  const int tid = threadIdx.x, lane = tid & 63, w = tid >> 6;
  __shared__ u16 hAg[16*HA_LD], hAu[16*HA_LD];
  __shared__ u16 BS[4][64*BG_LD];                 // time-shared Bg then Bu
  __shared__ u16 AWs[4][16*AW_LD];
  __shared__ u16 cgT[4][16*CT_LD], cuT[4][16*CT_LD];
  __shared__ int sTok[16], sSlot[16];
  __shared__ float sW[16];
  __shared__ float dAred[4][256];

  if (tid < 16) {
    int idx = g*16 + tid;
    if (idx < n) {
      int ent = listTok[e*TT + idx];
      sTok[tid] = ent & 0xFFFF; sSlot[tid] = (ent >> 20) & 1; sW[tid] = listW[e*TT + idx];
    } else { sTok[tid] = TT; sSlot[tid] = 0; sW[tid] = 0.f; }  // dummy -> dump row TT
  }
  __syncthreads();
  if (tid < 128) {   // stage hA (both tensors), zero-pad K 16..31
    int tensor = tid >> 6;
    int sub = tid & 63;
    int row = sub >> 2, c8 = (sub & 3) * 8;
    int trd = min(sTok[row], TT - 1);
    u16 vals[8];
    if (c8 < 16) {
      const u16* src = (tensor ? cuE : cgE) + (size_t)trd*NX + FD + e*NR + c8;
      #pragma unroll
      for (int q = 0; q < 8; ++q) vals[q] = src[q];
    } else {
      #pragma unroll
      for (int q = 0; q < 8; ++q) vals[q] = 0;
    }
    u16* dst = (tensor ? hAu : hAg) + row*HA_LD + c8;
    #pragma unroll
    for (int q = 0; q < 8; ++q) dst[q] = vals[q];
  }
  __syncthreads();

  int tR[4], slR[4]; float wR[4];
  #pragma unroll
  for (int j = 0; j < 4; ++j) {
    int r = (lane>>4)*4 + j;
    tR[j] = sTok[r]; slR[j] = sSlot[r]; wR[j] = sW[r];
  }
  v8s afg = *(const v8s*)(hAg + (lane&15)*HA_LD + (lane>>4)*8);
  v8s afu = *(const v8s*)(hAu + (lane&15)*HA_LD + (lane>>4)*8);
  v4f accDA = (v4f){0.f,0.f,0.f,0.f};
  u16* bsw = BS[w]; u16* aww = AWs[w]; u16* cgw = cgT[w]; u16* cuw = cuT[w];

  { // zero K=16..31 pad of B-staging once (wave-private region)
    v8s z = {0,0,0,0,0,0,0,0};
    *(v8s*)(bsw + lane*BG_LD + 16) = z; *(v8s*)(bsw + lane*BG_LD + 24) = z;
  }

  const int ch_end = fb*32 + 32;
  for (int ch = fb*32 + w; ch < ch_end; ch += 4) {   // 64-wide f-chunks, wave-private
    int f0 = ch * 64;
    { // stage common gate/up tile [16 tok][64 f] into LDS (v8s coalesced)
      int srow = lane >> 3, c8 = (lane & 7) * 8;
      #pragma unroll
      for (int rr = 0; rr < 2; ++rr) {
        int row = srow + rr*8;
        size_t trd = (size_t)min(sTok[row], TT - 1);
        *(v8s*)(cgw + row*CT_LD + c8) = *(const v8s*)(cgE + trd*NX + f0 + c8);
        *(v8s*)(cuw + row*CT_LD + c8) = *(const v8s*)(cuE + trd*NX + f0 + c8);
      }
    }
    v4f dg[4], du[4];
    { // stage Bg rows (lane = f-row) then MFMA
      const float* gp = Bg + ((size_t)e*FD + f0 + lane)*16;
      v4f q0 = *(const v4f*)gp, q1 = *(const v4f*)(gp+4), q2 = *(const v4f*)(gp+8), q3 = *(const v4f*)(gp+12);
      *(v8s*)(bsw + lane*BG_LD)     = pack8(q0, q1);
      *(v8s*)(bsw + lane*BG_LD + 8) = pack8(q2, q3);
      #pragma unroll
      for (int nf = 0; nf < 4; ++nf) {
        v8s bgf = *(const v8s*)(bsw + (nf*16 + (lane&15))*BG_LD + (lane>>4)*8);
        dg[nf] = __builtin_amdgcn_mfma_f32_16x16x32_bf16(afg, bgf, (v4f){0.f,0.f,0.f,0.f}, 0, 0, 0);
      }
    }
    { // stage Bu rows into the SAME wave-private buffer, then MFMA
      const float* up = Bu + ((size_t)e*FD + f0 + lane)*16;
      v4f r0 = *(const v4f*)up, r1 = *(const v4f*)(up+4), r2 = *(const v4f*)(up+8), r3 = *(const v4f*)(up+12);
      *(v8s*)(bsw + lane*BG_LD)     = pack8(r0, r1);
      *(v8s*)(bsw + lane*BG_LD + 8) = pack8(r2, r3);
      #pragma unroll
      for (int nf = 0; nf < 4; ++nf) {
        v8s buf = *(const v8s*)(bsw + (nf*16 + (lane&15))*BG_LD + (lane>>4)*8);
        du[nf] = __builtin_amdgcn_mfma_f32_16x16x32_bf16(afu, buf, (v4f){0.f,0.f,0.f,0.f}, 0, 0, 0);
      }
    }
    #pragma unroll
    for (int nf = 0; nf < 4; ++nf) {
      #pragma unroll
      for (int j = 0; j < 4; ++j) {
        int rj = (lane>>4)*4 + j;
        int fi = nf*16 + (lane&15);
        float cgv = b2f(cgw[rj*CT_LD + fi]);
        float cuv = b2f(cuw[rj*CT_LD + fi]);
        float gv = cgv + 2.f * dg[nf][j];
        float uv = cuv + 2.f * du[nf][j];
        float a  = gv / (1.f + __expf(-gv)) * uv;   // silu(g)*u
        u16 ab = f2b(wR[j] * a);
        (slR[j] ? actw1 : actw0)[(size_t)tR[j]*FD + f0 + fi] = ab;
        aww[rj*AW_LD + fi] = ab;
      }
    }
    #pragma unroll
    for (int ks = 0; ks < 2; ++ks) {   // dA accumulate: [16 tok] x [16 r] over K=64
      v8s aA = *(const v8s*)(aww + (lane&15)*AW_LD + ks*32 + (lane>>4)*8);
      const float* ap = Ad + ((size_t)e*16 + (lane&15))*FD + f0 + ks*32 + (lane>>4)*8;
      v4f q0 = *(const v4f*)ap, q1 = *(const v4f*)(ap+4);
      v8s bA = pack8(q0, q1);
      accDA = __builtin_amdgcn_mfma_f32_16x16x32_bf16(aA, bA, accDA, 0, 0, 0);
    }
  }
  #pragma unroll
  for (int j = 0; j < 4; ++j)
    dAred[w][((lane>>4)*4 + j)*16 + (lane&15)] = accDA[j];
  __syncthreads();
  {
    int row = tid >> 4, col = tid & 15;
    float s2 = dAred[0][row*16+col] + dAred[1][row*16+col] + dAred[2][row*16+col] + dAred[3][row*16+col];
    atomicAdd(&cC[((size_t)sTok[row]*2 + sSlot[row])*16 + col], 2.f * s2);  // LORA_SCALING folded
  }
}

// ---------- combine: abar_ext[t] = [actw0+actw1 (bf16), scattered c coefs] ----------
__global__ __launch_bounds__(256)
void combine2_kernel(const u16* __restrict__ a0, const u16* __restrict__ a1,
                     const float* __restrict__ cC, const int* __restrict__ sel,
                     u16* __restrict__ abx) {
  int t = blockIdx.x, tid = threadIdx.x;
  const u16* p0 = a0 + (size_t)t * FD;
  const u16* p1 = a1 + (size_t)t * FD;
  u16* po = abx + (size_t)t * KXD;
  for (int i = tid * 8; i < FD; i += 256 * 8) {
    v8s x = *(const v8s*)(p0 + i);
    v8s y = *(const v8s*)(p1 + i);
    v8s o;
    #pragma unroll
    for (int j = 0; j < 8; ++j) o[j] = (short)f2b(b2f((u16)x[j]) + b2f((u16)y[j]));
    *(v8s*)(po + i) = o;
  }
  if (tid < 128) {   // ext cols: c[t, e, r] scattered at FD + e*16 + r
    int e_i = tid >> 4, r = tid & 15;
    float v = 0.f;
    if (sel[2*t]     == e_i) v += cC[((size_t)t*2 + 0)*16 + r];
    if (sel[2*t + 1] == e_i) v += cC[((size_t)t*2 + 1)*16 + r];
    po[FD + tid] = f2b(v);
  }
}

// ---------- launch ----------
extern "C" void kernel_launch(void* const* d_in, const int* in_sizes, int n_in,
                              void* d_out, int out_size, void* d_ws, size_t ws_size,
                              hipStream_t stream) {
  (void)in_sizes; (void)n_in; (void)out_size; (void)ws_size;
  const float* h  = (const float*)d_in[0];
  const float* gw = (const float*)d_in[1];
  const float* Wg = (const float*)d_in[2];
  const float* Wu = (const float*)d_in[3];
  const float* Wd = (const float*)d_in[4];
  const float* Ag = (const float*)d_in[5];
  const float* Bg = (const float*)d_in[6];
  const float* Au = (const float*)d_in[7];
  const float* Bu = (const float*)d_in[8];
  const float* Ad = (const float*)d_in[9];
  const float* Bd = (const float*)d_in[10];

  char* ws = (char*)d_ws;
  size_t off = 0;
  auto alloc = [&](size_t bytes) { size_t c = off; off += (bytes + 255) & ~(size_t)255; return c; };
  u16*  hb     = (u16*)(ws + alloc((size_t)TT*HD*2));             // 8 MB
  u16*  Bgx    = (u16*)(ws + alloc((size_t)NX*HD*2));             // 34 MB; later actw0 [TT+1][F]
  u16*  Bux    = (u16*)(ws + alloc((size_t)NX*HD*2));             // 34 MB; later actw1
  u16*  Wdx    = (u16*)(ws + alloc((size_t)HD*KXD*2));            // 34.6 MB  [HD][KXD]
  u16*  CG     = (u16*)(ws + alloc((size_t)TT*KXD*2));            // 34.6 MB; later abar_ext [TT][KXD]
  u16*  CU     = (u16*)(ws + alloc((size_t)TT*NX*2));             // 34 MB
  float* cC    = (float*)(ws + alloc((size_t)(TT+1)*2*16*4));
  int*  sel    = (int*)(ws + alloc((size_t)TT*2*4));
  int*  count  = (int*)(ws + alloc(256));
  int*  listTok= (int*)(ws + alloc((size_t)NE*TT*4));
  float* listW = (float*)(ws + alloc((size_t)NE*TT*4));
  u16*  abx    = CG;   // alias: CG dead after expert_kernel

  hipMemsetAsync(count, 0, NE*sizeof(int), stream);
  hipMemsetAsync(cC, 0, (size_t)(TT+1)*2*16*4, stream);
  hipMemsetAsync(d_out, 0, (size_t)TT*HD*4, stream);

  // bf16 casts (Ag/Au rows appended onto Wg/Wu -> N = 8320)
  cast_kernel<<<2048, 256, 0, stream>>>(h,  hb,  (long)TT*HD);
  cast_kernel<<<4096, 256, 0, stream>>>(Wg, Bgx, (long)FD*HD);
  cast_kernel<<<128,  256, 0, stream>>>(Ag, Bgx + (size_t)FD*HD, (long)NE*NR*HD);
  cast_kernel<<<4096, 256, 0, stream>>>(Wu, Bux, (long)FD*HD);
  cast_kernel<<<128,  256, 0, stream>>>(Au, Bux + (size_t)FD*HD, (long)NE*NR*HD);
  cast_ld_kernel<<<4096, 256, 0, stream>>>(Wd, Wdx, HD, FD, KXD);
  bdext_kernel<<<1024, 256, 0, stream>>>(Bd, Wdx);

  router_kernel<<<TT, 64, 0, stream>>>(h, gw, sel, count, listTok, listW);

  // CG = h @ [Wg;Ag]^T , CU = h @ [Wu;Au]^T   (M=2048, N=8320, K=2048)
  gemm128<0><<<dim3(16, 65, 1), 256, 0, stream>>>(hb, Bgx, CG, HD, NX);
  gemm128<0><<<dim3(16, 65, 1), 256, 0, stream>>>(hb, Bux, CU, HD, NX);

  // per-expert: deltas, act, weighted act into slot buffers (aliasing Bgx/Bux), c coefs
  expert_kernel<<<dim3(128, NE, 4), 256, 0, stream>>>(CG, CU, Bg, Bu, Ad, count, listTok, listW,
                                                      Bgx /*actw0*/, Bux /*actw1*/, cC);

  // abar_ext = [actw0+actw1, c-scatter]  (writes into the dead CG region)
  combine2_kernel<<<TT, 256, 0, stream>>>(Bgx, Bux, cC, sel, abx);

  // out = abar_ext @ Wdx^T  (M=2048, N=2048, K=8448, split-K=4, fp32 atomicAdd)
  gemm128<2><<<dim3(16, 16, 4), 256, 0, stream>>>(abx, Wdx, d_out, KXD, HD);
}

// Round 4
// 564.024 us; speedup vs baseline: 1.2733x; 1.1593x over previous
//
#include <hip/hip_runtime.h>
#include <hip/hip_bf16.h>

typedef __attribute__((ext_vector_type(8))) short v8s;   // 8 x bf16 (as i16)
typedef __attribute__((ext_vector_type(4))) float v4f;
typedef unsigned short u16;

static constexpr int TT = 2048;        // tokens
static constexpr int HD = 2048;        // hidden
static constexpr int FD = 8192;        // ffn dim
static constexpr int NE = 8;           // experts
static constexpr int NR = 16;          // lora rank
static constexpr int NX2 = 2*FD + 2*NE*NR;  // 16640 = 65*256: [Wg | Ag | Wu | Au] cols
static constexpr int KXD = FD + 256;   // 8448 ext K for down GEMM (132*64; 22*64*6)

// col offsets inside the merged gate/up output CGU[t][NX2]
static constexpr int C_G  = 0;         // gate common [0,8192)
static constexpr int C_GA = 8192;      // gate hA     [8192,8320)
static constexpr int C_U  = 8320;      // up common   [8320,16512)
static constexpr int C_UA = 16512;     // up hA       [16512,16640)

// ---------- helpers ----------
__device__ __forceinline__ u16 f2b(float f) {            // fp32 -> bf16 RNE
  union { float f; unsigned u; } v; v.f = f;
  unsigned r = v.u + 0x7FFFu + ((v.u >> 16) & 1u);
  return (u16)(r >> 16);
}
__device__ __forceinline__ float b2f(u16 h) {
  union { unsigned u; float f; } v; v.u = ((unsigned)h) << 16;
  return v.f;
}
__device__ __forceinline__ v8s pack8(v4f a, v4f b) {
  v8s r;
  r[0]=(short)f2b(a.x); r[1]=(short)f2b(a.y); r[2]=(short)f2b(a.z); r[3]=(short)f2b(a.w);
  r[4]=(short)f2b(b.x); r[5]=(short)f2b(b.y); r[6]=(short)f2b(b.z); r[7]=(short)f2b(b.w);
  return r;
}
__device__ __forceinline__ void gload_lds16(const void* g, void* l) {
  __builtin_amdgcn_global_load_lds(
      (const __attribute__((address_space(1))) unsigned int*)g,
      (__attribute__((address_space(3))) unsigned int*)l, 16, 0, 0);
}
__device__ __forceinline__ void barrier_pin() {
  __builtin_amdgcn_s_barrier();
  __builtin_amdgcn_sched_barrier(0);
}
__device__ __forceinline__ void vm_wait4() { asm volatile("s_waitcnt vmcnt(4)" ::: "memory"); }
__device__ __forceinline__ void vm_wait0() { asm volatile("s_waitcnt vmcnt(0)" ::: "memory"); }

template<int Q>
__device__ __forceinline__ void mmq(v4f (&acc)[8][4], const v8s (&af)[2][2], const v8s (&bf)[4][2]) {
  __builtin_amdgcn_s_setprio(1);
  #pragma unroll
  for (int m2 = 0; m2 < 2; ++m2)
    #pragma unroll
    for (int nf = 0; nf < 4; ++nf) {
      acc[Q*2+m2][nf] = __builtin_amdgcn_mfma_f32_16x16x32_bf16(af[m2][0], bf[nf][0], acc[Q*2+m2][nf], 0, 0, 0);
      acc[Q*2+m2][nf] = __builtin_amdgcn_mfma_f32_16x16x32_bf16(af[m2][1], bf[nf][1], acc[Q*2+m2][nf], 0, 0, 0);
    }
  __builtin_amdgcn_s_setprio(0);
}

// ---------- cast fp32 -> bf16 (contiguous) ----------
__global__ __launch_bounds__(256)
void cast_kernel(const float* __restrict__ src, u16* __restrict__ dst, long n) {
  long stride = (long)gridDim.x * 256 * 8;
  for (long i = ((long)blockIdx.x * 256 + threadIdx.x) * 8; i < n; i += stride) {
    v4f a = *(const v4f*)(src + i);
    v4f b = *(const v4f*)(src + i + 4);
    *(v8s*)(dst + i) = pack8(a, b);
  }
}

// ---------- cast fp32 -> bf16 with dst leading-dim (Wd into Wdx[HD][KXD]) ----------
__global__ __launch_bounds__(256)
void cast_ld_kernel(const float* __restrict__ src, u16* __restrict__ dst,
                    int rows, int cols, int dld) {
  long total = (long)rows * (cols / 8);
  long stride = (long)gridDim.x * 256;
  for (long idx = (long)blockIdx.x * 256 + threadIdx.x; idx < total; idx += stride) {
    long r = idx / (cols / 8);
    int c8 = (int)(idx % (cols / 8)) * 8;
    v4f a = *(const v4f*)(src + r * cols + c8);
    v4f b = *(const v4f*)(src + r * cols + c8 + 4);
    *(v8s*)(dst + r * dld + c8) = pack8(a, b);
  }
}

// ---------- Bd[E][H][16] -> ext cols FD..FD+255 of Wdx (cols >=128 zeroed) ----------
__global__ __launch_bounds__(256)
void bdext_kernel(const float* __restrict__ Bd, u16* __restrict__ Wdx) {
  int idx = blockIdx.x * 256 + threadIdx.x;          // total HD*256
  int hrow = idx >> 8, c = idx & 255;
  float v = 0.f;
  if (c < 128) {
    int e = c >> 4, r = c & 15;
    v = Bd[((size_t)e * HD + hrow) * 16 + r];
  }
  Wdx[(size_t)hrow * KXD + FD + c] = f2b(v);
}

// ---------- router + gather ----------
__global__ __launch_bounds__(64)
void router_kernel(const float* __restrict__ h, const float* __restrict__ gw,
                   int* __restrict__ sel, int* __restrict__ count,
                   int* __restrict__ listTok, float* __restrict__ listW) {
  int t = blockIdx.x, lane = threadIdx.x;
  const float* hp = h + (size_t)t * HD;
  float acc[8] = {0,0,0,0,0,0,0,0};
  for (int i = lane; i < HD; i += 64) {
    float hv = hp[i];
    #pragma unroll
    for (int e = 0; e < 8; ++e) acc[e] += hv * gw[e*HD + i];
  }
  #pragma unroll
  for (int off = 32; off > 0; off >>= 1) {
    #pragma unroll
    for (int e = 0; e < 8; ++e) acc[e] += __shfl_xor(acc[e], off, 64);
  }
  if (lane == 0) {
    int e0 = -1, e1 = -1; float b0 = -1e30f, b1 = -1e30f;
    #pragma unroll
    for (int e = 0; e < 8; ++e) {
      float v = acc[e];
      if (v > b0) { b1 = b0; e1 = e0; b0 = v; e0 = e; }
      else if (v > b1) { b1 = v; e1 = e; }
    }
    float p1 = __expf(b1 - b0);            // p0 = 1
    float w0 = 1.f / (1.f + p1);
    float w1 = p1 * w0;
    sel[2*t] = e0; sel[2*t+1] = e1;
    int pos0 = atomicAdd(&count[e0], 1);
    listTok[e0*TT + pos0] = t;           listW[e0*TT + pos0] = w0;
    int pos1 = atomicAdd(&count[e1], 1);
    listTok[e1*TT + pos1] = t | (1<<20); listW[e1*TT + pos1] = w1;
  }
}

// ---------- 256x256 8-phase bf16 GEMM, C = A @ B^T  (T1+T2+T3+T4+T5) ----------
// 512 threads = 8 waves (2M x 4N); per-wave C: 128x64. LDS 128 KiB:
// lds[slot][A|B][half(128 rows)][128*64 bf16], XOR-swizzled c16 ^= (row&7).
// Per iteration: 2 K-tiles (BK=64), 8 phases; counted vmcnt(4) at phases 3,7.
// Stage schedule (iter i; kt0=2i, kt1=2i+1):
//  p0: A(kt1)h0->s1  p1: A(kt1)h1->s1  p2: B(kt0+2)h0->s0  p3: B(kt0+2)h1->s0 +vm4
//  p4: A(kt0+2)h0->s0  p5: A(kt0+2)h1->s0  p6: B(kt1+2)h0->s1  p7: B(kt1+2)h1->s1 +vm4
// MODE 0: bf16 store. MODE 2: fp32 atomicAdd (split-K; C pre-zeroed).
template<int MODE>
__global__ __launch_bounds__(512, 2)
void gemm256(const u16* __restrict__ A, const u16* __restrict__ B, void* __restrict__ Cout,
             int ldk, int kchunk, int ldc) {
  __shared__ u16 lds[2][2][2][8192];
  const int tid = threadIdx.x, lane = tid & 63, wid = tid >> 6;
  const int gx = gridDim.x;
  const int nwg = gx * gridDim.y;
  const int lin = blockIdx.y * gx + blockIdx.x;
  const int chunk = nwg >> 3;                       // nwg % 8 == 0 by construction
  const int wg = (lin & 7) * chunk + (lin >> 3);    // bijective XCD swizzle
  const int m0 = (wg % gx) * 256, n0 = (wg / gx) * 256;
  const long kbeg = (long)blockIdx.z * kchunk;
  const int NK = kchunk >> 6, NI = NK >> 1;         // NK even
  const int wr = wid >> 2, wc = wid & 3;

  const int s_r = (wid << 4) + (lane >> 3);         // staging row (load 0); +8 for load 1
  const int s_c = lane & 7;                          // linear c16 slot

  auto STAGE = [&](int slot, int ab, int half, const u16* M, int rc0, int kt) {
    const u16* g0 = M + (size_t)(rc0 + half*128 + s_r) * ldk + kbeg + kt*64 + ((s_c ^ (s_r & 7)) << 3);
    gload_lds16(g0, &lds[slot][ab][half][wid << 10]);
    const int r1 = s_r + 8;
    const u16* g1 = M + (size_t)(rc0 + half*128 + r1) * ldk + kbeg + kt*64 + ((s_c ^ (r1 & 7)) << 3);
    gload_lds16(g1, &lds[slot][ab][half][(wid << 10) + 512]);
  };
  auto LDA = [&](int slot, int mf, int c16b) -> v8s {  // A frag: rows in half wr
    int rr = (mf << 4) + (lane & 15);
    return *(const v8s*)&lds[slot][0][wr][rr*64 + (((c16b + (lane >> 4)) ^ (rr & 7)) << 3)];
  };
  auto LDB = [&](int slot, int nf, int c16b) -> v8s {
    int row = (wc << 6) + (nf << 4) + (lane & 15);
    int rr = row & 127;
    return *(const v8s*)&lds[slot][1][row >> 7][rr*64 + (((c16b + (lane >> 4)) ^ (rr & 7)) << 3)];
  };

  v4f acc[8][4];
  #pragma unroll
  for (int mf = 0; mf < 8; ++mf)
    #pragma unroll
    for (int nf = 0; nf < 4; ++nf) acc[mf][nf] = (v4f){0.f,0.f,0.f,0.f};

  // prologue: B(0), A(0), B(1); land B(0)+A(0), keep B(1) in flight
  STAGE(0,1,0,B,n0,0); STAGE(0,1,1,B,n0,0);
  STAGE(0,0,0,A,m0,0); STAGE(0,0,1,A,m0,0);
  STAGE(1,1,0,B,n0,1); STAGE(1,1,1,B,n0,1);
  vm_wait4();
  barrier_pin();

  for (int i = 0; i < NI; ++i) {
    const int kt0 = 2*i, kt1 = kt0 + 1;
    const int kt2c = (kt0 + 2 < NK) ? kt0 + 2 : kt0;   // clamped re-stage keeps vmcnt math uniform
    const bool s45 = (kt0 + 2 < NK), s67 = (kt1 + 2 < NK);
    v8s bf[4][2], af[2][2];
    // ---- phase 0 (slot0, q0)
    #pragma unroll
    for (int nf = 0; nf < 4; ++nf) { bf[nf][0] = LDB(0,nf,0); bf[nf][1] = LDB(0,nf,4); }
    af[0][0]=LDA(0,0,0); af[0][1]=LDA(0,0,4); af[1][0]=LDA(0,1,0); af[1][1]=LDA(0,1,4);
    STAGE(1,0,0,A,m0,kt1);
    barrier_pin(); mmq<0>(acc,af,bf); barrier_pin();
    // ---- phase 1 (slot0, q1)
    af[0][0]=LDA(0,2,0); af[0][1]=LDA(0,2,4); af[1][0]=LDA(0,3,0); af[1][1]=LDA(0,3,4);
    STAGE(1,0,1,A,m0,kt1);
    barrier_pin(); mmq<1>(acc,af,bf); barrier_pin();
    // ---- phase 2 (slot0, q2)
    af[0][0]=LDA(0,4,0); af[0][1]=LDA(0,4,4); af[1][0]=LDA(0,5,0); af[1][1]=LDA(0,5,4);
    STAGE(0,1,0,B,n0,kt2c);
    barrier_pin(); mmq<2>(acc,af,bf); barrier_pin();
    // ---- phase 3 (slot0, q3)
    af[0][0]=LDA(0,6,0); af[0][1]=LDA(0,6,4); af[1][0]=LDA(0,7,0); af[1][1]=LDA(0,7,4);
    STAGE(0,1,1,B,n0,kt2c);
    vm_wait4();
    barrier_pin(); mmq<3>(acc,af,bf); barrier_pin();
    // ---- phase 4 (slot1, q0)
    #pragma unroll
    for (int nf = 0; nf < 4; ++nf) { bf[nf][0] = LDB(1,nf,0); bf[nf][1] = LDB(1,nf,4); }
    af[0][0]=LDA(1,0,0); af[0][1]=LDA(1,0,4); af[1][0]=LDA(1,1,0); af[1][1]=LDA(1,1,4);
    if (s45) STAGE(0,0,0,A,m0,kt0+2);
    barrier_pin(); mmq<0>(acc,af,bf); barrier_pin();
    // ---- phase 5 (slot1, q1)
    af[0][0]=LDA(1,2,0); af[0][1]=LDA(1,2,4); af[1][0]=LDA(1,3,0); af[1][1]=LDA(1,3,4);
    if (s45) STAGE(0,0,1,A,m0,kt0+2);
    barrier_pin(); mmq<1>(acc,af,bf); barrier_pin();
    // ---- phase 6 (slot1, q2)
    af[0][0]=LDA(1,4,0); af[0][1]=LDA(1,4,4); af[1][0]=LDA(1,5,0); af[1][1]=LDA(1,5,4);
    if (s67) STAGE(1,1,0,B,n0,kt1+2);
    barrier_pin(); mmq<2>(acc,af,bf); barrier_pin();
    // ---- phase 7 (slot1, q3)
    af[0][0]=LDA(1,6,0); af[0][1]=LDA(1,6,4); af[1][0]=LDA(1,7,0); af[1][1]=LDA(1,7,4);
    if (s67) STAGE(1,1,1,B,n0,kt1+2);
    vm_wait4();
    barrier_pin(); mmq<3>(acc,af,bf); barrier_pin();
  }
  vm_wait0();   // drain (protects LDS of the next workgroup)

  if (MODE == 0) {
    u16* C = (u16*)Cout;
    #pragma unroll
    for (int mf = 0; mf < 8; ++mf)
      #pragma unroll
      for (int j = 0; j < 4; ++j) {
        int row = m0 + wr*128 + mf*16 + (lane>>4)*4 + j;
        size_t base = (size_t)row*ldc + n0 + wc*64 + (lane&15);
        #pragma unroll
        for (int nf = 0; nf < 4; ++nf)
          C[base + nf*16] = f2b(acc[mf][nf][j]);
      }
  } else {
    float* C = (float*)Cout;
    #pragma unroll
    for (int mf = 0; mf < 8; ++mf)
      #pragma unroll
      for (int j = 0; j < 4; ++j) {
        int row = m0 + wr*128 + mf*16 + (lane>>4)*4 + j;
        size_t base = (size_t)row*ldc + n0 + wc*64 + (lane&15);
        #pragma unroll
        for (int nf = 0; nf < 4; ++nf)
          atomicAdd(&C[base + nf*16], acc[mf][nf][j]);
      }
  }
}

// ---------- expert kernel ----------
// grid (128 groups, NE, 4 f-blocks). Per block: 16 tokens x 2048 f-cols.
static constexpr int HA_LD = 40;   // padded LDS strides (16B-aligned)
static constexpr int BG_LD = 40;
static constexpr int AW_LD = 72;
static constexpr int CT_LD = 72;

__global__ __launch_bounds__(256)
void expert_kernel(const u16* __restrict__ CGU,                                // [TT][NX2]
                   const float* __restrict__ Bg, const float* __restrict__ Bu, // [E][F][16]
                   const float* __restrict__ Ad,                               // [E][16][F]
                   const int* __restrict__ count, const int* __restrict__ listTok,
                   const float* __restrict__ listW,
                   u16* __restrict__ actw0, u16* __restrict__ actw1,           // [TT+1][F]
                   float* __restrict__ cC) {                                   // [TT+1][2][16]
  const int e = blockIdx.y, g = blockIdx.x, fb = blockIdx.z;
  const int n = count[e];
  if (g*16 >= n) return;
  const int tid = threadIdx.x, lane = tid & 63, w = tid >> 6;
  __shared__ u16 hAg[16*HA_LD], hAu[16*HA_LD];
  __shared__ u16 BS[4][64*BG_LD];                 // time-shared Bg then Bu
  __shared__ u16 AWs[4][16*AW_LD];
  __shared__ u16 cgT[4][16*CT_LD], cuT[4][16*CT_LD];
  __shared__ int sTok[16], sSlot[16];
  __shared__ float sW[16];
  __shared__ float dAred[4][256];

  if (tid < 16) {
    int idx = g*16 + tid;
    if (idx < n) {
      int ent = listTok[e*TT + idx];
      sTok[tid] = ent & 0xFFFF; sSlot[tid] = (ent >> 20) & 1; sW[tid] = listW[e*TT + idx];
    } else { sTok[tid] = TT; sSlot[tid] = 0; sW[tid] = 0.f; }  // dummy -> dump row TT
  }
  __syncthreads();
  if (tid < 128) {   // stage hA (both tensors), zero-pad K 16..31
    int tensor = tid >> 6;
    int sub = tid & 63;
    int row = sub >> 2, c8 = (sub & 3) * 8;
    int trd = min(sTok[row], TT - 1);
    u16 vals[8];
    if (c8 < 16) {
      const u16* src = CGU + (size_t)trd*NX2 + (tensor ? C_UA : C_GA) + e*NR + c8;
      #pragma unroll
      for (int q = 0; q < 8; ++q) vals[q] = src[q];
    } else {
      #pragma unroll
      for (int q = 0; q < 8; ++q) vals[q] = 0;
    }
    u16* dst = (tensor ? hAu : hAg) + row*HA_LD + c8;
    #pragma unroll
    for (int q = 0; q < 8; ++q) dst[q] = vals[q];
  }
  __syncthreads();

  int tR[4], slR[4]; float wR[4];
  #pragma unroll
  for (int j = 0; j < 4; ++j) {
    int r = (lane>>4)*4 + j;
    tR[j] = sTok[r]; slR[j] = sSlot[r]; wR[j] = sW[r];
  }
  v8s afg = *(const v8s*)(hAg + (lane&15)*HA_LD + (lane>>4)*8);
  v8s afu = *(const v8s*)(hAu + (lane&15)*HA_LD + (lane>>4)*8);
  v4f accDA = (v4f){0.f,0.f,0.f,0.f};
  u16* bsw = BS[w]; u16* aww = AWs[w]; u16* cgw = cgT[w]; u16* cuw = cuT[w];

  { // zero K=16..31 pad of B-staging once (wave-private region)
    v8s z = {0,0,0,0,0,0,0,0};
    *(v8s*)(bsw + lane*BG_LD + 16) = z; *(v8s*)(bsw + lane*BG_LD + 24) = z;
  }

  const int ch_end = fb*32 + 32;
  for (int ch = fb*32 + w; ch < ch_end; ch += 4) {   // 64-wide f-chunks, wave-private
    int f0 = ch * 64;
    { // stage common gate/up tile [16 tok][64 f] into LDS (v8s coalesced)
      int srow = lane >> 3, c8 = (lane & 7) * 8;
      #pragma unroll
      for (int rr = 0; rr < 2; ++rr) {
        int row = srow + rr*8;
        size_t trd = (size_t)min(sTok[row], TT - 1);
        *(v8s*)(cgw + row*CT_LD + c8) = *(const v8s*)(CGU + trd*NX2 + C_G + f0 + c8);
        *(v8s*)(cuw + row*CT_LD + c8) = *(const v8s*)(CGU + trd*NX2 + C_U + f0 + c8);
      }
    }
    v4f dg[4], du[4];
    { // stage Bg rows (lane = f-row) then MFMA
      const float* gp = Bg + ((size_t)e*FD + f0 + lane)*16;
      v4f q0 = *(const v4f*)gp, q1 = *(const v4f*)(gp+4), q2 = *(const v4f*)(gp+8), q3 = *(const v4f*)(gp+12);
      *(v8s*)(bsw + lane*BG_LD)     = pack8(q0, q1);
      *(v8s*)(bsw + lane*BG_LD + 8) = pack8(q2, q3);
      #pragma unroll
      for (int nf = 0; nf < 4; ++nf) {
        v8s bgf = *(const v8s*)(bsw + (nf*16 + (lane&15))*BG_LD + (lane>>4)*8);
        dg[nf] = __builtin_amdgcn_mfma_f32_16x16x32_bf16(afg, bgf, (v4f){0.f,0.f,0.f,0.f}, 0, 0, 0);
      }
    }
    { // stage Bu rows into the SAME wave-private buffer, then MFMA
      const float* up = Bu + ((size_t)e*FD + f0 + lane)*16;
      v4f r0 = *(const v4f*)up, r1 = *(const v4f*)(up+4), r2 = *(const v4f*)(up+8), r3 = *(const v4f*)(up+12);
      *(v8s*)(bsw + lane*BG_LD)     = pack8(r0, r1);
      *(v8s*)(bsw + lane*BG_LD + 8) = pack8(r2, r3);
      #pragma unroll
      for (int nf = 0; nf < 4; ++nf) {
        v8s buf = *(const v8s*)(bsw + (nf*16 + (lane&15))*BG_LD + (lane>>4)*8);
        du[nf] = __builtin_amdgcn_mfma_f32_16x16x32_bf16(afu, buf, (v4f){0.f,0.f,0.f,0.f}, 0, 0, 0);
      }
    }
    #pragma unroll
    for (int nf = 0; nf < 4; ++nf) {
      #pragma unroll
      for (int j = 0; j < 4; ++j) {
        int rj = (lane>>4)*4 + j;
        int fi = nf*16 + (lane&15);
        float cgv = b2f(cgw[rj*CT_LD + fi]);
        float cuv = b2f(cuw[rj*CT_LD + fi]);
        float gv = cgv + 2.f * dg[nf][j];
        float uv = cuv + 2.f * du[nf][j];
        float a  = gv / (1.f + __expf(-gv)) * uv;   // silu(g)*u
        u16 ab = f2b(wR[j] * a);
        (slR[j] ? actw1 : actw0)[(size_t)tR[j]*FD + f0 + fi] = ab;
        aww[rj*AW_LD + fi] = ab;
      }
    }
    #pragma unroll
    for (int ks = 0; ks < 2; ++ks) {   // dA accumulate: [16 tok] x [16 r] over K=64
      v8s aA = *(const v8s*)(aww + (lane&15)*AW_LD + ks*32 + (lane>>4)*8);
      const float* ap = Ad + ((size_t)e*16 + (lane&15))*FD + f0 + ks*32 + (lane>>4)*8;
      v4f q0 = *(const v4f*)ap, q1 = *(const v4f*)(ap+4);
      v8s bA = pack8(q0, q1);
      accDA = __builtin_amdgcn_mfma_f32_16x16x32_bf16(aA, bA, accDA, 0, 0, 0);
    }
  }
  #pragma unroll
  for (int j = 0; j < 4; ++j)
    dAred[w][((lane>>4)*4 + j)*16 + (lane&15)] = accDA[j];
  __syncthreads();
  {
    int row = tid >> 4, col = tid & 15;
    float s2 = dAred[0][row*16+col] + dAred[1][row*16+col] + dAred[2][row*16+col] + dAred[3][row*16+col];
    atomicAdd(&cC[((size_t)sTok[row]*2 + sSlot[row])*16 + col], 2.f * s2);  // LORA_SCALING folded
  }
}

// ---------- combine: abx[t] = [actw0+actw1 (bf16), scattered c coefs, zeros] ----------
__global__ __launch_bounds__(256)
void combine2_kernel(const u16* __restrict__ a0, const u16* __restrict__ a1,
                     const float* __restrict__ cC, const int* __restrict__ sel,
                     u16* __restrict__ abx) {
  int t = blockIdx.x, tid = threadIdx.x;
  const u16* p0 = a0 + (size_t)t * FD;
  const u16* p1 = a1 + (size_t)t * FD;
  u16* po = abx + (size_t)t * KXD;
  for (int i = tid * 8; i < FD; i += 256 * 8) {
    v8s x = *(const v8s*)(p0 + i);
    v8s y = *(const v8s*)(p1 + i);
    v8s o;
    #pragma unroll
    for (int j = 0; j < 8; ++j) o[j] = (short)f2b(b2f((u16)x[j]) + b2f((u16)y[j]));
    *(v8s*)(po + i) = o;
  }
  {   // ext cols: c[t, e, r] scattered at FD + e*16 + r; cols >=128 zeroed
    int c = tid;       // 0..255
    float v = 0.f;
    if (c < 128) {
      int e_i = c >> 4, r = c & 15;
      if (sel[2*t]     == e_i) v += cC[((size_t)t*2 + 0)*16 + r];
      if (sel[2*t + 1] == e_i) v += cC[((size_t)t*2 + 1)*16 + r];
    }
    po[FD + c] = f2b(v);
  }
}

// ---------- launch ----------
extern "C" void kernel_launch(void* const* d_in, const int* in_sizes, int n_in,
                              void* d_out, int out_size, void* d_ws, size_t ws_size,
                              hipStream_t stream) {
  (void)in_sizes; (void)n_in; (void)out_size; (void)ws_size;
  const float* h  = (const float*)d_in[0];
  const float* gw = (const float*)d_in[1];
  const float* Wg = (const float*)d_in[2];
  const float* Wu = (const float*)d_in[3];
  const float* Wd = (const float*)d_in[4];
  const float* Ag = (const float*)d_in[5];
  const float* Bg = (const float*)d_in[6];
  const float* Au = (const float*)d_in[7];
  const float* Bu = (const float*)d_in[8];
  const float* Ad = (const float*)d_in[9];
  const float* Bd = (const float*)d_in[10];

  char* ws = (char*)d_ws;
  size_t off = 0;
  auto alloc = [&](size_t bytes) { size_t c = off; off += (bytes + 255) & ~(size_t)255; return c; };
  u16*  hb     = (u16*)(ws + alloc((size_t)TT*HD*2));             // 8 MB
  u16*  Bgux   = (u16*)(ws + alloc((size_t)NX2*HD*2));            // 68 MB [Wg|Ag|Wu|Au]; later actw0/actw1
  u16*  Wdx    = (u16*)(ws + alloc((size_t)HD*KXD*2));            // 34.6 MB [HD][KXD]
  u16*  CGU    = (u16*)(ws + alloc((size_t)TT*NX2*2));            // 68 MB [TT][NX2]; later abx [TT][KXD]
  float* cC    = (float*)(ws + alloc((size_t)(TT+1)*2*16*4));
  int*  sel    = (int*)(ws + alloc((size_t)TT*2*4));
  int*  count  = (int*)(ws + alloc(256));
  int*  listTok= (int*)(ws + alloc((size_t)NE*TT*4));
  float* listW = (float*)(ws + alloc((size_t)NE*TT*4));
  u16*  actw0  = Bgux;                                  // alias: Bgux dead after merged GEMM
  u16*  actw1  = Bgux + (size_t)(TT+1)*FD;
  u16*  abx    = CGU;                                   // alias: CGU dead after expert_kernel

  hipMemsetAsync(count, 0, NE*sizeof(int), stream);
  hipMemsetAsync(cC, 0, (size_t)(TT+1)*2*16*4, stream);
  hipMemsetAsync(d_out, 0, (size_t)TT*HD*4, stream);

  // bf16 casts into merged B = [Wg rows 0..8191 | Ag 8192..8319 | Wu 8320..16511 | Au 16512..16639]
  cast_kernel<<<2048, 256, 0, stream>>>(h,  hb,  (long)TT*HD);
  cast_kernel<<<4096, 256, 0, stream>>>(Wg, Bgux + (size_t)C_G*HD,  (long)FD*HD);
  cast_kernel<<<128,  256, 0, stream>>>(Ag, Bgux + (size_t)C_GA*HD, (long)NE*NR*HD);
  cast_kernel<<<4096, 256, 0, stream>>>(Wu, Bgux + (size_t)C_U*HD,  (long)FD*HD);
  cast_kernel<<<128,  256, 0, stream>>>(Au, Bgux + (size_t)C_UA*HD, (long)NE*NR*HD);
  cast_ld_kernel<<<4096, 256, 0, stream>>>(Wd, Wdx, HD, FD, KXD);
  bdext_kernel<<<2048, 256, 0, stream>>>(Bd, Wdx);

  router_kernel<<<TT, 64, 0, stream>>>(h, gw, sel, count, listTok, listW);

  // CGU = h @ Bgux^T  (M=2048, N=16640, K=2048) — merged gate+up+hA, 8-phase 256^2
  gemm256<0><<<dim3(8, 65, 1), 512, 0, stream>>>(hb, Bgux, CGU, HD, HD, NX2);

  // per-expert: deltas, act, weighted act into slot buffers (aliasing Bgux), c coefs
  expert_kernel<<<dim3(128, NE, 4), 256, 0, stream>>>(CGU, Bg, Bu, Ad, count, listTok, listW,
                                                      actw0, actw1, cC);

  // abx = [actw0+actw1, c-scatter, zeros]  (writes into the dead CGU region)
  combine2_kernel<<<TT, 256, 0, stream>>>(actw0, actw1, cC, sel, abx);

  // out = abx @ Wdx^T  (M=2048, N=2048, K=8448, split-K=6, fp32 atomicAdd)
  gemm256<2><<<dim3(8, 8, 6), 512, 0, stream>>>(abx, Wdx, d_out, KXD, KXD/6, HD);
}

// Round 5
// 516.800 us; speedup vs baseline: 1.3897x; 1.0914x over previous
//
#include <hip/hip_runtime.h>
#include <hip/hip_bf16.h>

typedef __attribute__((ext_vector_type(8))) short v8s;   // 8 x bf16 (as i16)
typedef __attribute__((ext_vector_type(4))) float v4f;
typedef unsigned short u16;

static constexpr int TT = 2048;        // tokens
static constexpr int HD = 2048;        // hidden
static constexpr int FD = 8192;        // ffn dim
static constexpr int NE = 8;           // experts
static constexpr int NR = 16;          // lora rank
static constexpr int NXE = 2*FD;       // 16384: merged [Wg | Wu] cols
static constexpr int CU_OFF = FD;      // up offset inside CGU row
static constexpr int KXD = FD + 512;   // 8704 = 136*64 ext K for down GEMM (34*64*4)

// ---------- helpers ----------
__device__ __forceinline__ u16 f2b(float f) {            // fp32 -> bf16 RNE
  union { float f; unsigned u; } v; v.f = f;
  unsigned r = v.u + 0x7FFFu + ((v.u >> 16) & 1u);
  return (u16)(r >> 16);
}
__device__ __forceinline__ float b2f(u16 h) {
  union { unsigned u; float f; } v; v.u = ((unsigned)h) << 16;
  return v.f;
}
__device__ __forceinline__ v8s pack8(v4f a, v4f b) {
  v8s r;
  r[0]=(short)f2b(a.x); r[1]=(short)f2b(a.y); r[2]=(short)f2b(a.z); r[3]=(short)f2b(a.w);
  r[4]=(short)f2b(b.x); r[5]=(short)f2b(b.y); r[6]=(short)f2b(b.z); r[7]=(short)f2b(b.w);
  return r;
}
__device__ __forceinline__ void gload_lds16(const void* g, void* l) {
  __builtin_amdgcn_global_load_lds(
      (const __attribute__((address_space(1))) unsigned int*)g,
      (__attribute__((address_space(3))) unsigned int*)l, 16, 0, 0);
}
__device__ __forceinline__ void barrier_pin() {
  __builtin_amdgcn_s_barrier();
  __builtin_amdgcn_sched_barrier(0);
}
__device__ __forceinline__ void vm_wait4() { asm volatile("s_waitcnt vmcnt(4)" ::: "memory"); }
__device__ __forceinline__ void vm_wait0() { asm volatile("s_waitcnt vmcnt(0)" ::: "memory"); }

template<int Q>
__device__ __forceinline__ void mmq(v4f (&acc)[8][4], const v8s (&af)[2][2], const v8s (&bf)[4][2]) {
  __builtin_amdgcn_s_setprio(1);
  #pragma unroll
  for (int m2 = 0; m2 < 2; ++m2)
    #pragma unroll
    for (int nf = 0; nf < 4; ++nf) {
      acc[Q*2+m2][nf] = __builtin_amdgcn_mfma_f32_16x16x32_bf16(af[m2][0], bf[nf][0], acc[Q*2+m2][nf], 0, 0, 0);
      acc[Q*2+m2][nf] = __builtin_amdgcn_mfma_f32_16x16x32_bf16(af[m2][1], bf[nf][1], acc[Q*2+m2][nf], 0, 0, 0);
    }
  __builtin_amdgcn_s_setprio(0);
}

// ---------- cast fp32 -> bf16 (contiguous) ----------
__global__ __launch_bounds__(256)
void cast_kernel(const float* __restrict__ src, u16* __restrict__ dst, long n) {
  long stride = (long)gridDim.x * 256 * 8;
  for (long i = ((long)blockIdx.x * 256 + threadIdx.x) * 8; i < n; i += stride) {
    v4f a = *(const v4f*)(src + i);
    v4f b = *(const v4f*)(src + i + 4);
    *(v8s*)(dst + i) = pack8(a, b);
  }
}

// ---------- cast fp32 -> bf16 with dst leading-dim (Wd into Wdx[HD][KXD]) ----------
__global__ __launch_bounds__(256)
void cast_ld_kernel(const float* __restrict__ src, u16* __restrict__ dst,
                    int rows, int cols, int dld) {
  long total = (long)rows * (cols / 8);
  long stride = (long)gridDim.x * 256;
  for (long idx = (long)blockIdx.x * 256 + threadIdx.x; idx < total; idx += stride) {
    long r = idx / (cols / 8);
    int c8 = (int)(idx % (cols / 8)) * 8;
    v4f a = *(const v4f*)(src + r * cols + c8);
    v4f b = *(const v4f*)(src + r * cols + c8 + 4);
    *(v8s*)(dst + r * dld + c8) = pack8(a, b);
  }
}

// ---------- Bd[E][H][16] -> ext cols FD..FD+511 of Wdx (cols >=128 zeroed) ----------
__global__ __launch_bounds__(256)
void bdext_kernel(const float* __restrict__ Bd, u16* __restrict__ Wdx) {
  int idx = blockIdx.x * 256 + threadIdx.x;          // total HD*512
  int hrow = idx >> 9, c = idx & 511;
  float v = 0.f;
  if (c < 128) {
    int e = c >> 4, r = c & 15;
    v = Bd[((size_t)e * HD + hrow) * 16 + r];
  }
  Wdx[(size_t)hrow * KXD + FD + c] = f2b(v);
}

// ---------- router + gather ----------
__global__ __launch_bounds__(64)
void router_kernel(const float* __restrict__ h, const float* __restrict__ gw,
                   int* __restrict__ sel, int* __restrict__ count,
                   int* __restrict__ listTok, float* __restrict__ listW) {
  int t = blockIdx.x, lane = threadIdx.x;
  const float* hp = h + (size_t)t * HD;
  float acc[8] = {0,0,0,0,0,0,0,0};
  for (int i = lane; i < HD; i += 64) {
    float hv = hp[i];
    #pragma unroll
    for (int e = 0; e < 8; ++e) acc[e] += hv * gw[e*HD + i];
  }
  #pragma unroll
  for (int off = 32; off > 0; off >>= 1) {
    #pragma unroll
    for (int e = 0; e < 8; ++e) acc[e] += __shfl_xor(acc[e], off, 64);
  }
  if (lane == 0) {
    int e0 = -1, e1 = -1; float b0 = -1e30f, b1 = -1e30f;
    #pragma unroll
    for (int e = 0; e < 8; ++e) {
      float v = acc[e];
      if (v > b0) { b1 = b0; e1 = e0; b0 = v; e0 = e; }
      else if (v > b1) { b1 = v; e1 = e; }
    }
    float p1 = __expf(b1 - b0);            // p0 = 1
    float w0 = 1.f / (1.f + p1);
    float w1 = p1 * w0;
    sel[2*t] = e0; sel[2*t+1] = e1;
    int pos0 = atomicAdd(&count[e0], 1);
    listTok[e0*TT + pos0] = t;           listW[e0*TT + pos0] = w0;
    int pos1 = atomicAdd(&count[e1], 1);
    listTok[e1*TT + pos1] = t | (1<<20); listW[e1*TT + pos1] = w1;
  }
}

// ---------- 128x128x64 bf16 GEMM (m97 structure), C = A @ B^T, split-K atomic ----------
__global__ __launch_bounds__(256)
void gemm128a(const u16* __restrict__ A, const u16* __restrict__ B, float* __restrict__ Cout,
              int K, int ldc) {
  __shared__ u16 As[128*64];
  __shared__ u16 Bs[128*64];
  const int tid  = threadIdx.x;
  const int lane = tid & 63, wid = tid >> 6;
  const int gx = gridDim.x;
  const int lin = blockIdx.y * gx + blockIdx.x;
  const int chunk = (gx * gridDim.y) >> 3;
  const int wg = (lin & 7) * chunk + (lin >> 3);
  const int m0 = (wg % gx) * 128, n0 = (wg / gx) * 128;
  const int kc = K / gridDim.z;
  const int kbeg = blockIdx.z * kc;
  const int wr = wid >> 1, wc = wid & 1;
  const int lrow = lane >> 3, lcol = (lane & 7) * 8;
  v4f acc[4][4];
  #pragma unroll
  for (int mi = 0; mi < 4; ++mi)
    #pragma unroll
    for (int ni = 0; ni < 4; ++ni) acc[mi][ni] = (v4f){0.f,0.f,0.f,0.f};

  for (int k0 = kbeg; k0 < kbeg + kc; k0 += 64) {
    #pragma unroll
    for (int it = 0; it < 4; ++it) {
      int seg = wid*4 + it;
      int row = seg*8 + lrow;
      gload_lds16(A + (size_t)(m0+row)*K + k0 + lcol, As + seg*512);
      gload_lds16(B + (size_t)(n0+row)*K + k0 + lcol, Bs + seg*512);
    }
    __syncthreads();
    #pragma unroll
    for (int kk = 0; kk < 64; kk += 32) {
      v8s af[4], bfr[4];
      #pragma unroll
      for (int mi = 0; mi < 4; ++mi)
        af[mi] = *(const v8s*)(As + (wr*64 + mi*16 + (lane&15))*64 + kk + (lane>>4)*8);
      #pragma unroll
      for (int ni = 0; ni < 4; ++ni)
        bfr[ni] = *(const v8s*)(Bs + (wc*64 + ni*16 + (lane&15))*64 + kk + (lane>>4)*8);
      #pragma unroll
      for (int mi = 0; mi < 4; ++mi)
        #pragma unroll
        for (int ni = 0; ni < 4; ++ni)
          acc[mi][ni] = __builtin_amdgcn_mfma_f32_16x16x32_bf16(af[mi], bfr[ni], acc[mi][ni], 0, 0, 0);
    }
    __syncthreads();
  }

  #pragma unroll
  for (int mi = 0; mi < 4; ++mi)
    #pragma unroll
    for (int j = 0; j < 4; ++j) {
      int row = m0 + wr*64 + mi*16 + (lane>>4)*4 + j;
      size_t base = (size_t)row*ldc + n0 + wc*64 + (lane&15);
      #pragma unroll
      for (int ni = 0; ni < 4; ++ni)
        atomicAdd(&Cout[base + ni*16], acc[mi][ni][j]);
    }
}

// ---------- 256x256 8-phase bf16 GEMM, C = A @ B^T  (T1+T2+T3+T4+T5) ----------
// MODE 0: bf16 store. MODE 2: fp32 atomicAdd (split-K; C pre-zeroed).
template<int MODE>
__global__ __launch_bounds__(512, 2)
void gemm256(const u16* __restrict__ A, const u16* __restrict__ B, void* __restrict__ Cout,
             int ldk, int kchunk, int ldc) {
  __shared__ u16 lds[2][2][2][8192];
  const int tid = threadIdx.x, lane = tid & 63, wid = tid >> 6;
  const int gx = gridDim.x;
  const int nwg = gx * gridDim.y;
  const int lin = blockIdx.y * gx + blockIdx.x;
  const int chunk = nwg >> 3;                       // nwg % 8 == 0 by construction
  const int wg = (lin & 7) * chunk + (lin >> 3);    // bijective XCD swizzle
  const int m0 = (wg % gx) * 256, n0 = (wg / gx) * 256;
  const long kbeg = (long)blockIdx.z * kchunk;
  const int NK = kchunk >> 6, NI = NK >> 1;         // NK even
  const int wr = wid >> 2, wc = wid & 3;

  const int s_r = (wid << 4) + (lane >> 3);
  const int s_c = lane & 7;

  auto STAGE = [&](int slot, int ab, int half, const u16* M, int rc0, int kt) {
    const u16* g0 = M + (size_t)(rc0 + half*128 + s_r) * ldk + kbeg + kt*64 + ((s_c ^ (s_r & 7)) << 3);
    gload_lds16(g0, &lds[slot][ab][half][wid << 10]);
    const int r1 = s_r + 8;
    const u16* g1 = M + (size_t)(rc0 + half*128 + r1) * ldk + kbeg + kt*64 + ((s_c ^ (r1 & 7)) << 3);
    gload_lds16(g1, &lds[slot][ab][half][(wid << 10) + 512]);
  };
  auto LDA = [&](int slot, int mf, int c16b) -> v8s {
    int rr = (mf << 4) + (lane & 15);
    return *(const v8s*)&lds[slot][0][wr][rr*64 + (((c16b + (lane >> 4)) ^ (rr & 7)) << 3)];
  };
  auto LDB = [&](int slot, int nf, int c16b) -> v8s {
    int row = (wc << 6) + (nf << 4) + (lane & 15);
    int rr = row & 127;
    return *(const v8s*)&lds[slot][1][row >> 7][rr*64 + (((c16b + (lane >> 4)) ^ (rr & 7)) << 3)];
  };

  v4f acc[8][4];
  #pragma unroll
  for (int mf = 0; mf < 8; ++mf)
    #pragma unroll
    for (int nf = 0; nf < 4; ++nf) acc[mf][nf] = (v4f){0.f,0.f,0.f,0.f};

  STAGE(0,1,0,B,n0,0); STAGE(0,1,1,B,n0,0);
  STAGE(0,0,0,A,m0,0); STAGE(0,0,1,A,m0,0);
  STAGE(1,1,0,B,n0,1); STAGE(1,1,1,B,n0,1);
  vm_wait4();
  barrier_pin();

  for (int i = 0; i < NI; ++i) {
    const int kt0 = 2*i, kt1 = kt0 + 1;
    const int kt2c = (kt0 + 2 < NK) ? kt0 + 2 : kt0;
    const bool s45 = (kt0 + 2 < NK), s67 = (kt1 + 2 < NK);
    v8s bf[4][2], af[2][2];
    // ---- phase 0 (slot0, q0)
    #pragma unroll
    for (int nf = 0; nf < 4; ++nf) { bf[nf][0] = LDB(0,nf,0); bf[nf][1] = LDB(0,nf,4); }
    af[0][0]=LDA(0,0,0); af[0][1]=LDA(0,0,4); af[1][0]=LDA(0,1,0); af[1][1]=LDA(0,1,4);
    STAGE(1,0,0,A,m0,kt1);
    barrier_pin(); mmq<0>(acc,af,bf); barrier_pin();
    // ---- phase 1 (slot0, q1)
    af[0][0]=LDA(0,2,0); af[0][1]=LDA(0,2,4); af[1][0]=LDA(0,3,0); af[1][1]=LDA(0,3,4);
    STAGE(1,0,1,A,m0,kt1);
    barrier_pin(); mmq<1>(acc,af,bf); barrier_pin();
    // ---- phase 2 (slot0, q2)
    af[0][0]=LDA(0,4,0); af[0][1]=LDA(0,4,4); af[1][0]=LDA(0,5,0); af[1][1]=LDA(0,5,4);
    STAGE(0,1,0,B,n0,kt2c);
    barrier_pin(); mmq<2>(acc,af,bf); barrier_pin();
    // ---- phase 3 (slot0, q3)
    af[0][0]=LDA(0,6,0); af[0][1]=LDA(0,6,4); af[1][0]=LDA(0,7,0); af[1][1]=LDA(0,7,4);
    STAGE(0,1,1,B,n0,kt2c);
    vm_wait4();
    barrier_pin(); mmq<3>(acc,af,bf); barrier_pin();
    // ---- phase 4 (slot1, q0)
    #pragma unroll
    for (int nf = 0; nf < 4; ++nf) { bf[nf][0] = LDB(1,nf,0); bf[nf][1] = LDB(1,nf,4); }
    af[0][0]=LDA(1,0,0); af[0][1]=LDA(1,0,4); af[1][0]=LDA(1,1,0); af[1][1]=LDA(1,1,4);
    if (s45) STAGE(0,0,0,A,m0,kt0+2);
    barrier_pin(); mmq<0>(acc,af,bf); barrier_pin();
    // ---- phase 5 (slot1, q1)
    af[0][0]=LDA(1,2,0); af[0][1]=LDA(1,2,4); af[1][0]=LDA(1,3,0); af[1][1]=LDA(1,3,4);
    if (s45) STAGE(0,0,1,A,m0,kt0+2);
    barrier_pin(); mmq<1>(acc,af,bf); barrier_pin();
    // ---- phase 6 (slot1, q2)
    af[0][0]=LDA(1,4,0); af[0][1]=LDA(1,4,4); af[1][0]=LDA(1,5,0); af[1][1]=LDA(1,5,4);
    if (s67) STAGE(1,1,0,B,n0,kt1+2);
    barrier_pin(); mmq<2>(acc,af,bf); barrier_pin();
    // ---- phase 7 (slot1, q3)
    af[0][0]=LDA(1,6,0); af[0][1]=LDA(1,6,4); af[1][0]=LDA(1,7,0); af[1][1]=LDA(1,7,4);
    if (s67) STAGE(1,1,1,B,n0,kt1+2);
    vm_wait4();
    barrier_pin(); mmq<3>(acc,af,bf); barrier_pin();
  }
  vm_wait0();

  if (MODE == 0) {
    u16* C = (u16*)Cout;
    #pragma unroll
    for (int mf = 0; mf < 8; ++mf)
      #pragma unroll
      for (int j = 0; j < 4; ++j) {
        int row = m0 + wr*128 + mf*16 + (lane>>4)*4 + j;
        size_t base = (size_t)row*ldc + n0 + wc*64 + (lane&15);
        #pragma unroll
        for (int nf = 0; nf < 4; ++nf)
          C[base + nf*16] = f2b(acc[mf][nf][j]);
      }
  } else {
    float* C = (float*)Cout;
    #pragma unroll
    for (int mf = 0; mf < 8; ++mf)
      #pragma unroll
      for (int j = 0; j < 4; ++j) {
        int row = m0 + wr*128 + mf*16 + (lane>>4)*4 + j;
        size_t base = (size_t)row*ldc + n0 + wc*64 + (lane&15);
        #pragma unroll
        for (int nf = 0; nf < 4; ++nf)
          atomicAdd(&C[base + nf*16], acc[mf][nf][j]);
      }
  }
}

// ---------- expert kernel ----------
// grid (128 groups, NE, 4 f-blocks). Per block: 16 tokens x 2048 f-cols.
static constexpr int HA_LD = 40;
static constexpr int BG_LD = 40;
static constexpr int AW_LD = 72;
static constexpr int CT_LD = 72;

__global__ __launch_bounds__(256)
void expert_kernel(const u16* __restrict__ CGU,                                // [TT][NXE]
                   const float* __restrict__ hAx,                              // [TT][256] fp32
                   const float* __restrict__ Bg, const float* __restrict__ Bu, // [E][F][16]
                   const float* __restrict__ Ad,                               // [E][16][F]
                   const int* __restrict__ count, const int* __restrict__ listTok,
                   const float* __restrict__ listW,
                   u16* __restrict__ actw0, u16* __restrict__ actw1,           // [TT+1][F]
                   float* __restrict__ cC) {                                   // [TT+1][2][16]
  const int e = blockIdx.y, g = blockIdx.x, fb = blockIdx.z;
  const int n = count[e];
  if (g*16 >= n) return;
  const int tid = threadIdx.x, lane = tid & 63, w = tid >> 6;
  __shared__ u16 hAg[16*HA_LD], hAu[16*HA_LD];
  __shared__ u16 BS[4][64*BG_LD];
  __shared__ u16 AWs[4][16*AW_LD];
  __shared__ u16 cgT[4][16*CT_LD], cuT[4][16*CT_LD];
  __shared__ int sTok[16], sSlot[16];
  __shared__ float sW[16];
  __shared__ float dAred[4][256];

  if (tid < 16) {
    int idx = g*16 + tid;
    if (idx < n) {
      int ent = listTok[e*TT + idx];
      sTok[tid] = ent & 0xFFFF; sSlot[tid] = (ent >> 20) & 1; sW[tid] = listW[e*TT + idx];
    } else { sTok[tid] = TT; sSlot[tid] = 0; sW[tid] = 0.f; }
  }
  __syncthreads();
  if (tid < 128) {   // stage hA (both tensors) from hAx fp32, zero-pad K 16..31
    int tensor = tid >> 6;
    int sub = tid & 63;
    int row = sub >> 2, c8 = (sub & 3) * 8;
    int trd = min(sTok[row], TT - 1);
    u16 vals[8];
    if (c8 < 16) {
      const float* src = hAx + (size_t)trd*256 + tensor*128 + e*NR + c8;
      v4f a = *(const v4f*)src, b = *(const v4f*)(src + 4);
      v8s p = pack8(a, b);
      #pragma unroll
      for (int q = 0; q < 8; ++q) vals[q] = (u16)p[q];
    } else {
      #pragma unroll
      for (int q = 0; q < 8; ++q) vals[q] = 0;
    }
    u16* dst = (tensor ? hAu : hAg) + row*HA_LD + c8;
    #pragma unroll
    for (int q = 0; q < 8; ++q) dst[q] = vals[q];
  }
  __syncthreads();

  int tR[4], slR[4]; float wR[4];
  #pragma unroll
  for (int j = 0; j < 4; ++j) {
    int r = (lane>>4)*4 + j;
    tR[j] = sTok[r]; slR[j] = sSlot[r]; wR[j] = sW[r];
  }
  v8s afg = *(const v8s*)(hAg + (lane&15)*HA_LD + (lane>>4)*8);
  v8s afu = *(const v8s*)(hAu + (lane&15)*HA_LD + (lane>>4)*8);
  v4f accDA = (v4f){0.f,0.f,0.f,0.f};
  u16* bsw = BS[w]; u16* aww = AWs[w]; u16* cgw = cgT[w]; u16* cuw = cuT[w];

  {
    v8s z = {0,0,0,0,0,0,0,0};
    *(v8s*)(bsw + lane*BG_LD + 16) = z; *(v8s*)(bsw + lane*BG_LD + 24) = z;
  }

  const int ch_end = fb*32 + 32;
  for (int ch = fb*32 + w; ch < ch_end; ch += 4) {
    int f0 = ch * 64;
    {
      int srow = lane >> 3, c8 = (lane & 7) * 8;
      #pragma unroll
      for (int rr = 0; rr < 2; ++rr) {
        int row = srow + rr*8;
        size_t trd = (size_t)min(sTok[row], TT - 1);
        *(v8s*)(cgw + row*CT_LD + c8) = *(const v8s*)(CGU + trd*NXE + f0 + c8);
        *(v8s*)(cuw + row*CT_LD + c8) = *(const v8s*)(CGU + trd*NXE + CU_OFF + f0 + c8);
      }
    }
    v4f dg[4], du[4];
    {
      const float* gp = Bg + ((size_t)e*FD + f0 + lane)*16;
      v4f q0 = *(const v4f*)gp, q1 = *(const v4f*)(gp+4), q2 = *(const v4f*)(gp+8), q3 = *(const v4f*)(gp+12);
      *(v8s*)(bsw + lane*BG_LD)     = pack8(q0, q1);
      *(v8s*)(bsw + lane*BG_LD + 8) = pack8(q2, q3);
      #pragma unroll
      for (int nf = 0; nf < 4; ++nf) {
        v8s bgf = *(const v8s*)(bsw + (nf*16 + (lane&15))*BG_LD + (lane>>4)*8);
        dg[nf] = __builtin_amdgcn_mfma_f32_16x16x32_bf16(afg, bgf, (v4f){0.f,0.f,0.f,0.f}, 0, 0, 0);
      }
    }
    {
      const float* up = Bu + ((size_t)e*FD + f0 + lane)*16;
      v4f r0 = *(const v4f*)up, r1 = *(const v4f*)(up+4), r2 = *(const v4f*)(up+8), r3 = *(const v4f*)(up+12);
      *(v8s*)(bsw + lane*BG_LD)     = pack8(r0, r1);
      *(v8s*)(bsw + lane*BG_LD + 8) = pack8(r2, r3);
      #pragma unroll
      for (int nf = 0; nf < 4; ++nf) {
        v8s buf = *(const v8s*)(bsw + (nf*16 + (lane&15))*BG_LD + (lane>>4)*8);
        du[nf] = __builtin_amdgcn_mfma_f32_16x16x32_bf16(afu, buf, (v4f){0.f,0.f,0.f,0.f}, 0, 0, 0);
      }
    }
    #pragma unroll
    for (int nf = 0; nf < 4; ++nf) {
      #pragma unroll
      for (int j = 0; j < 4; ++j) {
        int rj = (lane>>4)*4 + j;
        int fi = nf*16 + (lane&15);
        float cgv = b2f(cgw[rj*CT_LD + fi]);
        float cuv = b2f(cuw[rj*CT_LD + fi]);
        float gv = cgv + 2.f * dg[nf][j];
        float uv = cuv + 2.f * du[nf][j];
        float a  = gv / (1.f + __expf(-gv)) * uv;   // silu(g)*u
        u16 ab = f2b(wR[j] * a);
        (slR[j] ? actw1 : actw0)[(size_t)tR[j]*FD + f0 + fi] = ab;
        aww[rj*AW_LD + fi] = ab;
      }
    }
    #pragma unroll
    for (int ks = 0; ks < 2; ++ks) {
      v8s aA = *(const v8s*)(aww + (lane&15)*AW_LD + ks*32 + (lane>>4)*8);
      const float* ap = Ad + ((size_t)e*16 + (lane&15))*FD + f0 + ks*32 + (lane>>4)*8;
      v4f q0 = *(const v4f*)ap, q1 = *(const v4f*)(ap+4);
      v8s bA = pack8(q0, q1);
      accDA = __builtin_amdgcn_mfma_f32_16x16x32_bf16(aA, bA, accDA, 0, 0, 0);
    }
  }
  #pragma unroll
  for (int j = 0; j < 4; ++j)
    dAred[w][((lane>>4)*4 + j)*16 + (lane&15)] = accDA[j];
  __syncthreads();
  {
    int row = tid >> 4, col = tid & 15;
    float s2 = dAred[0][row*16+col] + dAred[1][row*16+col] + dAred[2][row*16+col] + dAred[3][row*16+col];
    atomicAdd(&cC[((size_t)sTok[row]*2 + sSlot[row])*16 + col], 2.f * s2);
  }
}

// ---------- combine: abx[t] = [actw0+actw1 (bf16), scattered c coefs, zeros] ----------
__global__ __launch_bounds__(256)
void combine2_kernel(const u16* __restrict__ a0, const u16* __restrict__ a1,
                     const float* __restrict__ cC, const int* __restrict__ sel,
                     u16* __restrict__ abx) {
  int t = blockIdx.x, tid = threadIdx.x;
  const u16* p0 = a0 + (size_t)t * FD;
  const u16* p1 = a1 + (size_t)t * FD;
  u16* po = abx + (size_t)t * KXD;
  for (int i = tid * 8; i < FD; i += 256 * 8) {
    v8s x = *(const v8s*)(p0 + i);
    v8s y = *(const v8s*)(p1 + i);
    v8s o;
    #pragma unroll
    for (int j = 0; j < 8; ++j) o[j] = (short)f2b(b2f((u16)x[j]) + b2f((u16)y[j]));
    *(v8s*)(po + i) = o;
  }
  for (int c = tid; c < 512; c += 256) {  // ext cols; c>=128 zeroed
    float v = 0.f;
    if (c < 128) {
      int e_i = c >> 4, r = c & 15;
      if (sel[2*t]     == e_i) v += cC[((size_t)t*2 + 0)*16 + r];
      if (sel[2*t + 1] == e_i) v += cC[((size_t)t*2 + 1)*16 + r];
    }
    po[FD + c] = f2b(v);
  }
}

// ---------- launch ----------
extern "C" void kernel_launch(void* const* d_in, const int* in_sizes, int n_in,
                              void* d_out, int out_size, void* d_ws, size_t ws_size,
                              hipStream_t stream) {
  (void)in_sizes; (void)n_in; (void)out_size; (void)ws_size;
  const float* h  = (const float*)d_in[0];
  const float* gw = (const float*)d_in[1];
  const float* Wg = (const float*)d_in[2];
  const float* Wu = (const float*)d_in[3];
  const float* Wd = (const float*)d_in[4];
  const float* Ag = (const float*)d_in[5];
  const float* Bg = (const float*)d_in[6];
  const float* Au = (const float*)d_in[7];
  const float* Bu = (const float*)d_in[8];
  const float* Ad = (const float*)d_in[9];
  const float* Bd = (const float*)d_in[10];

  char* ws = (char*)d_ws;
  size_t off = 0;
  auto alloc = [&](size_t bytes) { size_t c = off; off += (bytes + 255) & ~(size_t)255; return c; };
  u16*  hb     = (u16*)(ws + alloc((size_t)TT*HD*2));             // 8 MB
  u16*  Bgux   = (u16*)(ws + alloc((size_t)(TT+1)*FD*2*2));       // 67.2 MB [Wg|Wu]; later actw0/actw1
  u16*  Agu    = (u16*)(ws + alloc((size_t)256*HD*2));            // 1 MB [Ag all|Au all]
  u16*  Wdx    = (u16*)(ws + alloc((size_t)HD*KXD*2));            // 35.7 MB [HD][KXD]
  u16*  CGU    = (u16*)(ws + alloc((size_t)TT*NXE*2));            // 64 MB [TT][NXE]; later abx [TT][KXD]
  float* hAx   = (float*)(ws + alloc((size_t)TT*256*4));          // 2 MB
  float* cC    = (float*)(ws + alloc((size_t)(TT+1)*2*16*4));
  int*  sel    = (int*)(ws + alloc((size_t)TT*2*4));
  int*  count  = (int*)(ws + alloc(256));
  int*  listTok= (int*)(ws + alloc((size_t)NE*TT*4));
  float* listW = (float*)(ws + alloc((size_t)NE*TT*4));
  u16*  actw0  = Bgux;                                  // alias: Bgux dead after merged GEMM
  u16*  actw1  = Bgux + (size_t)(TT+1)*FD;
  u16*  abx    = CGU;                                   // alias: CGU dead after expert_kernel

  hipMemsetAsync(count, 0, NE*sizeof(int), stream);
  hipMemsetAsync(cC, 0, (size_t)(TT+1)*2*16*4, stream);
  hipMemsetAsync(hAx, 0, (size_t)TT*256*4, stream);
  hipMemsetAsync(d_out, 0, (size_t)TT*HD*4, stream);

  // bf16 casts: merged B = [Wg rows 0..8191 | Wu rows 8192..16383]; Agu = [Ag|Au]
  cast_kernel<<<2048, 256, 0, stream>>>(h,  hb,  (long)TT*HD);
  cast_kernel<<<4096, 256, 0, stream>>>(Wg, Bgux, (long)FD*HD);
  cast_kernel<<<4096, 256, 0, stream>>>(Wu, Bgux + (size_t)FD*HD, (long)FD*HD);
  cast_kernel<<<128,  256, 0, stream>>>(Ag, Agu, (long)NE*NR*HD);
  cast_kernel<<<128,  256, 0, stream>>>(Au, Agu + (size_t)128*HD, (long)NE*NR*HD);
  cast_ld_kernel<<<4096, 256, 0, stream>>>(Wd, Wdx, HD, FD, KXD);
  bdext_kernel<<<4096, 256, 0, stream>>>(Bd, Wdx);

  router_kernel<<<TT, 64, 0, stream>>>(h, gw, sel, count, listTok, listW);

  // hAx = h @ [Ag;Au]^T  (M=2048, N=256, K=2048, split-K=8 -> 256 blocks)
  gemm128a<<<dim3(16, 2, 8), 256, 0, stream>>>(hb, Agu, hAx, HD, 256);

  // CGU = h @ [Wg|Wu]^T  (M=2048, N=16384, K=2048) -> 512 blocks = 2 exact rounds
  gemm256<0><<<dim3(8, 64, 1), 512, 0, stream>>>(hb, Bgux, CGU, HD, HD, NXE);

  // per-expert: deltas, act, weighted act into slot buffers (aliasing Bgux), c coefs
  expert_kernel<<<dim3(128, NE, 4), 256, 0, stream>>>(CGU, hAx, Bg, Bu, Ad, count, listTok, listW,
                                                      actw0, actw1, cC);

  // abx = [actw0+actw1, c-scatter, zeros]  (writes into the dead CGU region)
  combine2_kernel<<<TT, 256, 0, stream>>>(actw0, actw1, cC, sel, abx);

  // out = abx @ Wdx^T  (M=2048, N=2048, K=8704, split-K=4 -> 256 blocks = 1 round)
  gemm256<2><<<dim3(8, 8, 4), 512, 0, stream>>>(abx, Wdx, d_out, KXD, KXD/4, HD);
}

// Round 6
// 508.434 us; speedup vs baseline: 1.4126x; 1.0165x over previous
//
#include <hip/hip_runtime.h>
#include <hip/hip_bf16.h>

typedef __attribute__((ext_vector_type(8))) short v8s;   // 8 x bf16 (as i16)
typedef __attribute__((ext_vector_type(4))) float v4f;
typedef unsigned short u16;

static constexpr int TT = 2048;        // tokens
static constexpr int HD = 2048;        // hidden
static constexpr int FD = 8192;        // ffn dim
static constexpr int NE = 8;           // experts
static constexpr int NR = 16;          // lora rank
static constexpr int NXE = 2*FD;       // 16384: merged [Wg | Wu] cols
static constexpr int CU_OFF = FD;      // up offset inside CGU row
static constexpr int KXD = FD + 512;   // 8704 = 136*64 ext K for down GEMM (34*64*4)

// ---------- helpers ----------
__device__ __forceinline__ u16 f2b(float f) {            // fp32 -> bf16 RNE
  union { float f; unsigned u; } v; v.f = f;
  unsigned r = v.u + 0x7FFFu + ((v.u >> 16) & 1u);
  return (u16)(r >> 16);
}
__device__ __forceinline__ float b2f(u16 h) {
  union { unsigned u; float f; } v; v.u = ((unsigned)h) << 16;
  return v.f;
}
__device__ __forceinline__ v8s pack8(v4f a, v4f b) {
  v8s r;
  r[0]=(short)f2b(a.x); r[1]=(short)f2b(a.y); r[2]=(short)f2b(a.z); r[3]=(short)f2b(a.w);
  r[4]=(short)f2b(b.x); r[5]=(short)f2b(b.y); r[6]=(short)f2b(b.z); r[7]=(short)f2b(b.w);
  return r;
}
__device__ __forceinline__ void gload_lds16(const void* g, void* l) {
  __builtin_amdgcn_global_load_lds(
      (const __attribute__((address_space(1))) unsigned int*)g,
      (__attribute__((address_space(3))) unsigned int*)l, 16, 0, 0);
}
__device__ __forceinline__ void barrier_pin() {
  __builtin_amdgcn_s_barrier();
  __builtin_amdgcn_sched_barrier(0);
}
__device__ __forceinline__ void vm_wait4() { asm volatile("s_waitcnt vmcnt(4)" ::: "memory"); }
__device__ __forceinline__ void vm_wait0() { asm volatile("s_waitcnt vmcnt(0)" ::: "memory"); }

template<int Q>
__device__ __forceinline__ void mmq(v4f (&acc)[8][4], const v8s (&af)[2][2], const v8s (&bf)[4][2]) {
  __builtin_amdgcn_s_setprio(1);
  #pragma unroll
  for (int m2 = 0; m2 < 2; ++m2)
    #pragma unroll
    for (int nf = 0; nf < 4; ++nf) {
      acc[Q*2+m2][nf] = __builtin_amdgcn_mfma_f32_16x16x32_bf16(af[m2][0], bf[nf][0], acc[Q*2+m2][nf], 0, 0, 0);
      acc[Q*2+m2][nf] = __builtin_amdgcn_mfma_f32_16x16x32_bf16(af[m2][1], bf[nf][1], acc[Q*2+m2][nf], 0, 0, 0);
    }
  __builtin_amdgcn_s_setprio(0);
}

// ---------- mega prep: all casts + Bd-ext + output/hAx zeroing, one launch ----------
// segment block ranges (256 thr, 8 elems/thr):
//   [0,2048)      h -> hb
//   [2048,10240)  Wg -> Bgux
//   [10240,18432) Wu -> Bgux+FD*HD
//   [18432,26624) Wd -> Wdx (ld KXD)
//   [26624,26752) Ag -> Agu
//   [26752,26880) Au -> Agu+128*HD
//   [26880,27392) Bg -> Bgb (bf16)
//   [27392,27904) Bu -> Bub
//   [27904,28416) Ad -> Adb
//   [28416,28928) Bd -> Wdx ext cols (c>=128 zero)
//   [28928,30976) zero d_out
//   [30976,31232) zero hAx
static constexpr int PREP_BLOCKS = 31232;
__global__ __launch_bounds__(256)
void prep_kernel(const float* __restrict__ h, const float* __restrict__ Wg,
                 const float* __restrict__ Wu, const float* __restrict__ Wd,
                 const float* __restrict__ Ag, const float* __restrict__ Au,
                 const float* __restrict__ Bg, const float* __restrict__ Bu,
                 const float* __restrict__ Ad, const float* __restrict__ Bd,
                 u16* __restrict__ hb, u16* __restrict__ Bgux, u16* __restrict__ Agu,
                 u16* __restrict__ Wdx, u16* __restrict__ Bgb, u16* __restrict__ Bub,
                 u16* __restrict__ Adb, float* __restrict__ outz, float* __restrict__ hAx) {
  const int b = blockIdx.x, tid = threadIdx.x;
  if (b < 2048) {
    long i = ((long)b*256 + tid)*8;
    *(v8s*)(hb+i) = pack8(*(const v4f*)(h+i), *(const v4f*)(h+i+4));
  } else if (b < 10240) {
    long i = ((long)(b-2048)*256 + tid)*8;
    *(v8s*)(Bgux+i) = pack8(*(const v4f*)(Wg+i), *(const v4f*)(Wg+i+4));
  } else if (b < 18432) {
    long i = ((long)(b-10240)*256 + tid)*8;
    *(v8s*)(Bgux+(size_t)FD*HD+i) = pack8(*(const v4f*)(Wu+i), *(const v4f*)(Wu+i+4));
  } else if (b < 26624) {
    long idx = (long)(b-18432)*256 + tid;     // v8 index over [HD][FD]
    long r = idx >> 10;                        // FD/8 = 1024
    int c8 = (int)(idx & 1023) * 8;
    const float* s = Wd + r*FD + c8;
    *(v8s*)(Wdx + r*KXD + c8) = pack8(*(const v4f*)s, *(const v4f*)(s+4));
  } else if (b < 26752) {
    long i = ((long)(b-26624)*256 + tid)*8;
    *(v8s*)(Agu+i) = pack8(*(const v4f*)(Ag+i), *(const v4f*)(Ag+i+4));
  } else if (b < 26880) {
    long i = ((long)(b-26752)*256 + tid)*8;
    *(v8s*)(Agu+(size_t)128*HD+i) = pack8(*(const v4f*)(Au+i), *(const v4f*)(Au+i+4));
  } else if (b < 27392) {
    long i = ((long)(b-26880)*256 + tid)*8;
    *(v8s*)(Bgb+i) = pack8(*(const v4f*)(Bg+i), *(const v4f*)(Bg+i+4));
  } else if (b < 27904) {
    long i = ((long)(b-27392)*256 + tid)*8;
    *(v8s*)(Bub+i) = pack8(*(const v4f*)(Bu+i), *(const v4f*)(Bu+i+4));
  } else if (b < 28416) {
    long i = ((long)(b-27904)*256 + tid)*8;
    *(v8s*)(Adb+i) = pack8(*(const v4f*)(Ad+i), *(const v4f*)(Ad+i+4));
  } else if (b < 28928) {
    long idx = (long)(b-28416)*256 + tid;     // 8 ext cols per thread
    int hrow = (int)(idx >> 6);
    int c8 = (int)(idx & 63) * 8;
    v8s o;
    if (c8 < 128) {
      int e = c8 >> 4, r0 = c8 & 15;
      const float* s = Bd + ((size_t)e*HD + hrow)*16 + r0;
      o = pack8(*(const v4f*)s, *(const v4f*)(s+4));
    } else {
      #pragma unroll
      for (int q = 0; q < 8; ++q) o[q] = 0;
    }
    *(v8s*)(Wdx + (size_t)hrow*KXD + FD + c8) = o;
  } else if (b < 30976) {
    long i = ((long)(b-28928)*256 + tid)*8;
    v4f z = {0.f,0.f,0.f,0.f};
    *(v4f*)(outz+i) = z; *(v4f*)(outz+i+4) = z;
  } else {
    long i = ((long)(b-30976)*256 + tid)*8;
    v4f z = {0.f,0.f,0.f,0.f};
    *(v4f*)(hAx+i) = z; *(v4f*)(hAx+i+4) = z;
  }
}

// ---------- router + gather ----------
__global__ __launch_bounds__(64)
void router_kernel(const float* __restrict__ h, const float* __restrict__ gw,
                   int* __restrict__ sel, int* __restrict__ count,
                   int* __restrict__ listTok, float* __restrict__ listW) {
  int t = blockIdx.x, lane = threadIdx.x;
  const float* hp = h + (size_t)t * HD;
  float acc[8] = {0,0,0,0,0,0,0,0};
  for (int i = lane; i < HD; i += 64) {
    float hv = hp[i];
    #pragma unroll
    for (int e = 0; e < 8; ++e) acc[e] += hv * gw[e*HD + i];
  }
  #pragma unroll
  for (int off = 32; off > 0; off >>= 1) {
    #pragma unroll
    for (int e = 0; e < 8; ++e) acc[e] += __shfl_xor(acc[e], off, 64);
  }
  if (lane == 0) {
    int e0 = -1, e1 = -1; float b0 = -1e30f, b1 = -1e30f;
    #pragma unroll
    for (int e = 0; e < 8; ++e) {
      float v = acc[e];
      if (v > b0) { b1 = b0; e1 = e0; b0 = v; e0 = e; }
      else if (v > b1) { b1 = v; e1 = e; }
    }
    float p1 = __expf(b1 - b0);            // p0 = 1
    float w0 = 1.f / (1.f + p1);
    float w1 = p1 * w0;
    sel[2*t] = e0; sel[2*t+1] = e1;
    int pos0 = atomicAdd(&count[e0], 1);
    listTok[e0*TT + pos0] = t;           listW[e0*TT + pos0] = w0;
    int pos1 = atomicAdd(&count[e1], 1);
    listTok[e1*TT + pos1] = t | (1<<20); listW[e1*TT + pos1] = w1;
  }
}

// ---------- 128x128x64 bf16 GEMM (m97 structure), C = A @ B^T, split-K atomic ----------
__global__ __launch_bounds__(256)
void gemm128a(const u16* __restrict__ A, const u16* __restrict__ B, float* __restrict__ Cout,
              int K, int ldc) {
  __shared__ u16 As[128*64];
  __shared__ u16 Bs[128*64];
  const int tid  = threadIdx.x;
  const int lane = tid & 63, wid = tid >> 6;
  const int gx = gridDim.x;
  const int lin = blockIdx.y * gx + blockIdx.x;
  const int chunk = (gx * gridDim.y) >> 3;
  const int wg = (lin & 7) * chunk + (lin >> 3);
  const int m0 = (wg % gx) * 128, n0 = (wg / gx) * 128;
  const int kc = K / gridDim.z;
  const int kbeg = blockIdx.z * kc;
  const int wr = wid >> 1, wc = wid & 1;
  const int lrow = lane >> 3, lcol = (lane & 7) * 8;
  v4f acc[4][4];
  #pragma unroll
  for (int mi = 0; mi < 4; ++mi)
    #pragma unroll
    for (int ni = 0; ni < 4; ++ni) acc[mi][ni] = (v4f){0.f,0.f,0.f,0.f};

  for (int k0 = kbeg; k0 < kbeg + kc; k0 += 64) {
    #pragma unroll
    for (int it = 0; it < 4; ++it) {
      int seg = wid*4 + it;
      int row = seg*8 + lrow;
      gload_lds16(A + (size_t)(m0+row)*K + k0 + lcol, As + seg*512);
      gload_lds16(B + (size_t)(n0+row)*K + k0 + lcol, Bs + seg*512);
    }
    __syncthreads();
    #pragma unroll
    for (int kk = 0; kk < 64; kk += 32) {
      v8s af[4], bfr[4];
      #pragma unroll
      for (int mi = 0; mi < 4; ++mi)
        af[mi] = *(const v8s*)(As + (wr*64 + mi*16 + (lane&15))*64 + kk + (lane>>4)*8);
      #pragma unroll
      for (int ni = 0; ni < 4; ++ni)
        bfr[ni] = *(const v8s*)(Bs + (wc*64 + ni*16 + (lane&15))*64 + kk + (lane>>4)*8);
      #pragma unroll
      for (int mi = 0; mi < 4; ++mi)
        #pragma unroll
        for (int ni = 0; ni < 4; ++ni)
          acc[mi][ni] = __builtin_amdgcn_mfma_f32_16x16x32_bf16(af[mi], bfr[ni], acc[mi][ni], 0, 0, 0);
    }
    __syncthreads();
  }

  #pragma unroll
  for (int mi = 0; mi < 4; ++mi)
    #pragma unroll
    for (int j = 0; j < 4; ++j) {
      int row = m0 + wr*64 + mi*16 + (lane>>4)*4 + j;
      size_t base = (size_t)row*ldc + n0 + wc*64 + (lane&15);
      #pragma unroll
      for (int ni = 0; ni < 4; ++ni)
        atomicAdd(&Cout[base + ni*16], acc[mi][ni][j]);
    }
}

// ---------- 256x256 8-phase bf16 GEMM, C = A @ B^T  (T1+T2+T3+T4+T5) ----------
// MODE 0: bf16 store. MODE 2: fp32 atomicAdd (split-K; C pre-zeroed).
template<int MODE>
__global__ __launch_bounds__(512, 2)
void gemm256(const u16* __restrict__ A, const u16* __restrict__ B, void* __restrict__ Cout,
             int ldk, int kchunk, int ldc) {
  __shared__ u16 lds[2][2][2][8192];
  const int tid = threadIdx.x, lane = tid & 63, wid = tid >> 6;
  const int gx = gridDim.x;
  const int nwg = gx * gridDim.y;
  const int lin = blockIdx.y * gx + blockIdx.x;
  const int chunk = nwg >> 3;                       // nwg % 8 == 0 by construction
  const int wg = (lin & 7) * chunk + (lin >> 3);    // bijective XCD swizzle
  const int m0 = (wg % gx) * 256, n0 = (wg / gx) * 256;
  const long kbeg = (long)blockIdx.z * kchunk;
  const int NK = kchunk >> 6, NI = NK >> 1;         // NK even
  const int wr = wid >> 2, wc = wid & 3;

  const int s_r = (wid << 4) + (lane >> 3);
  const int s_c = lane & 7;

  auto STAGE = [&](int slot, int ab, int half, const u16* M, int rc0, int kt) {
    const u16* g0 = M + (size_t)(rc0 + half*128 + s_r) * ldk + kbeg + kt*64 + ((s_c ^ (s_r & 7)) << 3);
    gload_lds16(g0, &lds[slot][ab][half][wid << 10]);
    const int r1 = s_r + 8;
    const u16* g1 = M + (size_t)(rc0 + half*128 + r1) * ldk + kbeg + kt*64 + ((s_c ^ (r1 & 7)) << 3);
    gload_lds16(g1, &lds[slot][ab][half][(wid << 10) + 512]);
  };
  auto LDA = [&](int slot, int mf, int c16b) -> v8s {
    int rr = (mf << 4) + (lane & 15);
    return *(const v8s*)&lds[slot][0][wr][rr*64 + (((c16b + (lane >> 4)) ^ (rr & 7)) << 3)];
  };
  auto LDB = [&](int slot, int nf, int c16b) -> v8s {
    int row = (wc << 6) + (nf << 4) + (lane & 15);
    int rr = row & 127;
    return *(const v8s*)&lds[slot][1][row >> 7][rr*64 + (((c16b + (lane >> 4)) ^ (rr & 7)) << 3)];
  };

  v4f acc[8][4];
  #pragma unroll
  for (int mf = 0; mf < 8; ++mf)
    #pragma unroll
    for (int nf = 0; nf < 4; ++nf) acc[mf][nf] = (v4f){0.f,0.f,0.f,0.f};

  STAGE(0,1,0,B,n0,0); STAGE(0,1,1,B,n0,0);
  STAGE(0,0,0,A,m0,0); STAGE(0,0,1,A,m0,0);
  STAGE(1,1,0,B,n0,1); STAGE(1,1,1,B,n0,1);
  vm_wait4();
  barrier_pin();

  for (int i = 0; i < NI; ++i) {
    const int kt0 = 2*i, kt1 = kt0 + 1;
    const int kt2c = (kt0 + 2 < NK) ? kt0 + 2 : kt0;
    const bool s45 = (kt0 + 2 < NK), s67 = (kt1 + 2 < NK);
    v8s bf[4][2], af[2][2];
    // ---- phase 0 (slot0, q0)
    #pragma unroll
    for (int nf = 0; nf < 4; ++nf) { bf[nf][0] = LDB(0,nf,0); bf[nf][1] = LDB(0,nf,4); }
    af[0][0]=LDA(0,0,0); af[0][1]=LDA(0,0,4); af[1][0]=LDA(0,1,0); af[1][1]=LDA(0,1,4);
    STAGE(1,0,0,A,m0,kt1);
    barrier_pin(); mmq<0>(acc,af,bf); barrier_pin();
    // ---- phase 1 (slot0, q1)
    af[0][0]=LDA(0,2,0); af[0][1]=LDA(0,2,4); af[1][0]=LDA(0,3,0); af[1][1]=LDA(0,3,4);
    STAGE(1,0,1,A,m0,kt1);
    barrier_pin(); mmq<1>(acc,af,bf); barrier_pin();
    // ---- phase 2 (slot0, q2)
    af[0][0]=LDA(0,4,0); af[0][1]=LDA(0,4,4); af[1][0]=LDA(0,5,0); af[1][1]=LDA(0,5,4);
    STAGE(0,1,0,B,n0,kt2c);
    barrier_pin(); mmq<2>(acc,af,bf); barrier_pin();
    // ---- phase 3 (slot0, q3)
    af[0][0]=LDA(0,6,0); af[0][1]=LDA(0,6,4); af[1][0]=LDA(0,7,0); af[1][1]=LDA(0,7,4);
    STAGE(0,1,1,B,n0,kt2c);
    vm_wait4();
    barrier_pin(); mmq<3>(acc,af,bf); barrier_pin();
    // ---- phase 4 (slot1, q0)
    #pragma unroll
    for (int nf = 0; nf < 4; ++nf) { bf[nf][0] = LDB(1,nf,0); bf[nf][1] = LDB(1,nf,4); }
    af[0][0]=LDA(1,0,0); af[0][1]=LDA(1,0,4); af[1][0]=LDA(1,1,0); af[1][1]=LDA(1,1,4);
    if (s45) STAGE(0,0,0,A,m0,kt0+2);
    barrier_pin(); mmq<0>(acc,af,bf); barrier_pin();
    // ---- phase 5 (slot1, q1)
    af[0][0]=LDA(1,2,0); af[0][1]=LDA(1,2,4); af[1][0]=LDA(1,3,0); af[1][1]=LDA(1,3,4);
    if (s45) STAGE(0,0,1,A,m0,kt0+2);
    barrier_pin(); mmq<1>(acc,af,bf); barrier_pin();
    // ---- phase 6 (slot1, q2)
    af[0][0]=LDA(1,4,0); af[0][1]=LDA(1,4,4); af[1][0]=LDA(1,5,0); af[1][1]=LDA(1,5,4);
    if (s67) STAGE(1,1,0,B,n0,kt1+2);
    barrier_pin(); mmq<2>(acc,af,bf); barrier_pin();
    // ---- phase 7 (slot1, q3)
    af[0][0]=LDA(1,6,0); af[0][1]=LDA(1,6,4); af[1][0]=LDA(1,7,0); af[1][1]=LDA(1,7,4);
    if (s67) STAGE(1,1,1,B,n0,kt1+2);
    vm_wait4();
    barrier_pin(); mmq<3>(acc,af,bf); barrier_pin();
  }
  vm_wait0();

  if (MODE == 0) {
    u16* C = (u16*)Cout;
    #pragma unroll
    for (int mf = 0; mf < 8; ++mf)
      #pragma unroll
      for (int j = 0; j < 4; ++j) {
        int row = m0 + wr*128 + mf*16 + (lane>>4)*4 + j;
        size_t base = (size_t)row*ldc + n0 + wc*64 + (lane&15);
        #pragma unroll
        for (int nf = 0; nf < 4; ++nf)
          C[base + nf*16] = f2b(acc[mf][nf][j]);
      }
  } else {
    float* C = (float*)Cout;
    #pragma unroll
    for (int mf = 0; mf < 8; ++mf)
      #pragma unroll
      for (int j = 0; j < 4; ++j) {
        int row = m0 + wr*128 + mf*16 + (lane>>4)*4 + j;
        size_t base = (size_t)row*ldc + n0 + wc*64 + (lane&15);
        #pragma unroll
        for (int nf = 0; nf < 4; ++nf)
          atomicAdd(&C[base + nf*16], acc[mf][nf][j]);
      }
  }
}

// ---------- expert kernel (bf16 weights, direct global B-fragments) ----------
// grid (128 groups, NE, 4 f-blocks). Per block: 16 tokens x 2048 f-cols.
static constexpr int HA_LD = 40;
static constexpr int AW_LD = 72;
static constexpr int CT_LD = 72;

__global__ __launch_bounds__(256)
void expert_kernel(const u16* __restrict__ CGU,                                // [TT][NXE]
                   const float* __restrict__ hAx,                              // [TT][256] fp32
                   const u16* __restrict__ Bgb, const u16* __restrict__ Bub,   // [E][F][16] bf16
                   const u16* __restrict__ Adb,                                // [E][16][F] bf16
                   const int* __restrict__ count, const int* __restrict__ listTok,
                   const float* __restrict__ listW,
                   u16* __restrict__ actw0, u16* __restrict__ actw1,           // [TT+1][F]
                   float* __restrict__ cC) {                                   // [TT+1][2][16]
  const int e = blockIdx.y, g = blockIdx.x, fb = blockIdx.z;
  const int n = count[e];
  if (g*16 >= n) return;
  const int tid = threadIdx.x, lane = tid & 63, w = tid >> 6;
  __shared__ u16 hAg[16*HA_LD], hAu[16*HA_LD];
  __shared__ u16 AWs[4][16*AW_LD];
  __shared__ u16 cgT[4][16*CT_LD], cuT[4][16*CT_LD];
  __shared__ int sTok[16], sSlot[16];
  __shared__ float sW[16];
  __shared__ float dAred[4][256];

  if (tid < 16) {
    int idx = g*16 + tid;
    if (idx < n) {
      int ent = listTok[e*TT + idx];
      sTok[tid] = ent & 0xFFFF; sSlot[tid] = (ent >> 20) & 1; sW[tid] = listW[e*TT + idx];
    } else { sTok[tid] = TT; sSlot[tid] = 0; sW[tid] = 0.f; }
  }
  __syncthreads();
  if (tid < 128) {   // stage hA (both tensors) from hAx fp32, zero-pad K 16..31
    int tensor = tid >> 6;
    int sub = tid & 63;
    int row = sub >> 2, c8 = (sub & 3) * 8;
    int trd = min(sTok[row], TT - 1);
    u16 vals[8];
    if (c8 < 16) {
      const float* src = hAx + (size_t)trd*256 + tensor*128 + e*NR + c8;
      v4f a = *(const v4f*)src, b = *(const v4f*)(src + 4);
      v8s p = pack8(a, b);
      #pragma unroll
      for (int q = 0; q < 8; ++q) vals[q] = (u16)p[q];
    } else {
      #pragma unroll
      for (int q = 0; q < 8; ++q) vals[q] = 0;
    }
    u16* dst = (tensor ? hAu : hAg) + row*HA_LD + c8;
    #pragma unroll
    for (int q = 0; q < 8; ++q) dst[q] = vals[q];
  }
  __syncthreads();

  int tR[4], slR[4]; float wR[4];
  #pragma unroll
  for (int j = 0; j < 4; ++j) {
    int r = (lane>>4)*4 + j;
    tR[j] = sTok[r]; slR[j] = sSlot[r]; wR[j] = sW[r];
  }
  const int khalf = lane >> 4;
  v8s afg = *(const v8s*)(hAg + (lane&15)*HA_LD + khalf*8);
  v8s afu = *(const v8s*)(hAu + (lane&15)*HA_LD + khalf*8);
  v4f accDA = (v4f){0.f,0.f,0.f,0.f};
  u16* aww = AWs[w]; u16* cgw = cgT[w]; u16* cuw = cuT[w];
  const v8s zero8 = {0,0,0,0,0,0,0,0};
  const u16* BgE = Bgb + (size_t)e*FD*16;
  const u16* BuE = Bub + (size_t)e*FD*16;
  const u16* AdE = Adb + (size_t)e*16*FD;

  const int ch_end = fb*32 + 32;
  for (int ch = fb*32 + w; ch < ch_end; ch += 4) {   // 64-wide f-chunks, wave-private
    int f0 = ch * 64;
    { // stage common gate/up tile [16 tok][64 f] into LDS (v8s coalesced)
      int srow = lane >> 3, c8 = (lane & 7) * 8;
      #pragma unroll
      for (int rr = 0; rr < 2; ++rr) {
        int row = srow + rr*8;
        size_t trd = (size_t)min(sTok[row], TT - 1);
        *(v8s*)(cgw + row*CT_LD + c8) = *(const v8s*)(CGU + trd*NXE + f0 + c8);
        *(v8s*)(cuw + row*CT_LD + c8) = *(const v8s*)(CGU + trd*NXE + CU_OFF + f0 + c8);
      }
    }
    v4f dg[4], du[4];
    #pragma unroll
    for (int nf = 0; nf < 4; ++nf) {   // B-fragments direct from global bf16 (L2-hot)
      int f = f0 + nf*16 + (lane & 15);
      v8s bgf = (khalf < 2) ? *(const v8s*)(BgE + (size_t)f*16 + khalf*8) : zero8;
      dg[nf] = __builtin_amdgcn_mfma_f32_16x16x32_bf16(afg, bgf, (v4f){0.f,0.f,0.f,0.f}, 0, 0, 0);
      v8s buf = (khalf < 2) ? *(const v8s*)(BuE + (size_t)f*16 + khalf*8) : zero8;
      du[nf] = __builtin_amdgcn_mfma_f32_16x16x32_bf16(afu, buf, (v4f){0.f,0.f,0.f,0.f}, 0, 0, 0);
    }
    #pragma unroll
    for (int nf = 0; nf < 4; ++nf) {
      #pragma unroll
      for (int j = 0; j < 4; ++j) {
        int rj = (lane>>4)*4 + j;
        int fi = nf*16 + (lane&15);
        float cgv = b2f(cgw[rj*CT_LD + fi]);
        float cuv = b2f(cuw[rj*CT_LD + fi]);
        float gv = cgv + 2.f * dg[nf][j];
        float uv = cuv + 2.f * du[nf][j];
        float a  = gv / (1.f + __expf(-gv)) * uv;   // silu(g)*u
        u16 ab = f2b(wR[j] * a);
        (slR[j] ? actw1 : actw0)[(size_t)tR[j]*FD + f0 + fi] = ab;
        aww[rj*AW_LD + fi] = ab;
      }
    }
    #pragma unroll
    for (int ks = 0; ks < 2; ++ks) {   // dA accumulate: [16 tok] x [16 r] over K=64
      v8s aA = *(const v8s*)(aww + (lane&15)*AW_LD + ks*32 + khalf*8);
      v8s bA = *(const v8s*)(AdE + (size_t)(lane&15)*FD + f0 + ks*32 + khalf*8);
      accDA = __builtin_amdgcn_mfma_f32_16x16x32_bf16(aA, bA, accDA, 0, 0, 0);
    }
  }
  #pragma unroll
  for (int j = 0; j < 4; ++j)
    dAred[w][((lane>>4)*4 + j)*16 + (lane&15)] = accDA[j];
  __syncthreads();
  {
    int row = tid >> 4, col = tid & 15;
    float s2 = dAred[0][row*16+col] + dAred[1][row*16+col] + dAred[2][row*16+col] + dAred[3][row*16+col];
    atomicAdd(&cC[((size_t)sTok[row]*2 + sSlot[row])*16 + col], 2.f * s2);
  }
}

// ---------- combine: abx[t] = [actw0+actw1 (bf16), scattered c coefs, zeros] ----------
__global__ __launch_bounds__(256)
void combine2_kernel(const u16* __restrict__ a0, const u16* __restrict__ a1,
                     const float* __restrict__ cC, const int* __restrict__ sel,
                     u16* __restrict__ abx) {
  int t = blockIdx.x, tid = threadIdx.x;
  const u16* p0 = a0 + (size_t)t * FD;
  const u16* p1 = a1 + (size_t)t * FD;
  u16* po = abx + (size_t)t * KXD;
  for (int i = tid * 8; i < FD; i += 256 * 8) {
    v8s x = *(const v8s*)(p0 + i);
    v8s y = *(const v8s*)(p1 + i);
    v8s o;
    #pragma unroll
    for (int j = 0; j < 8; ++j) o[j] = (short)f2b(b2f((u16)x[j]) + b2f((u16)y[j]));
    *(v8s*)(po + i) = o;
  }
  for (int c = tid; c < 512; c += 256) {  // ext cols; c>=128 zeroed
    float v = 0.f;
    if (c < 128) {
      int e_i = c >> 4, r = c & 15;
      if (sel[2*t]     == e_i) v += cC[((size_t)t*2 + 0)*16 + r];
      if (sel[2*t + 1] == e_i) v += cC[((size_t)t*2 + 1)*16 + r];
    }
    po[FD + c] = f2b(v);
  }
}

// ---------- launch ----------
extern "C" void kernel_launch(void* const* d_in, const int* in_sizes, int n_in,
                              void* d_out, int out_size, void* d_ws, size_t ws_size,
                              hipStream_t stream) {
  (void)in_sizes; (void)n_in; (void)out_size; (void)ws_size;
  const float* h  = (const float*)d_in[0];
  const float* gw = (const float*)d_in[1];
  const float* Wg = (const float*)d_in[2];
  const float* Wu = (const float*)d_in[3];
  const float* Wd = (const float*)d_in[4];
  const float* Ag = (const float*)d_in[5];
  const float* Bg = (const float*)d_in[6];
  const float* Au = (const float*)d_in[7];
  const float* Bu = (const float*)d_in[8];
  const float* Ad = (const float*)d_in[9];
  const float* Bd = (const float*)d_in[10];

  char* ws = (char*)d_ws;
  size_t off = 0;
  auto alloc = [&](size_t bytes) { size_t c = off; off += (bytes + 255) & ~(size_t)255; return c; };
  u16*  hb     = (u16*)(ws + alloc((size_t)TT*HD*2));             // 8 MB
  u16*  Bgux   = (u16*)(ws + alloc((size_t)(TT+1)*FD*2*2));       // 67.2 MB [Wg|Wu]; later actw0/actw1
  u16*  Agu    = (u16*)(ws + alloc((size_t)256*HD*2));            // 1 MB [Ag all|Au all]
  u16*  Wdx    = (u16*)(ws + alloc((size_t)HD*KXD*2));            // 35.7 MB [HD][KXD]
  u16*  CGU    = (u16*)(ws + alloc((size_t)TT*NXE*2));            // 64 MB [TT][NXE]; later abx [TT][KXD]
  u16*  Bgb    = (u16*)(ws + alloc((size_t)NE*FD*16*2));          // 2 MB bf16
  u16*  Bub    = (u16*)(ws + alloc((size_t)NE*FD*16*2));          // 2 MB
  u16*  Adb    = (u16*)(ws + alloc((size_t)NE*16*FD*2));          // 2 MB
  float* hAx   = (float*)(ws + alloc((size_t)TT*256*4));          // 2 MB
  float* cC    = (float*)(ws + alloc((size_t)(TT+1)*2*16*4));
  int*  sel    = (int*)(ws + alloc((size_t)TT*2*4));
  int*  count  = (int*)(ws + alloc(256));
  int*  listTok= (int*)(ws + alloc((size_t)NE*TT*4));
  float* listW = (float*)(ws + alloc((size_t)NE*TT*4));
  u16*  actw0  = Bgux;                                  // alias: Bgux dead after merged GEMM
  u16*  actw1  = Bgux + (size_t)(TT+1)*FD;
  u16*  abx    = CGU;                                   // alias: CGU dead after expert_kernel

  hipMemsetAsync(count, 0, NE*sizeof(int), stream);
  hipMemsetAsync(cC, 0, (size_t)(TT+1)*2*16*4, stream);

  // one mega-prep: all casts + Bd-ext + d_out/hAx zero
  prep_kernel<<<PREP_BLOCKS, 256, 0, stream>>>(h, Wg, Wu, Wd, Ag, Au, Bg, Bu, Ad, Bd,
                                               hb, Bgux, Agu, Wdx, Bgb, Bub, Adb,
                                               (float*)d_out, hAx);

  router_kernel<<<TT, 64, 0, stream>>>(h, gw, sel, count, listTok, listW);

  // hAx = h @ [Ag;Au]^T  (M=2048, N=256, K=2048, split-K=8 -> 256 blocks)
  gemm128a<<<dim3(16, 2, 8), 256, 0, stream>>>(hb, Agu, hAx, HD, 256);

  // CGU = h @ [Wg|Wu]^T  (M=2048, N=16384, K=2048) -> 512 blocks = 2 exact rounds
  gemm256<0><<<dim3(8, 64, 1), 512, 0, stream>>>(hb, Bgux, CGU, HD, HD, NXE);

  // per-expert: deltas, act, weighted act into slot buffers (aliasing Bgux), c coefs
  expert_kernel<<<dim3(128, NE, 4), 256, 0, stream>>>(CGU, hAx, Bgb, Bub, Adb, count, listTok, listW,
                                                      actw0, actw1, cC);

  // abx = [actw0+actw1, c-scatter, zeros]  (writes into the dead CGU region)
  combine2_kernel<<<TT, 256, 0, stream>>>(actw0, actw1, cC, sel, abx);

  // out = abx @ Wdx^T  (M=2048, N=2048, K=8704, split-K=4 -> 256 blocks = 1 round)
  gemm256<2><<<dim3(8, 8, 4), 512, 0, stream>>>(abx, Wdx, d_out, KXD, KXD/4, HD);
}

// Round 7
// 491.285 us; speedup vs baseline: 1.4619x; 1.0349x over previous
//
#include <hip/hip_runtime.h>
#include <hip/hip_bf16.h>

typedef __attribute__((ext_vector_type(8))) short v8s;   // 8 x bf16 (as i16)
typedef __attribute__((ext_vector_type(4))) float v4f;
typedef unsigned short u16;

static constexpr int TT = 2048;        // tokens
static constexpr int HD = 2048;        // hidden
static constexpr int FD = 8192;        // ffn dim
static constexpr int NE = 8;           // experts
static constexpr int NR = 16;          // lora rank
static constexpr int NXE = 2*FD;       // 16384: merged [Wg | Wu] cols
static constexpr int CU_OFF = FD;      // up offset inside CGU row
static constexpr int KXD = FD + 512;   // 8704 = 136*64 ext K for down GEMM (34*64*4)

// ---------- helpers ----------
__device__ __forceinline__ u16 f2b(float f) {            // fp32 -> bf16 RNE
  union { float f; unsigned u; } v; v.f = f;
  unsigned r = v.u + 0x7FFFu + ((v.u >> 16) & 1u);
  return (u16)(r >> 16);
}
__device__ __forceinline__ float b2f(u16 h) {
  union { unsigned u; float f; } v; v.u = ((unsigned)h) << 16;
  return v.f;
}
__device__ __forceinline__ v8s pack8(v4f a, v4f b) {
  v8s r;
  r[0]=(short)f2b(a.x); r[1]=(short)f2b(a.y); r[2]=(short)f2b(a.z); r[3]=(short)f2b(a.w);
  r[4]=(short)f2b(b.x); r[5]=(short)f2b(b.y); r[6]=(short)f2b(b.z); r[7]=(short)f2b(b.w);
  return r;
}
__device__ __forceinline__ void gload_lds16(const void* g, void* l) {
  __builtin_amdgcn_global_load_lds(
      (const __attribute__((address_space(1))) unsigned int*)g,
      (__attribute__((address_space(3))) unsigned int*)l, 16, 0, 0);
}
__device__ __forceinline__ void barrier_pin() {
  __builtin_amdgcn_s_barrier();
  __builtin_amdgcn_sched_barrier(0);
}
__device__ __forceinline__ void vm_wait4() { asm volatile("s_waitcnt vmcnt(4)" ::: "memory"); }
__device__ __forceinline__ void vm_wait0() { asm volatile("s_waitcnt vmcnt(0)" ::: "memory"); }

template<int Q>
__device__ __forceinline__ void mmq(v4f (&acc)[8][4], const v8s (&af)[2][2], const v8s (&bf)[4][2]) {
  __builtin_amdgcn_s_setprio(1);
  #pragma unroll
  for (int m2 = 0; m2 < 2; ++m2)
    #pragma unroll
    for (int nf = 0; nf < 4; ++nf) {
      acc[Q*2+m2][nf] = __builtin_amdgcn_mfma_f32_16x16x32_bf16(af[m2][0], bf[nf][0], acc[Q*2+m2][nf], 0, 0, 0);
      acc[Q*2+m2][nf] = __builtin_amdgcn_mfma_f32_16x16x32_bf16(af[m2][1], bf[nf][1], acc[Q*2+m2][nf], 0, 0, 0);
    }
  __builtin_amdgcn_s_setprio(0);
}

// ---------- mega prep: all casts + Bd-ext + output/hAx zeroing, one launch ----------
static constexpr int PREP_BLOCKS = 31232;
__global__ __launch_bounds__(256)
void prep_kernel(const float* __restrict__ h, const float* __restrict__ Wg,
                 const float* __restrict__ Wu, const float* __restrict__ Wd,
                 const float* __restrict__ Ag, const float* __restrict__ Au,
                 const float* __restrict__ Bg, const float* __restrict__ Bu,
                 const float* __restrict__ Ad, const float* __restrict__ Bd,
                 u16* __restrict__ hb, u16* __restrict__ Bgux, u16* __restrict__ Agu,
                 u16* __restrict__ Wdx, u16* __restrict__ Bgb, u16* __restrict__ Bub,
                 u16* __restrict__ Adb, float* __restrict__ outz, float* __restrict__ hAx) {
  const int b = blockIdx.x, tid = threadIdx.x;
  if (b < 2048) {
    long i = ((long)b*256 + tid)*8;
    *(v8s*)(hb+i) = pack8(*(const v4f*)(h+i), *(const v4f*)(h+i+4));
  } else if (b < 10240) {
    long i = ((long)(b-2048)*256 + tid)*8;
    *(v8s*)(Bgux+i) = pack8(*(const v4f*)(Wg+i), *(const v4f*)(Wg+i+4));
  } else if (b < 18432) {
    long i = ((long)(b-10240)*256 + tid)*8;
    *(v8s*)(Bgux+(size_t)FD*HD+i) = pack8(*(const v4f*)(Wu+i), *(const v4f*)(Wu+i+4));
  } else if (b < 26624) {
    long idx = (long)(b-18432)*256 + tid;     // v8 index over [HD][FD]
    long r = idx >> 10;                        // FD/8 = 1024
    int c8 = (int)(idx & 1023) * 8;
    const float* s = Wd + r*FD + c8;
    *(v8s*)(Wdx + r*KXD + c8) = pack8(*(const v4f*)s, *(const v4f*)(s+4));
  } else if (b < 26752) {
    long i = ((long)(b-26624)*256 + tid)*8;
    *(v8s*)(Agu+i) = pack8(*(const v4f*)(Ag+i), *(const v4f*)(Ag+i+4));
  } else if (b < 26880) {
    long i = ((long)(b-26752)*256 + tid)*8;
    *(v8s*)(Agu+(size_t)128*HD+i) = pack8(*(const v4f*)(Au+i), *(const v4f*)(Au+i+4));
  } else if (b < 27392) {
    long i = ((long)(b-26880)*256 + tid)*8;
    *(v8s*)(Bgb+i) = pack8(*(const v4f*)(Bg+i), *(const v4f*)(Bg+i+4));
  } else if (b < 27904) {
    long i = ((long)(b-27392)*256 + tid)*8;
    *(v8s*)(Bub+i) = pack8(*(const v4f*)(Bu+i), *(const v4f*)(Bu+i+4));
  } else if (b < 28416) {
    long i = ((long)(b-27904)*256 + tid)*8;
    *(v8s*)(Adb+i) = pack8(*(const v4f*)(Ad+i), *(const v4f*)(Ad+i+4));
  } else if (b < 28928) {
    long idx = (long)(b-28416)*256 + tid;     // 8 ext cols per thread
    int hrow = (int)(idx >> 6);
    int c8 = (int)(idx & 63) * 8;
    v8s o;
    if (c8 < 128) {
      int e = c8 >> 4, r0 = c8 & 15;
      const float* s = Bd + ((size_t)e*HD + hrow)*16 + r0;
      o = pack8(*(const v4f*)s, *(const v4f*)(s+4));
    } else {
      #pragma unroll
      for (int q = 0; q < 8; ++q) o[q] = 0;
    }
    *(v8s*)(Wdx + (size_t)hrow*KXD + FD + c8) = o;
  } else if (b < 30976) {
    long i = ((long)(b-28928)*256 + tid)*8;
    v4f z = {0.f,0.f,0.f,0.f};
    *(v4f*)(outz+i) = z; *(v4f*)(outz+i+4) = z;
  } else {
    long i = ((long)(b-30976)*256 + tid)*8;
    v4f z = {0.f,0.f,0.f,0.f};
    *(v4f*)(hAx+i) = z; *(v4f*)(hAx+i+4) = z;
  }
}

// ---------- router + gather ----------
__global__ __launch_bounds__(64)
void router_kernel(const float* __restrict__ h, const float* __restrict__ gw,
                   int* __restrict__ sel, int* __restrict__ count,
                   int* __restrict__ listTok, float* __restrict__ listW) {
  int t = blockIdx.x, lane = threadIdx.x;
  const float* hp = h + (size_t)t * HD;
  float acc[8] = {0,0,0,0,0,0,0,0};
  for (int i = lane; i < HD; i += 64) {
    float hv = hp[i];
    #pragma unroll
    for (int e = 0; e < 8; ++e) acc[e] += hv * gw[e*HD + i];
  }
  #pragma unroll
  for (int off = 32; off > 0; off >>= 1) {
    #pragma unroll
    for (int e = 0; e < 8; ++e) acc[e] += __shfl_xor(acc[e], off, 64);
  }
  if (lane == 0) {
    int e0 = -1, e1 = -1; float b0 = -1e30f, b1 = -1e30f;
    #pragma unroll
    for (int e = 0; e < 8; ++e) {
      float v = acc[e];
      if (v > b0) { b1 = b0; e1 = e0; b0 = v; e0 = e; }
      else if (v > b1) { b1 = v; e1 = e; }
    }
    float p1 = __expf(b1 - b0);            // p0 = 1
    float w0 = 1.f / (1.f + p1);
    float w1 = p1 * w0;
    sel[2*t] = e0; sel[2*t+1] = e1;
    int pos0 = atomicAdd(&count[e0], 1);
    listTok[e0*TT + pos0] = t;           listW[e0*TT + pos0] = w0;
    int pos1 = atomicAdd(&count[e1], 1);
    listTok[e1*TT + pos1] = t | (1<<20); listW[e1*TT + pos1] = w1;
  }
}

// ---------- 128x128x64 bf16 GEMM (m97 structure), C = A @ B^T, split-K atomic ----------
__global__ __launch_bounds__(256)
void gemm128a(const u16* __restrict__ A, const u16* __restrict__ B, float* __restrict__ Cout,
              int K, int ldc) {
  __shared__ u16 As[128*64];
  __shared__ u16 Bs[128*64];
  const int tid  = threadIdx.x;
  const int lane = tid & 63, wid = tid >> 6;
  const int gx = gridDim.x;
  const int lin = blockIdx.y * gx + blockIdx.x;
  const int chunk = (gx * gridDim.y) >> 3;
  const int wg = (lin & 7) * chunk + (lin >> 3);
  const int m0 = (wg % gx) * 128, n0 = (wg / gx) * 128;
  const int kc = K / gridDim.z;
  const int kbeg = blockIdx.z * kc;
  const int wr = wid >> 1, wc = wid & 1;
  const int lrow = lane >> 3, lcol = (lane & 7) * 8;
  v4f acc[4][4];
  #pragma unroll
  for (int mi = 0; mi < 4; ++mi)
    #pragma unroll
    for (int ni = 0; ni < 4; ++ni) acc[mi][ni] = (v4f){0.f,0.f,0.f,0.f};

  for (int k0 = kbeg; k0 < kbeg + kc; k0 += 64) {
    #pragma unroll
    for (int it = 0; it < 4; ++it) {
      int seg = wid*4 + it;
      int row = seg*8 + lrow;
      gload_lds16(A + (size_t)(m0+row)*K + k0 + lcol, As + seg*512);
      gload_lds16(B + (size_t)(n0+row)*K + k0 + lcol, Bs + seg*512);
    }
    __syncthreads();
    #pragma unroll
    for (int kk = 0; kk < 64; kk += 32) {
      v8s af[4], bfr[4];
      #pragma unroll
      for (int mi = 0; mi < 4; ++mi)
        af[mi] = *(const v8s*)(As + (wr*64 + mi*16 + (lane&15))*64 + kk + (lane>>4)*8);
      #pragma unroll
      for (int ni = 0; ni < 4; ++ni)
        bfr[ni] = *(const v8s*)(Bs + (wc*64 + ni*16 + (lane&15))*64 + kk + (lane>>4)*8);
      #pragma unroll
      for (int mi = 0; mi < 4; ++mi)
        #pragma unroll
        for (int ni = 0; ni < 4; ++ni)
          acc[mi][ni] = __builtin_amdgcn_mfma_f32_16x16x32_bf16(af[mi], bfr[ni], acc[mi][ni], 0, 0, 0);
    }
    __syncthreads();
  }

  #pragma unroll
  for (int mi = 0; mi < 4; ++mi)
    #pragma unroll
    for (int j = 0; j < 4; ++j) {
      int row = m0 + wr*64 + mi*16 + (lane>>4)*4 + j;
      size_t base = (size_t)row*ldc + n0 + wc*64 + (lane&15);
      #pragma unroll
      for (int ni = 0; ni < 4; ++ni)
        atomicAdd(&Cout[base + ni*16], acc[mi][ni][j]);
    }
}

// ---------- 256x256 8-phase bf16 GEMM, C = A @ B^T  (T1+T2+T3+T4+T5) ----------
// MODE 0: bf16 store. MODE 2: fp32 atomicAdd (split-K; C pre-zeroed).
template<int MODE>
__global__ __launch_bounds__(512, 2)
void gemm256(const u16* __restrict__ A, const u16* __restrict__ B, void* __restrict__ Cout,
             int ldk, int kchunk, int ldc) {
  __shared__ u16 lds[2][2][2][8192];
  const int tid = threadIdx.x, lane = tid & 63, wid = tid >> 6;
  const int gx = gridDim.x;
  const int nwg = gx * gridDim.y;
  const int lin = blockIdx.y * gx + blockIdx.x;
  const int chunk = nwg >> 3;                       // nwg % 8 == 0 by construction
  const int wg = (lin & 7) * chunk + (lin >> 3);    // bijective XCD swizzle
  const int m0 = (wg % gx) * 256, n0 = (wg / gx) * 256;
  const long kbeg = (long)blockIdx.z * kchunk;
  const int NK = kchunk >> 6, NI = NK >> 1;         // NK even
  const int wr = wid >> 2, wc = wid & 3;

  const int s_r = (wid << 4) + (lane >> 3);
  const int s_c = lane & 7;

  auto STAGE = [&](int slot, int ab, int half, const u16* M, int rc0, int kt) {
    const u16* g0 = M + (size_t)(rc0 + half*128 + s_r) * ldk + kbeg + kt*64 + ((s_c ^ (s_r & 7)) << 3);
    gload_lds16(g0, &lds[slot][ab][half][wid << 10]);
    const int r1 = s_r + 8;
    const u16* g1 = M + (size_t)(rc0 + half*128 + r1) * ldk + kbeg + kt*64 + ((s_c ^ (r1 & 7)) << 3);
    gload_lds16(g1, &lds[slot][ab][half][(wid << 10) + 512]);
  };
  auto LDA = [&](int slot, int mf, int c16b) -> v8s {
    int rr = (mf << 4) + (lane & 15);
    return *(const v8s*)&lds[slot][0][wr][rr*64 + (((c16b + (lane >> 4)) ^ (rr & 7)) << 3)];
  };
  auto LDB = [&](int slot, int nf, int c16b) -> v8s {
    int row = (wc << 6) + (nf << 4) + (lane & 15);
    int rr = row & 127;
    return *(const v8s*)&lds[slot][1][row >> 7][rr*64 + (((c16b + (lane >> 4)) ^ (rr & 7)) << 3)];
  };

  v4f acc[8][4];
  #pragma unroll
  for (int mf = 0; mf < 8; ++mf)
    #pragma unroll
    for (int nf = 0; nf < 4; ++nf) acc[mf][nf] = (v4f){0.f,0.f,0.f,0.f};

  STAGE(0,1,0,B,n0,0); STAGE(0,1,1,B,n0,0);
  STAGE(0,0,0,A,m0,0); STAGE(0,0,1,A,m0,0);
  STAGE(1,1,0,B,n0,1); STAGE(1,1,1,B,n0,1);
  vm_wait4();
  barrier_pin();

  for (int i = 0; i < NI; ++i) {
    const int kt0 = 2*i, kt1 = kt0 + 1;
    const int kt2c = (kt0 + 2 < NK) ? kt0 + 2 : kt0;
    const bool s45 = (kt0 + 2 < NK), s67 = (kt1 + 2 < NK);
    v8s bf[4][2], af[2][2];
    // ---- phase 0 (slot0, q0)
    #pragma unroll
    for (int nf = 0; nf < 4; ++nf) { bf[nf][0] = LDB(0,nf,0); bf[nf][1] = LDB(0,nf,4); }
    af[0][0]=LDA(0,0,0); af[0][1]=LDA(0,0,4); af[1][0]=LDA(0,1,0); af[1][1]=LDA(0,1,4);
    STAGE(1,0,0,A,m0,kt1);
    barrier_pin(); mmq<0>(acc,af,bf); barrier_pin();
    // ---- phase 1 (slot0, q1)
    af[0][0]=LDA(0,2,0); af[0][1]=LDA(0,2,4); af[1][0]=LDA(0,3,0); af[1][1]=LDA(0,3,4);
    STAGE(1,0,1,A,m0,kt1);
    barrier_pin(); mmq<1>(acc,af,bf); barrier_pin();
    // ---- phase 2 (slot0, q2)
    af[0][0]=LDA(0,4,0); af[0][1]=LDA(0,4,4); af[1][0]=LDA(0,5,0); af[1][1]=LDA(0,5,4);
    STAGE(0,1,0,B,n0,kt2c);
    barrier_pin(); mmq<2>(acc,af,bf); barrier_pin();
    // ---- phase 3 (slot0, q3)
    af[0][0]=LDA(0,6,0); af[0][1]=LDA(0,6,4); af[1][0]=LDA(0,7,0); af[1][1]=LDA(0,7,4);
    STAGE(0,1,1,B,n0,kt2c);
    vm_wait4();
    barrier_pin(); mmq<3>(acc,af,bf); barrier_pin();
    // ---- phase 4 (slot1, q0)
    #pragma unroll
    for (int nf = 0; nf < 4; ++nf) { bf[nf][0] = LDB(1,nf,0); bf[nf][1] = LDB(1,nf,4); }
    af[0][0]=LDA(1,0,0); af[0][1]=LDA(1,0,4); af[1][0]=LDA(1,1,0); af[1][1]=LDA(1,1,4);
    if (s45) STAGE(0,0,0,A,m0,kt0+2);
    barrier_pin(); mmq<0>(acc,af,bf); barrier_pin();
    // ---- phase 5 (slot1, q1)
    af[0][0]=LDA(1,2,0); af[0][1]=LDA(1,2,4); af[1][0]=LDA(1,3,0); af[1][1]=LDA(1,3,4);
    if (s45) STAGE(0,0,1,A,m0,kt0+2);
    barrier_pin(); mmq<1>(acc,af,bf); barrier_pin();
    // ---- phase 6 (slot1, q2)
    af[0][0]=LDA(1,4,0); af[0][1]=LDA(1,4,4); af[1][0]=LDA(1,5,0); af[1][1]=LDA(1,5,4);
    if (s67) STAGE(1,1,0,B,n0,kt1+2);
    barrier_pin(); mmq<2>(acc,af,bf); barrier_pin();
    // ---- phase 7 (slot1, q3)
    af[0][0]=LDA(1,6,0); af[0][1]=LDA(1,6,4); af[1][0]=LDA(1,7,0); af[1][1]=LDA(1,7,4);
    if (s67) STAGE(1,1,1,B,n0,kt1+2);
    vm_wait4();
    barrier_pin(); mmq<3>(acc,af,bf); barrier_pin();
  }
  vm_wait0();

  if (MODE == 0) {
    u16* C = (u16*)Cout;
    #pragma unroll
    for (int mf = 0; mf < 8; ++mf)
      #pragma unroll
      for (int j = 0; j < 4; ++j) {
        int row = m0 + wr*128 + mf*16 + (lane>>4)*4 + j;
        size_t base = (size_t)row*ldc + n0 + wc*64 + (lane&15);
        #pragma unroll
        for (int nf = 0; nf < 4; ++nf)
          C[base + nf*16] = f2b(acc[mf][nf][j]);
      }
  } else {
    float* C = (float*)Cout;
    #pragma unroll
    for (int mf = 0; mf < 8; ++mf)
      #pragma unroll
      for (int j = 0; j < 4; ++j) {
        int row = m0 + wr*128 + mf*16 + (lane>>4)*4 + j;
        size_t base = (size_t)row*ldc + n0 + wc*64 + (lane&15);
        #pragma unroll
        for (int nf = 0; nf < 4; ++nf)
          atomicAdd(&C[base + nf*16], acc[mf][nf][j]);
      }
  }
}

// ---------- expert kernel (bf16 weights, direct global B-fragments) ----------
// grid (128 groups, NE, 4 f-blocks). Per block: 16 tokens x 2048 f-cols.
static constexpr int HA_LD = 40;
static constexpr int AW_LD = 72;
static constexpr int CT_LD = 72;

__global__ __launch_bounds__(256)
void expert_kernel(const u16* __restrict__ CGU,                                // [TT][NXE]
                   const float* __restrict__ hAx,                              // [TT][256] fp32
                   const u16* __restrict__ Bgb, const u16* __restrict__ Bub,   // [E][F][16] bf16
                   const u16* __restrict__ Adb,                                // [E][16][F] bf16
                   const int* __restrict__ count, const int* __restrict__ listTok,
                   const float* __restrict__ listW,
                   u16* __restrict__ actw0, u16* __restrict__ actw1,           // [TT+1][F]
                   float* __restrict__ cC) {                                   // [TT+1][2][16]
  const int e = blockIdx.y, g = blockIdx.x, fb = blockIdx.z;
  const int n = count[e];
  if (g*16 >= n) return;
  const int tid = threadIdx.x, lane = tid & 63, w = tid >> 6;
  __shared__ u16 hAg[16*HA_LD], hAu[16*HA_LD];
  __shared__ u16 AWs[4][16*AW_LD];
  __shared__ u16 cgT[4][16*CT_LD], cuT[4][16*CT_LD];
  __shared__ int sTok[16], sSlot[16];
  __shared__ float sW[16];
  __shared__ float dAred[4][256];

  if (tid < 16) {
    int idx = g*16 + tid;
    if (idx < n) {
      int ent = listTok[e*TT + idx];
      sTok[tid] = ent & 0xFFFF; sSlot[tid] = (ent >> 20) & 1; sW[tid] = listW[e*TT + idx];
    } else { sTok[tid] = TT; sSlot[tid] = 0; sW[tid] = 0.f; }
  }
  __syncthreads();
  if (tid < 128) {   // stage hA (both tensors) from hAx fp32, zero-pad K 16..31
    int tensor = tid >> 6;
    int sub = tid & 63;
    int row = sub >> 2, c8 = (sub & 3) * 8;
    int trd = min(sTok[row], TT - 1);
    u16 vals[8];
    if (c8 < 16) {
      const float* src = hAx + (size_t)trd*256 + tensor*128 + e*NR + c8;
      v4f a = *(const v4f*)src, b = *(const v4f*)(src + 4);
      v8s p = pack8(a, b);
      #pragma unroll
      for (int q = 0; q < 8; ++q) vals[q] = (u16)p[q];
    } else {
      #pragma unroll
      for (int q = 0; q < 8; ++q) vals[q] = 0;
    }
    u16* dst = (tensor ? hAu : hAg) + row*HA_LD + c8;
    #pragma unroll
    for (int q = 0; q < 8; ++q) dst[q] = vals[q];
  }
  __syncthreads();

  int tR[4], slR[4]; float wR[4];
  #pragma unroll
  for (int j = 0; j < 4; ++j) {
    int r = (lane>>4)*4 + j;
    tR[j] = sTok[r]; slR[j] = sSlot[r]; wR[j] = sW[r];
  }
  const int khalf = lane >> 4;
  v8s afg = *(const v8s*)(hAg + (lane&15)*HA_LD + khalf*8);
  v8s afu = *(const v8s*)(hAu + (lane&15)*HA_LD + khalf*8);
  v4f accDA = (v4f){0.f,0.f,0.f,0.f};
  u16* aww = AWs[w]; u16* cgw = cgT[w]; u16* cuw = cuT[w];
  const v8s zero8 = {0,0,0,0,0,0,0,0};
  const u16* BgE = Bgb + (size_t)e*FD*16;
  const u16* BuE = Bub + (size_t)e*FD*16;
  const u16* AdE = Adb + (size_t)e*16*FD;

  // per-lane coalesced-store coords (from aww)
  const int srj = lane >> 2, sc = (lane & 3) * 16;

  const int ch_end = fb*32 + 32;
  for (int ch = fb*32 + w; ch < ch_end; ch += 4) {   // 64-wide f-chunks, wave-private
    int f0 = ch * 64;
    { // stage common gate/up tile [16 tok][64 f] into LDS (v8s coalesced)
      int srow = lane >> 3, c8 = (lane & 7) * 8;
      #pragma unroll
      for (int rr = 0; rr < 2; ++rr) {
        int row = srow + rr*8;
        size_t trd = (size_t)min(sTok[row], TT - 1);
        *(v8s*)(cgw + row*CT_LD + c8) = *(const v8s*)(CGU + trd*NXE + f0 + c8);
        *(v8s*)(cuw + row*CT_LD + c8) = *(const v8s*)(CGU + trd*NXE + CU_OFF + f0 + c8);
      }
    }
    v4f dg[4], du[4];
    #pragma unroll
    for (int nf = 0; nf < 4; ++nf) {   // B-fragments direct from global bf16 (L2-hot)
      int f = f0 + nf*16 + (lane & 15);
      v8s bgf = (khalf < 2) ? *(const v8s*)(BgE + (size_t)f*16 + khalf*8) : zero8;
      dg[nf] = __builtin_amdgcn_mfma_f32_16x16x32_bf16(afg, bgf, (v4f){0.f,0.f,0.f,0.f}, 0, 0, 0);
      v8s buf = (khalf < 2) ? *(const v8s*)(BuE + (size_t)f*16 + khalf*8) : zero8;
      du[nf] = __builtin_amdgcn_mfma_f32_16x16x32_bf16(afu, buf, (v4f){0.f,0.f,0.f,0.f}, 0, 0, 0);
    }
    #pragma unroll
    for (int nf = 0; nf < 4; ++nf) {
      #pragma unroll
      for (int j = 0; j < 4; ++j) {
        int rj = (lane>>4)*4 + j;
        int fi = nf*16 + (lane&15);
        float cgv = b2f(cgw[rj*CT_LD + fi]);
        float cuv = b2f(cuw[rj*CT_LD + fi]);
        float gv = cgv + 2.f * dg[nf][j];
        float uv = cuv + 2.f * du[nf][j];
        float a  = gv / (1.f + __expf(-gv)) * uv;   // silu(g)*u
        aww[rj*AW_LD + fi] = f2b(wR[j] * a);        // LDS only; global store below
      }
    }
    { // coalesced global store of weighted act from aww (4 x v8s per lane)
      int st = sTok[srj], ss = sSlot[srj];
      u16* dst = (ss ? actw1 : actw0) + (size_t)st*FD + f0 + sc;
      *(v8s*)dst       = *(const v8s*)(aww + srj*AW_LD + sc);
      *(v8s*)(dst + 8) = *(const v8s*)(aww + srj*AW_LD + sc + 8);
    }
    #pragma unroll
    for (int ks = 0; ks < 2; ++ks) {   // dA accumulate: [16 tok] x [16 r] over K=64
      v8s aA = *(const v8s*)(aww + (lane&15)*AW_LD + ks*32 + khalf*8);
      v8s bA = *(const v8s*)(AdE + (size_t)(lane&15)*FD + f0 + ks*32 + khalf*8);
      accDA = __builtin_amdgcn_mfma_f32_16x16x32_bf16(aA, bA, accDA, 0, 0, 0);
    }
  }
  #pragma unroll
  for (int j = 0; j < 4; ++j)
    dAred[w][((lane>>4)*4 + j)*16 + (lane&15)] = accDA[j];
  __syncthreads();
  {
    int row = tid >> 4, col = tid & 15;
    float s2 = dAred[0][row*16+col] + dAred[1][row*16+col] + dAred[2][row*16+col] + dAred[3][row*16+col];
    atomicAdd(&cC[((size_t)sTok[row]*2 + sSlot[row])*16 + col], 2.f * s2);
  }
}

// ---------- combine: abx[t] = [actw0+actw1 (bf16), scattered c coefs, zeros] ----------
__global__ __launch_bounds__(256)
void combine2_kernel(const u16* __restrict__ a0, const u16* __restrict__ a1,
                     const float* __restrict__ cC, const int* __restrict__ sel,
                     u16* __restrict__ abx) {
  int t = blockIdx.x, tid = threadIdx.x;
  const u16* p0 = a0 + (size_t)t * FD;
  const u16* p1 = a1 + (size_t)t * FD;
  u16* po = abx + (size_t)t * KXD;
  for (int i = tid * 8; i < FD; i += 256 * 8) {
    v8s x = *(const v8s*)(p0 + i);
    v8s y = *(const v8s*)(p1 + i);
    v8s o;
    #pragma unroll
    for (int j = 0; j < 8; ++j) o[j] = (short)f2b(b2f((u16)x[j]) + b2f((u16)y[j]));
    *(v8s*)(po + i) = o;
  }
  for (int c = tid; c < 512; c += 256) {  // ext cols; c>=128 zeroed
    float v = 0.f;
    if (c < 128) {
      int e_i = c >> 4, r = c & 15;
      if (sel[2*t]     == e_i) v += cC[((size_t)t*2 + 0)*16 + r];
      if (sel[2*t + 1] == e_i) v += cC[((size_t)t*2 + 1)*16 + r];
    }
    po[FD + c] = f2b(v);
  }
}

// ---------- launch ----------
extern "C" void kernel_launch(void* const* d_in, const int* in_sizes, int n_in,
                              void* d_out, int out_size, void* d_ws, size_t ws_size,
                              hipStream_t stream) {
  (void)in_sizes; (void)n_in; (void)out_size; (void)ws_size;
  const float* h  = (const float*)d_in[0];
  const float* gw = (const float*)d_in[1];
  const float* Wg = (const float*)d_in[2];
  const float* Wu = (const float*)d_in[3];
  const float* Wd = (const float*)d_in[4];
  const float* Ag = (const float*)d_in[5];
  const float* Bg = (const float*)d_in[6];
  const float* Au = (const float*)d_in[7];
  const float* Bu = (const float*)d_in[8];
  const float* Ad = (const float*)d_in[9];
  const float* Bd = (const float*)d_in[10];

  char* ws = (char*)d_ws;
  size_t off = 0;
  auto alloc = [&](size_t bytes) { size_t c = off; off += (bytes + 255) & ~(size_t)255; return c; };
  u16*  hb     = (u16*)(ws + alloc((size_t)TT*HD*2));             // 8 MB
  u16*  Bgux   = (u16*)(ws + alloc((size_t)(TT+1)*FD*2*2));       // 67.2 MB [Wg|Wu]; later actw0/actw1
  u16*  Agu    = (u16*)(ws + alloc((size_t)256*HD*2));            // 1 MB [Ag all|Au all]
  u16*  Wdx    = (u16*)(ws + alloc((size_t)HD*KXD*2));            // 35.7 MB [HD][KXD]
  u16*  CGU    = (u16*)(ws + alloc((size_t)TT*NXE*2));            // 64 MB [TT][NXE]; later abx [TT][KXD]
  u16*  Bgb    = (u16*)(ws + alloc((size_t)NE*FD*16*2));          // 2 MB bf16
  u16*  Bub    = (u16*)(ws + alloc((size_t)NE*FD*16*2));          // 2 MB
  u16*  Adb    = (u16*)(ws + alloc((size_t)NE*16*FD*2));          // 2 MB
  float* hAx   = (float*)(ws + alloc((size_t)TT*256*4));          // 2 MB
  float* cC    = (float*)(ws + alloc((size_t)(TT+1)*2*16*4));
  int*  sel    = (int*)(ws + alloc((size_t)TT*2*4));
  int*  count  = (int*)(ws + alloc(256));
  int*  listTok= (int*)(ws + alloc((size_t)NE*TT*4));
  float* listW = (float*)(ws + alloc((size_t)NE*TT*4));
  u16*  actw0  = Bgux;                                  // alias: Bgux dead after gate/up GEMMs
  u16*  actw1  = Bgux + (size_t)(TT+1)*FD;
  u16*  abx    = CGU;                                   // alias: CGU dead after expert_kernel

  hipMemsetAsync(count, 0, NE*sizeof(int), stream);
  hipMemsetAsync(cC, 0, (size_t)(TT+1)*2*16*4, stream);

  // one mega-prep: all casts + Bd-ext + d_out/hAx zero
  prep_kernel<<<PREP_BLOCKS, 256, 0, stream>>>(h, Wg, Wu, Wd, Ag, Au, Bg, Bu, Ad, Bd,
                                               hb, Bgux, Agu, Wdx, Bgb, Bub, Adb,
                                               (float*)d_out, hAx);

  router_kernel<<<TT, 64, 0, stream>>>(h, gw, sel, count, listTok, listW);

  // hAx = h @ [Ag;Au]^T  (M=2048, N=256, K=2048, split-K=8 -> 256 blocks)
  gemm128a<<<dim3(16, 2, 8), 256, 0, stream>>>(hb, Agu, hAx, HD, 256);

  // gate: CG = h @ Wg^T   (M=2048, N=8192, K=2048) -> 256 blocks = 1 exact round
  gemm256<0><<<dim3(8, 32, 1), 512, 0, stream>>>(hb, Bgux, CGU, HD, HD, NXE);
  // up:   CU = h @ Wu^T   -> 256 blocks = 1 exact round (writes CGU cols FD..)
  gemm256<0><<<dim3(8, 32, 1), 512, 0, stream>>>(hb, Bgux + (size_t)FD*HD, CGU + CU_OFF, HD, HD, NXE);

  // per-expert: deltas, act, weighted act into slot buffers (aliasing Bgux), c coefs
  expert_kernel<<<dim3(128, NE, 4), 256, 0, stream>>>(CGU, hAx, Bgb, Bub, Adb, count, listTok, listW,
                                                      actw0, actw1, cC);

  // abx = [actw0+actw1, c-scatter, zeros]  (writes into the dead CGU region)
  combine2_kernel<<<TT, 256, 0, stream>>>(actw0, actw1, cC, sel, abx);

  // out = abx @ Wdx^T  (M=2048, N=2048, K=8704, split-K=4 -> 256 blocks = 1 round)
  gemm256<2><<<dim3(8, 8, 4), 512, 0, stream>>>(abx, Wdx, d_out, KXD, KXD/4, HD);
}

// Round 8
// 450.714 us; speedup vs baseline: 1.5935x; 1.0900x over previous
//
#include <hip/hip_runtime.h>
#include <hip/hip_bf16.h>

typedef __attribute__((ext_vector_type(8))) short v8s;   // 8 x bf16 (as i16)
typedef __attribute__((ext_vector_type(4))) float v4f;
typedef unsigned short u16;

static constexpr int TT = 2048;        // tokens
static constexpr int HD = 2048;        // hidden
static constexpr int FD = 8192;        // ffn dim
static constexpr int NE = 8;           // experts
static constexpr int NR = 16;          // lora rank
static constexpr int NXE = 2*FD;       // 16384: merged [Wg | Wu] cols
static constexpr int CU_OFF = FD;      // up offset inside CGU row
static constexpr int KXD = FD + 512;   // 8704 = 136*64 ext K for down GEMM (34*64*4)

// ---------- helpers ----------
__device__ __forceinline__ u16 f2b(float f) {            // fp32 -> bf16 RNE
  union { float f; unsigned u; } v; v.f = f;
  unsigned r = v.u + 0x7FFFu + ((v.u >> 16) & 1u);
  return (u16)(r >> 16);
}
__device__ __forceinline__ float b2f(u16 h) {
  union { unsigned u; float f; } v; v.u = ((unsigned)h) << 16;
  return v.f;
}
__device__ __forceinline__ v8s pack8(v4f a, v4f b) {
  v8s r;
  r[0]=(short)f2b(a.x); r[1]=(short)f2b(a.y); r[2]=(short)f2b(a.z); r[3]=(short)f2b(a.w);
  r[4]=(short)f2b(b.x); r[5]=(short)f2b(b.y); r[6]=(short)f2b(b.z); r[7]=(short)f2b(b.w);
  return r;
}
__device__ __forceinline__ void gload_lds16(const void* g, void* l) {
  __builtin_amdgcn_global_load_lds(
      (const __attribute__((address_space(1))) unsigned int*)g,
      (__attribute__((address_space(3))) unsigned int*)l, 16, 0, 0);
}
__device__ __forceinline__ void barrier_pin() {
  __builtin_amdgcn_s_barrier();
  __builtin_amdgcn_sched_barrier(0);
}
__device__ __forceinline__ void vm_wait4() { asm volatile("s_waitcnt vmcnt(4)" ::: "memory"); }
__device__ __forceinline__ void vm_wait0() { asm volatile("s_waitcnt vmcnt(0)" ::: "memory"); }

template<int Q>
__device__ __forceinline__ void mmq(v4f (&acc)[8][4], const v8s (&af)[2][2], const v8s (&bf)[4][2]) {
  __builtin_amdgcn_s_setprio(1);
  #pragma unroll
  for (int m2 = 0; m2 < 2; ++m2)
    #pragma unroll
    for (int nf = 0; nf < 4; ++nf) {
      acc[Q*2+m2][nf] = __builtin_amdgcn_mfma_f32_16x16x32_bf16(af[m2][0], bf[nf][0], acc[Q*2+m2][nf], 0, 0, 0);
      acc[Q*2+m2][nf] = __builtin_amdgcn_mfma_f32_16x16x32_bf16(af[m2][1], bf[nf][1], acc[Q*2+m2][nf], 0, 0, 0);
    }
  __builtin_amdgcn_s_setprio(0);
}

// ---------- mega prep: all casts + Bd-ext + hAx zeroing, one launch ----------
// segment block ranges (256 thr, 8 elems/thr):
//   [0,2048) h->hb  [2048,10240) Wg  [10240,18432) Wu  [18432,26624) Wd->Wdx
//   [26624,26752) Ag  [26752,26880) Au  [26880,27392) Bg  [27392,27904) Bu
//   [27904,28416) Ad  [28416,28928) Bd->Wdx ext  [28928,29184) zero hAx
static constexpr int PREP_BLOCKS = 29184;
__global__ __launch_bounds__(256)
void prep_kernel(const float* __restrict__ h, const float* __restrict__ Wg,
                 const float* __restrict__ Wu, const float* __restrict__ Wd,
                 const float* __restrict__ Ag, const float* __restrict__ Au,
                 const float* __restrict__ Bg, const float* __restrict__ Bu,
                 const float* __restrict__ Ad, const float* __restrict__ Bd,
                 u16* __restrict__ hb, u16* __restrict__ Bgux, u16* __restrict__ Agu,
                 u16* __restrict__ Wdx, u16* __restrict__ Bgb, u16* __restrict__ Bub,
                 u16* __restrict__ Adb, float* __restrict__ hAx) {
  const int b = blockIdx.x, tid = threadIdx.x;
  if (b < 2048) {
    long i = ((long)b*256 + tid)*8;
    *(v8s*)(hb+i) = pack8(*(const v4f*)(h+i), *(const v4f*)(h+i+4));
  } else if (b < 10240) {
    long i = ((long)(b-2048)*256 + tid)*8;
    *(v8s*)(Bgux+i) = pack8(*(const v4f*)(Wg+i), *(const v4f*)(Wg+i+4));
  } else if (b < 18432) {
    long i = ((long)(b-10240)*256 + tid)*8;
    *(v8s*)(Bgux+(size_t)FD*HD+i) = pack8(*(const v4f*)(Wu+i), *(const v4f*)(Wu+i+4));
  } else if (b < 26624) {
    long idx = (long)(b-18432)*256 + tid;     // v8 index over [HD][FD]
    long r = idx >> 10;                        // FD/8 = 1024
    int c8 = (int)(idx & 1023) * 8;
    const float* s = Wd + r*FD + c8;
    *(v8s*)(Wdx + r*KXD + c8) = pack8(*(const v4f*)s, *(const v4f*)(s+4));
  } else if (b < 26752) {
    long i = ((long)(b-26624)*256 + tid)*8;
    *(v8s*)(Agu+i) = pack8(*(const v4f*)(Ag+i), *(const v4f*)(Ag+i+4));
  } else if (b < 26880) {
    long i = ((long)(b-26752)*256 + tid)*8;
    *(v8s*)(Agu+(size_t)128*HD+i) = pack8(*(const v4f*)(Au+i), *(const v4f*)(Au+i+4));
  } else if (b < 27392) {
    long i = ((long)(b-26880)*256 + tid)*8;
    *(v8s*)(Bgb+i) = pack8(*(const v4f*)(Bg+i), *(const v4f*)(Bg+i+4));
  } else if (b < 27904) {
    long i = ((long)(b-27392)*256 + tid)*8;
    *(v8s*)(Bub+i) = pack8(*(const v4f*)(Bu+i), *(const v4f*)(Bu+i+4));
  } else if (b < 28416) {
    long i = ((long)(b-27904)*256 + tid)*8;
    *(v8s*)(Adb+i) = pack8(*(const v4f*)(Ad+i), *(const v4f*)(Ad+i+4));
  } else if (b < 28928) {
    long idx = (long)(b-28416)*256 + tid;     // 8 ext cols per thread
    int hrow = (int)(idx >> 6);
    int c8 = (int)(idx & 63) * 8;
    v8s o;
    if (c8 < 128) {
      int e = c8 >> 4, r0 = c8 & 15;
      const float* s = Bd + ((size_t)e*HD + hrow)*16 + r0;
      o = pack8(*(const v4f*)s, *(const v4f*)(s+4));
    } else {
      #pragma unroll
      for (int q = 0; q < 8; ++q) o[q] = 0;
    }
    *(v8s*)(Wdx + (size_t)hrow*KXD + FD + c8) = o;
  } else {
    long i = ((long)(b-28928)*256 + tid)*8;
    v4f z = {0.f,0.f,0.f,0.f};
    *(v4f*)(hAx+i) = z; *(v4f*)(hAx+i+4) = z;
  }
}

// ---------- router + gather ----------
__global__ __launch_bounds__(64)
void router_kernel(const float* __restrict__ h, const float* __restrict__ gw,
                   int* __restrict__ sel, int* __restrict__ count,
                   int* __restrict__ listTok, float* __restrict__ listW) {
  int t = blockIdx.x, lane = threadIdx.x;
  const float* hp = h + (size_t)t * HD;
  float acc[8] = {0,0,0,0,0,0,0,0};
  for (int i = lane; i < HD; i += 64) {
    float hv = hp[i];
    #pragma unroll
    for (int e = 0; e < 8; ++e) acc[e] += hv * gw[e*HD + i];
  }
  #pragma unroll
  for (int off = 32; off > 0; off >>= 1) {
    #pragma unroll
    for (int e = 0; e < 8; ++e) acc[e] += __shfl_xor(acc[e], off, 64);
  }
  if (lane == 0) {
    int e0 = -1, e1 = -1; float b0 = -1e30f, b1 = -1e30f;
    #pragma unroll
    for (int e = 0; e < 8; ++e) {
      float v = acc[e];
      if (v > b0) { b1 = b0; e1 = e0; b0 = v; e0 = e; }
      else if (v > b1) { b1 = v; e1 = e; }
    }
    float p1 = __expf(b1 - b0);            // p0 = 1
    float w0 = 1.f / (1.f + p1);
    float w1 = p1 * w0;
    sel[2*t] = e0; sel[2*t+1] = e1;
    int pos0 = atomicAdd(&count[e0], 1);
    listTok[e0*TT + pos0] = t;           listW[e0*TT + pos0] = w0;
    int pos1 = atomicAdd(&count[e1], 1);
    listTok[e1*TT + pos1] = t | (1<<20); listW[e1*TT + pos1] = w1;
  }
}

// ---------- 128x128x64 bf16 GEMM (m97 structure), C = A @ B^T, split-K atomic ----------
__global__ __launch_bounds__(256)
void gemm128a(const u16* __restrict__ A, const u16* __restrict__ B, float* __restrict__ Cout,
              int K, int ldc) {
  __shared__ u16 As[128*64];
  __shared__ u16 Bs[128*64];
  const int tid  = threadIdx.x;
  const int lane = tid & 63, wid = tid >> 6;
  const int gx = gridDim.x;
  const int lin = blockIdx.y * gx + blockIdx.x;
  const int chunk = (gx * gridDim.y) >> 3;
  const int wg = (lin & 7) * chunk + (lin >> 3);
  const int m0 = (wg % gx) * 128, n0 = (wg / gx) * 128;
  const int kc = K / gridDim.z;
  const int kbeg = blockIdx.z * kc;
  const int wr = wid >> 1, wc = wid & 1;
  const int lrow = lane >> 3, lcol = (lane & 7) * 8;
  v4f acc[4][4];
  #pragma unroll
  for (int mi = 0; mi < 4; ++mi)
    #pragma unroll
    for (int ni = 0; ni < 4; ++ni) acc[mi][ni] = (v4f){0.f,0.f,0.f,0.f};

  for (int k0 = kbeg; k0 < kbeg + kc; k0 += 64) {
    #pragma unroll
    for (int it = 0; it < 4; ++it) {
      int seg = wid*4 + it;
      int row = seg*8 + lrow;
      gload_lds16(A + (size_t)(m0+row)*K + k0 + lcol, As + seg*512);
      gload_lds16(B + (size_t)(n0+row)*K + k0 + lcol, Bs + seg*512);
    }
    __syncthreads();
    #pragma unroll
    for (int kk = 0; kk < 64; kk += 32) {
      v8s af[4], bfr[4];
      #pragma unroll
      for (int mi = 0; mi < 4; ++mi)
        af[mi] = *(const v8s*)(As + (wr*64 + mi*16 + (lane&15))*64 + kk + (lane>>4)*8);
      #pragma unroll
      for (int ni = 0; ni < 4; ++ni)
        bfr[ni] = *(const v8s*)(Bs + (wc*64 + ni*16 + (lane&15))*64 + kk + (lane>>4)*8);
      #pragma unroll
      for (int mi = 0; mi < 4; ++mi)
        #pragma unroll
        for (int ni = 0; ni < 4; ++ni)
          acc[mi][ni] = __builtin_amdgcn_mfma_f32_16x16x32_bf16(af[mi], bfr[ni], acc[mi][ni], 0, 0, 0);
    }
    __syncthreads();
  }

  #pragma unroll
  for (int mi = 0; mi < 4; ++mi)
    #pragma unroll
    for (int j = 0; j < 4; ++j) {
      int row = m0 + wr*64 + mi*16 + (lane>>4)*4 + j;
      size_t base = (size_t)row*ldc + n0 + wc*64 + (lane&15);
      #pragma unroll
      for (int ni = 0; ni < 4; ++ni)
        atomicAdd(&Cout[base + ni*16], acc[mi][ni][j]);
    }
}

// ---------- 256x256 8-phase bf16 GEMM, C = A @ B^T  (T1+T2+T3+T4+T5) ----------
// MODE 0: bf16 store. MODE 3: fp32 per-z-slice partial store (no atomics).
template<int MODE>
__global__ __launch_bounds__(512, 2)
void gemm256(const u16* __restrict__ A, const u16* __restrict__ B, void* __restrict__ Cout,
             int ldk, int kchunk, int ldc) {
  __shared__ u16 lds[2][2][2][8192];
  const int tid = threadIdx.x, lane = tid & 63, wid = tid >> 6;
  const int gx = gridDim.x;
  const int nwg = gx * gridDim.y;
  const int lin = blockIdx.y * gx + blockIdx.x;
  const int chunk = nwg >> 3;                       // nwg % 8 == 0 by construction
  const int wg = (lin & 7) * chunk + (lin >> 3);    // bijective XCD swizzle
  const int m0 = (wg % gx) * 256, n0 = (wg / gx) * 256;
  const long kbeg = (long)blockIdx.z * kchunk;
  const int NK = kchunk >> 6, NI = NK >> 1;         // NK even
  const int wr = wid >> 2, wc = wid & 3;

  const int s_r = (wid << 4) + (lane >> 3);
  const int s_c = lane & 7;

  auto STAGE = [&](int slot, int ab, int half, const u16* M, int rc0, int kt) {
    const u16* g0 = M + (size_t)(rc0 + half*128 + s_r) * ldk + kbeg + kt*64 + ((s_c ^ (s_r & 7)) << 3);
    gload_lds16(g0, &lds[slot][ab][half][wid << 10]);
    const int r1 = s_r + 8;
    const u16* g1 = M + (size_t)(rc0 + half*128 + r1) * ldk + kbeg + kt*64 + ((s_c ^ (r1 & 7)) << 3);
    gload_lds16(g1, &lds[slot][ab][half][(wid << 10) + 512]);
  };
  auto LDA = [&](int slot, int mf, int c16b) -> v8s {
    int rr = (mf << 4) + (lane & 15);
    return *(const v8s*)&lds[slot][0][wr][rr*64 + (((c16b + (lane >> 4)) ^ (rr & 7)) << 3)];
  };
  auto LDB = [&](int slot, int nf, int c16b) -> v8s {
    int row = (wc << 6) + (nf << 4) + (lane & 15);
    int rr = row & 127;
    return *(const v8s*)&lds[slot][1][row >> 7][rr*64 + (((c16b + (lane >> 4)) ^ (rr & 7)) << 3)];
  };

  v4f acc[8][4];
  #pragma unroll
  for (int mf = 0; mf < 8; ++mf)
    #pragma unroll
    for (int nf = 0; nf < 4; ++nf) acc[mf][nf] = (v4f){0.f,0.f,0.f,0.f};

  STAGE(0,1,0,B,n0,0); STAGE(0,1,1,B,n0,0);
  STAGE(0,0,0,A,m0,0); STAGE(0,0,1,A,m0,0);
  STAGE(1,1,0,B,n0,1); STAGE(1,1,1,B,n0,1);
  vm_wait4();
  barrier_pin();

  for (int i = 0; i < NI; ++i) {
    const int kt0 = 2*i, kt1 = kt0 + 1;
    const int kt2c = (kt0 + 2 < NK) ? kt0 + 2 : kt0;
    const bool s45 = (kt0 + 2 < NK), s67 = (kt1 + 2 < NK);
    v8s bf[4][2], af[2][2];
    // ---- phase 0 (slot0, q0)
    #pragma unroll
    for (int nf = 0; nf < 4; ++nf) { bf[nf][0] = LDB(0,nf,0); bf[nf][1] = LDB(0,nf,4); }
    af[0][0]=LDA(0,0,0); af[0][1]=LDA(0,0,4); af[1][0]=LDA(0,1,0); af[1][1]=LDA(0,1,4);
    STAGE(1,0,0,A,m0,kt1);
    barrier_pin(); mmq<0>(acc,af,bf); barrier_pin();
    // ---- phase 1 (slot0, q1)
    af[0][0]=LDA(0,2,0); af[0][1]=LDA(0,2,4); af[1][0]=LDA(0,3,0); af[1][1]=LDA(0,3,4);
    STAGE(1,0,1,A,m0,kt1);
    barrier_pin(); mmq<1>(acc,af,bf); barrier_pin();
    // ---- phase 2 (slot0, q2)
    af[0][0]=LDA(0,4,0); af[0][1]=LDA(0,4,4); af[1][0]=LDA(0,5,0); af[1][1]=LDA(0,5,4);
    STAGE(0,1,0,B,n0,kt2c);
    barrier_pin(); mmq<2>(acc,af,bf); barrier_pin();
    // ---- phase 3 (slot0, q3)
    af[0][0]=LDA(0,6,0); af[0][1]=LDA(0,6,4); af[1][0]=LDA(0,7,0); af[1][1]=LDA(0,7,4);
    STAGE(0,1,1,B,n0,kt2c);
    vm_wait4();
    barrier_pin(); mmq<3>(acc,af,bf); barrier_pin();
    // ---- phase 4 (slot1, q0)
    #pragma unroll
    for (int nf = 0; nf < 4; ++nf) { bf[nf][0] = LDB(1,nf,0); bf[nf][1] = LDB(1,nf,4); }
    af[0][0]=LDA(1,0,0); af[0][1]=LDA(1,0,4); af[1][0]=LDA(1,1,0); af[1][1]=LDA(1,1,4);
    if (s45) STAGE(0,0,0,A,m0,kt0+2);
    barrier_pin(); mmq<0>(acc,af,bf); barrier_pin();
    // ---- phase 5 (slot1, q1)
    af[0][0]=LDA(1,2,0); af[0][1]=LDA(1,2,4); af[1][0]=LDA(1,3,0); af[1][1]=LDA(1,3,4);
    if (s45) STAGE(0,0,1,A,m0,kt0+2);
    barrier_pin(); mmq<1>(acc,af,bf); barrier_pin();
    // ---- phase 6 (slot1, q2)
    af[0][0]=LDA(1,4,0); af[0][1]=LDA(1,4,4); af[1][0]=LDA(1,5,0); af[1][1]=LDA(1,5,4);
    if (s67) STAGE(1,1,0,B,n0,kt1+2);
    barrier_pin(); mmq<2>(acc,af,bf); barrier_pin();
    // ---- phase 7 (slot1, q3)
    af[0][0]=LDA(1,6,0); af[0][1]=LDA(1,6,4); af[1][0]=LDA(1,7,0); af[1][1]=LDA(1,7,4);
    if (s67) STAGE(1,1,1,B,n0,kt1+2);
    vm_wait4();
    barrier_pin(); mmq<3>(acc,af,bf); barrier_pin();
  }
  vm_wait0();

  if (MODE == 0) {
    u16* C = (u16*)Cout;
    #pragma unroll
    for (int mf = 0; mf < 8; ++mf)
      #pragma unroll
      for (int j = 0; j < 4; ++j) {
        int row = m0 + wr*128 + mf*16 + (lane>>4)*4 + j;
        size_t base = (size_t)row*ldc + n0 + wc*64 + (lane&15);
        #pragma unroll
        for (int nf = 0; nf < 4; ++nf)
          C[base + nf*16] = f2b(acc[mf][nf][j]);
      }
  } else {
    float* C = (float*)Cout + (size_t)blockIdx.z * TT * HD;   // per-slice partial
    #pragma unroll
    for (int mf = 0; mf < 8; ++mf)
      #pragma unroll
      for (int j = 0; j < 4; ++j) {
        int row = m0 + wr*128 + mf*16 + (lane>>4)*4 + j;
        size_t base = (size_t)row*ldc + n0 + wc*64 + (lane&15);
        #pragma unroll
        for (int nf = 0; nf < 4; ++nf)
          C[base + nf*16] = acc[mf][nf][j];
      }
  }
}

// ---------- reduce: out = sum of 4 fp32 partials ----------
__global__ __launch_bounds__(256)
void reduce4_kernel(const float* __restrict__ P, float* __restrict__ out) {
  long i = ((long)blockIdx.x * 256 + threadIdx.x) * 4;
  const size_t S = (size_t)TT * HD;
  v4f s = *(const v4f*)(P + i);
  s = s + *(const v4f*)(P + S + i);
  s = s + *(const v4f*)(P + 2*S + i);
  s = s + *(const v4f*)(P + 3*S + i);
  *(v4f*)(out + i) = s;
}

// ---------- expert kernel (bf16 weights, direct global B-fragments) ----------
static constexpr int HA_LD = 40;
static constexpr int AW_LD = 72;
static constexpr int CT_LD = 72;

__global__ __launch_bounds__(256)
void expert_kernel(const u16* __restrict__ CGU,                                // [TT][NXE]
                   const float* __restrict__ hAx,                              // [TT][256] fp32
                   const u16* __restrict__ Bgb, const u16* __restrict__ Bub,   // [E][F][16] bf16
                   const u16* __restrict__ Adb,                                // [E][16][F] bf16
                   const int* __restrict__ count, const int* __restrict__ listTok,
                   const float* __restrict__ listW,
                   u16* __restrict__ actw0, u16* __restrict__ actw1,           // [TT+1][F]
                   float* __restrict__ cC) {                                   // [TT+1][2][16]
  const int e = blockIdx.y, g = blockIdx.x, fb = blockIdx.z;
  const int n = count[e];
  if (g*16 >= n) return;
  const int tid = threadIdx.x, lane = tid & 63, w = tid >> 6;
  __shared__ u16 hAg[16*HA_LD], hAu[16*HA_LD];
  __shared__ u16 AWs[4][16*AW_LD];
  __shared__ u16 cgT[4][16*CT_LD], cuT[4][16*CT_LD];
  __shared__ int sTok[16], sSlot[16];
  __shared__ float sW[16];
  __shared__ float dAred[4][256];

  if (tid < 16) {
    int idx = g*16 + tid;
    if (idx < n) {
      int ent = listTok[e*TT + idx];
      sTok[tid] = ent & 0xFFFF; sSlot[tid] = (ent >> 20) & 1; sW[tid] = listW[e*TT + idx];
    } else { sTok[tid] = TT; sSlot[tid] = 0; sW[tid] = 0.f; }
  }
  __syncthreads();
  if (tid < 128) {   // stage hA (both tensors) from hAx fp32, zero-pad K 16..31
    int tensor = tid >> 6;
    int sub = tid & 63;
    int row = sub >> 2, c8 = (sub & 3) * 8;
    int trd = min(sTok[row], TT - 1);
    u16 vals[8];
    if (c8 < 16) {
      const float* src = hAx + (size_t)trd*256 + tensor*128 + e*NR + c8;
      v4f a = *(const v4f*)src, b = *(const v4f*)(src + 4);
      v8s p = pack8(a, b);
      #pragma unroll
      for (int q = 0; q < 8; ++q) vals[q] = (u16)p[q];
    } else {
      #pragma unroll
      for (int q = 0; q < 8; ++q) vals[q] = 0;
    }
    u16* dst = (tensor ? hAu : hAg) + row*HA_LD + c8;
    #pragma unroll
    for (int q = 0; q < 8; ++q) dst[q] = vals[q];
  }
  __syncthreads();

  int tR[4], slR[4]; float wR[4];
  #pragma unroll
  for (int j = 0; j < 4; ++j) {
    int r = (lane>>4)*4 + j;
    tR[j] = sTok[r]; slR[j] = sSlot[r]; wR[j] = sW[r];
  }
  const int khalf = lane >> 4;
  v8s afg = *(const v8s*)(hAg + (lane&15)*HA_LD + khalf*8);
  v8s afu = *(const v8s*)(hAu + (lane&15)*HA_LD + khalf*8);
  v4f accDA = (v4f){0.f,0.f,0.f,0.f};
  u16* aww = AWs[w]; u16* cgw = cgT[w]; u16* cuw = cuT[w];
  const v8s zero8 = {0,0,0,0,0,0,0,0};
  const u16* BgE = Bgb + (size_t)e*FD*16;
  const u16* BuE = Bub + (size_t)e*FD*16;
  const u16* AdE = Adb + (size_t)e*16*FD;

  // per-lane coalesced-store coords (from aww)
  const int srj = lane >> 2, sc = (lane & 3) * 16;

  const int ch_end = fb*32 + 32;
  for (int ch = fb*32 + w; ch < ch_end; ch += 4) {   // 64-wide f-chunks, wave-private
    int f0 = ch * 64;
    { // stage common gate/up tile [16 tok][64 f] into LDS (v8s coalesced)
      int srow = lane >> 3, c8 = (lane & 7) * 8;
      #pragma unroll
      for (int rr = 0; rr < 2; ++rr) {
        int row = srow + rr*8;
        size_t trd = (size_t)min(sTok[row], TT - 1);
        *(v8s*)(cgw + row*CT_LD + c8) = *(const v8s*)(CGU + trd*NXE + f0 + c8);
        *(v8s*)(cuw + row*CT_LD + c8) = *(const v8s*)(CGU + trd*NXE + CU_OFF + f0 + c8);
      }
    }
    v4f dg[4], du[4];
    #pragma unroll
    for (int nf = 0; nf < 4; ++nf) {   // B-fragments direct from global bf16 (L2-hot)
      int f = f0 + nf*16 + (lane & 15);
      v8s bgf = (khalf < 2) ? *(const v8s*)(BgE + (size_t)f*16 + khalf*8) : zero8;
      dg[nf] = __builtin_amdgcn_mfma_f32_16x16x32_bf16(afg, bgf, (v4f){0.f,0.f,0.f,0.f}, 0, 0, 0);
      v8s buf = (khalf < 2) ? *(const v8s*)(BuE + (size_t)f*16 + khalf*8) : zero8;
      du[nf] = __builtin_amdgcn_mfma_f32_16x16x32_bf16(afu, buf, (v4f){0.f,0.f,0.f,0.f}, 0, 0, 0);
    }
    #pragma unroll
    for (int nf = 0; nf < 4; ++nf) {
      #pragma unroll
      for (int j = 0; j < 4; ++j) {
        int rj = (lane>>4)*4 + j;
        int fi = nf*16 + (lane&15);
        float cgv = b2f(cgw[rj*CT_LD + fi]);
        float cuv = b2f(cuw[rj*CT_LD + fi]);
        float gv = cgv + 2.f * dg[nf][j];
        float uv = cuv + 2.f * du[nf][j];
        float a  = gv / (1.f + __expf(-gv)) * uv;   // silu(g)*u
        aww[rj*AW_LD + fi] = f2b(wR[j] * a);        // LDS only; global store below
      }
    }
    { // coalesced global store of weighted act from aww (4 x v8s per lane)
      int st = sTok[srj], ss = sSlot[srj];
      u16* dst = (ss ? actw1 : actw0) + (size_t)st*FD + f0 + sc;
      *(v8s*)dst       = *(const v8s*)(aww + srj*AW_LD + sc);
      *(v8s*)(dst + 8) = *(const v8s*)(aww + srj*AW_LD + sc + 8);
    }
    #pragma unroll
    for (int ks = 0; ks < 2; ++ks) {   // dA accumulate: [16 tok] x [16 r] over K=64
      v8s aA = *(const v8s*)(aww + (lane&15)*AW_LD + ks*32 + khalf*8);
      v8s bA = *(const v8s*)(AdE + (size_t)(lane&15)*FD + f0 + ks*32 + khalf*8);
      accDA = __builtin_amdgcn_mfma_f32_16x16x32_bf16(aA, bA, accDA, 0, 0, 0);
    }
  }
  #pragma unroll
  for (int j = 0; j < 4; ++j)
    dAred[w][((lane>>4)*4 + j)*16 + (lane&15)] = accDA[j];
  __syncthreads();
  {
    int row = tid >> 4, col = tid & 15;
    float s2 = dAred[0][row*16+col] + dAred[1][row*16+col] + dAred[2][row*16+col] + dAred[3][row*16+col];
    atomicAdd(&cC[((size_t)sTok[row]*2 + sSlot[row])*16 + col], 2.f * s2);
  }
}

// ---------- combine: abx[t] = [actw0+actw1 (bf16), scattered c coefs, zeros] ----------
__global__ __launch_bounds__(256)
void combine2_kernel(const u16* __restrict__ a0, const u16* __restrict__ a1,
                     const float* __restrict__ cC, const int* __restrict__ sel,
                     u16* __restrict__ abx) {
  int t = blockIdx.x, tid = threadIdx.x;
  const u16* p0 = a0 + (size_t)t * FD;
  const u16* p1 = a1 + (size_t)t * FD;
  u16* po = abx + (size_t)t * KXD;
  for (int i = tid * 8; i < FD; i += 256 * 8) {
    v8s x = *(const v8s*)(p0 + i);
    v8s y = *(const v8s*)(p1 + i);
    v8s o;
    #pragma unroll
    for (int j = 0; j < 8; ++j) o[j] = (short)f2b(b2f((u16)x[j]) + b2f((u16)y[j]));
    *(v8s*)(po + i) = o;
  }
  for (int c = tid; c < 512; c += 256) {  // ext cols; c>=128 zeroed
    float v = 0.f;
    if (c < 128) {
      int e_i = c >> 4, r = c & 15;
      if (sel[2*t]     == e_i) v += cC[((size_t)t*2 + 0)*16 + r];
      if (sel[2*t + 1] == e_i) v += cC[((size_t)t*2 + 1)*16 + r];
    }
    po[FD + c] = f2b(v);
  }
}

// ---------- launch ----------
extern "C" void kernel_launch(void* const* d_in, const int* in_sizes, int n_in,
                              void* d_out, int out_size, void* d_ws, size_t ws_size,
                              hipStream_t stream) {
  (void)in_sizes; (void)n_in; (void)out_size; (void)ws_size;
  const float* h  = (const float*)d_in[0];
  const float* gw = (const float*)d_in[1];
  const float* Wg = (const float*)d_in[2];
  const float* Wu = (const float*)d_in[3];
  const float* Wd = (const float*)d_in[4];
  const float* Ag = (const float*)d_in[5];
  const float* Bg = (const float*)d_in[6];
  const float* Au = (const float*)d_in[7];
  const float* Bu = (const float*)d_in[8];
  const float* Ad = (const float*)d_in[9];
  const float* Bd = (const float*)d_in[10];

  char* ws = (char*)d_ws;
  size_t off = 0;
  auto alloc = [&](size_t bytes) { size_t c = off; off += (bytes + 255) & ~(size_t)255; return c; };
  u16*  hb     = (u16*)(ws + alloc((size_t)TT*HD*2));             // 8 MB
  u16*  Bgux   = (u16*)(ws + alloc((size_t)(TT+1)*FD*2*2));       // 67.2 MB [Wg|Wu]; actw0/1; down partials
  u16*  Agu    = (u16*)(ws + alloc((size_t)256*HD*2));            // 1 MB [Ag all|Au all]
  u16*  Wdx    = (u16*)(ws + alloc((size_t)HD*KXD*2));            // 35.7 MB [HD][KXD]
  u16*  CGU    = (u16*)(ws + alloc((size_t)TT*NXE*2));            // 64 MB [TT][NXE]; later abx [TT][KXD]
  u16*  Bgb    = (u16*)(ws + alloc((size_t)NE*FD*16*2));          // 2 MB bf16
  u16*  Bub    = (u16*)(ws + alloc((size_t)NE*FD*16*2));          // 2 MB
  u16*  Adb    = (u16*)(ws + alloc((size_t)NE*16*FD*2));          // 2 MB
  float* hAx   = (float*)(ws + alloc((size_t)TT*256*4));          // 2 MB
  float* cC    = (float*)(ws + alloc((size_t)(TT+1)*2*16*4));
  int*  sel    = (int*)(ws + alloc((size_t)TT*2*4));
  int*  count  = (int*)(ws + alloc(256));
  int*  listTok= (int*)(ws + alloc((size_t)NE*TT*4));
  float* listW = (float*)(ws + alloc((size_t)NE*TT*4));
  u16*  actw0  = Bgux;                                  // alias: Bgux dead after gate/up GEMMs
  u16*  actw1  = Bgux + (size_t)(TT+1)*FD;
  u16*  abx    = CGU;                                   // alias: CGU dead after expert_kernel
  float* parts = (float*)Bgux;                          // alias: actw dead after combine2 (64 MB <= 67.2)

  hipMemsetAsync(count, 0, NE*sizeof(int), stream);
  hipMemsetAsync(cC, 0, (size_t)(TT+1)*2*16*4, stream);

  // one mega-prep: all casts + Bd-ext + hAx zero
  prep_kernel<<<PREP_BLOCKS, 256, 0, stream>>>(h, Wg, Wu, Wd, Ag, Au, Bg, Bu, Ad, Bd,
                                               hb, Bgux, Agu, Wdx, Bgb, Bub, Adb, hAx);

  router_kernel<<<TT, 64, 0, stream>>>(h, gw, sel, count, listTok, listW);

  // hAx = h @ [Ag;Au]^T  (M=2048, N=256, K=2048, split-K=8 -> 256 blocks)
  gemm128a<<<dim3(16, 2, 8), 256, 0, stream>>>(hb, Agu, hAx, HD, 256);

  // gate: CG = h @ Wg^T   (M=2048, N=8192, K=2048) -> 256 blocks = 1 exact round
  gemm256<0><<<dim3(8, 32, 1), 512, 0, stream>>>(hb, Bgux, CGU, HD, HD, NXE);
  // up:   CU = h @ Wu^T   -> 256 blocks = 1 exact round (writes CGU cols FD..)
  gemm256<0><<<dim3(8, 32, 1), 512, 0, stream>>>(hb, Bgux + (size_t)FD*HD, CGU + CU_OFF, HD, HD, NXE);

  // per-expert: deltas, act, weighted act into slot buffers (aliasing Bgux), c coefs
  expert_kernel<<<dim3(128, NE, 4), 256, 0, stream>>>(CGU, hAx, Bgb, Bub, Adb, count, listTok, listW,
                                                      actw0, actw1, cC);

  // abx = [actw0+actw1, c-scatter, zeros]  (writes into the dead CGU region)
  combine2_kernel<<<TT, 256, 0, stream>>>(actw0, actw1, cC, sel, abx);

  // partials[z] = abx @ Wdx^T slice z  (M=2048, N=2048, K=8704, split-K=4 -> 256 blocks, no atomics)
  gemm256<3><<<dim3(8, 8, 4), 512, 0, stream>>>(abx, Wdx, parts, KXD, KXD/4, HD);

  // out = sum of 4 partials
  reduce4_kernel<<<4096, 256, 0, stream>>>(parts, (float*)d_out);
}